// Round 1
// baseline (160.789 us; speedup 1.0000x reference)
//
#include <hip/hip_runtime.h>
#include <hip/hip_fp16.h>

typedef _Float16 h16;
typedef h16 v2h __attribute__((ext_vector_type(2)));
typedef h16 v4h __attribute__((ext_vector_type(4)));
typedef float f4 __attribute__((ext_vector_type(4)));

#define NATOM 4096
#define HALF_N 2048

__device__ __forceinline__ float rcp_fast(float x) {
#if __has_builtin(__builtin_amdgcn_rcpf)
  return __builtin_amdgcn_rcpf(x);
#else
  return 1.0f / x;
#endif
}

// tanh via exp2-based __expf; clamp avoids inf/NaN for |x| up to ~1e7
__device__ __forceinline__ float fast_tanh(float x) {
  float ax = fminf(fabsf(x), 12.0f);
  float e = __expf(2.0f * ax);
  float t = 1.0f - 2.0f * rcp_fast(e + 1.0f);
  return copysignf(t, x);
}

__device__ __forceinline__ float hdot2(v2h a, v2h b, float c) {
#if __has_builtin(__builtin_amdgcn_fdot2)
  return __builtin_amdgcn_fdot2(a, b, c, false);
#else
  return c + (float)a.x * (float)b.x + (float)a.y * (float)b.y;
#endif
}

// ---------------------------------------------------------------------------
// Kernel 1: one block (128 threads) per atom.
//   stage A: geometry + R rows + h0 = tanh(srcn*W0+b0)        (per neighbor)
//   stage B: h1 = tanh(h0 @ W1 + b1)   (register-blocked 8m x 4j GEMM)
//   fused C+D: E = tanh(h1 @ W2 + b2) consumed immediately into
//              T[x][c] += R[x][m] * E[m][c]  (lane = channel c, W2 col in regs)
//   stage G: G_NAC tensor algebra, write Gflat (N x 1024) to workspace
// ---------------------------------------------------------------------------
__global__ __launch_bounds__(128) void k_embed(
    const float* __restrict__ coord, const float* __restrict__ box,
    const int* __restrict__ nbrs,
    const float* __restrict__ eW0, const float* __restrict__ eb0,
    const float* __restrict__ eW1, const float* __restrict__ eb1,
    const float* __restrict__ eW2, const float* __restrict__ eb2,
    const float* __restrict__ Tbias,
    float* __restrict__ Gout)
{
  __shared__ float sW0[2][16], sb0[2][16], sb1[2][32];
  __shared__ float sW1[2][512];
  __shared__ float h0s[16][128];
  __shared__ h16   h1s[128][32];
  __shared__ float Rs[128][12];
  __shared__ float Ts[10][64];
  __shared__ float Tp[10][64];

  const int tid = threadIdx.x;
  const int n = blockIdx.x;
  const int ti = (n >= HALF_N) ? 1 : 0;

  // ---- stage weights for both neighbor-type slots ----
  for (int idx = tid; idx < 32; idx += 128) {
    int s = idx >> 4, i = idx & 15;
    sW0[s][i] = eW0[(ti * 2 + s) * 16 + i];
    sb0[s][i] = eb0[(ti * 2 + s) * 16 + i];
  }
  for (int idx = tid; idx < 64; idx += 128) {
    int s = idx >> 5, i = idx & 31;
    sb1[s][i] = eb1[(ti * 2 + s) * 32 + i];
  }
  for (int idx = tid; idx < 1024; idx += 128) {
    int s = idx >> 9, i = idx & 511;
    sW1[s][i] = eW1[(ti * 2 + s) * 512 + i];
  }
  __syncthreads();

  // ---- stage A: per-neighbor geometry, R rows, h0 ----
  {
    const int m = tid;
    const int j = nbrs[(size_t)n * 128 + m];
    const float bx = box[0], by = box[1], bz = box[2];
    float dx = coord[j] - coord[n];
    float dy = coord[NATOM + j] - coord[NATOM + n];
    float dz = coord[2 * NATOM + j] - coord[2 * NATOM + n];
    dx -= bx * rintf(dx / bx);   // round-half-even == jnp.round
    dy -= by * rintf(dy / by);
    dz -= bz * rintf(dz / bz);
    float r2 = dx * dx + dy * dy + dz * dz;
    bool mk = r2 > 1e-12f;
    float rs = sqrtf(mk ? r2 : 1.0f);
    float r  = mk ? rs : 0.0f;
    float sw = 0.5f * __cosf(0.52359878f * fminf(r, 6.0f)) + 0.5f;  // pi/6
    float invr = mk ? rcp_fast(rs) : 1.0f;
    float sr = (mk && r < 6.0f) ? sw * invr : 0.0f;
    float x0 = dx * invr, x1 = dy * invr, x2 = dz * invr;
    float srn  = sr * 20.0f;              // sr / 0.05
    float srcn = (sr - 0.1f) * 20.0f;     // (sr - mean)/std
    Rs[m][0] = srn;
    Rs[m][1] = 1.7320508f * srn * x0;
    Rs[m][2] = 1.7320508f * srn * x1;
    Rs[m][3] = 1.7320508f * srn * x2;
    Rs[m][4] = 3.0f * srn * (x0 * x0 - 0.33333334f);
    Rs[m][5] = 3.0f * srn * (x1 * x1 - 0.33333334f);
    Rs[m][6] = 3.0f * srn * (x2 * x2 - 0.33333334f);
    Rs[m][7] = 4.2426407f * srn * (x0 * x1);
    Rs[m][8] = 4.2426407f * srn * (x1 * x2);
    Rs[m][9] = 4.2426407f * srn * (x2 * x0);
    Rs[m][10] = 0.0f; Rs[m][11] = 0.0f;
    const int sl = m >> 6;
#pragma unroll
    for (int i = 0; i < 16; ++i)
      h0s[i][m] = fast_tanh(srcn * sW0[sl][i] + sb0[sl][i]);
  }
  __syncthreads();

  // ---- stage B: h1 = tanh(h0 @ W1 + b1), 8m x 4j per thread ----
  {
    const int mb = tid & 15, jb = tid >> 4;
    const int m0 = mb * 8, j0 = jb * 4, sl = mb >> 3;
    float acc[8][4];
#pragma unroll
    for (int p = 0; p < 8; ++p)
#pragma unroll
      for (int q = 0; q < 4; ++q) acc[p][q] = sb1[sl][j0 + q];
#pragma unroll
    for (int i = 0; i < 16; ++i) {
      f4 aLo = *(const f4*)&h0s[i][m0];
      f4 aHi = *(const f4*)&h0s[i][m0 + 4];
      f4 w   = *(const f4*)&sW1[sl][i * 32 + j0];
#pragma unroll
      for (int q = 0; q < 4; ++q) {
        acc[0][q] += aLo.x * w[q];
        acc[1][q] += aLo.y * w[q];
        acc[2][q] += aLo.z * w[q];
        acc[3][q] += aLo.w * w[q];
        acc[4][q] += aHi.x * w[q];
        acc[5][q] += aHi.y * w[q];
        acc[6][q] += aHi.z * w[q];
        acc[7][q] += aHi.w * w[q];
      }
    }
#pragma unroll
    for (int p = 0; p < 8; ++p) {
      v4h hv;
      hv.x = (h16)fast_tanh(acc[p][0]);
      hv.y = (h16)fast_tanh(acc[p][1]);
      hv.z = (h16)fast_tanh(acc[p][2]);
      hv.w = (h16)fast_tanh(acc[p][3]);
      *(v4h*)&h1s[m0 + p][j0] = hv;
    }
  }
  __syncthreads();

  // ---- fused C+D: lane = channel c; wave = neighbor-type half ----
  float Tacc[10];
  {
    const int wv = tid >> 6, c = tid & 63;
    const int k = ti * 2 + wv;
    v2h w2[16];
#pragma unroll
    for (int jj = 0; jj < 16; ++jj) {
      float w0 = eW2[(size_t)k * 2048 + (2 * jj) * 64 + c];
      float w1 = eW2[(size_t)k * 2048 + (2 * jj + 1) * 64 + c];
      w2[jj].x = (h16)w0; w2[jj].y = (h16)w1;
    }
    const float b2c = eb2[k * 64 + c];
#pragma unroll
    for (int x = 0; x < 10; ++x) Tacc[x] = 0.0f;
    const int mbase = wv * 64;
    for (int mm = 0; mm < 64; ++mm) {
      const int m = mbase + mm;
      const v2h* hp = (const v2h*)&h1s[m][0];
      float d = b2c;
#pragma unroll
      for (int jj = 0; jj < 16; ++jj) d = hdot2(hp[jj], w2[jj], d);
      const float E = fast_tanh(d);
      const f4 r0 = *(const f4*)&Rs[m][0];
      const f4 r1 = *(const f4*)&Rs[m][4];
      const f4 r2 = *(const f4*)&Rs[m][8];
      Tacc[0] += r0.x * E; Tacc[1] += r0.y * E; Tacc[2] += r0.z * E; Tacc[3] += r0.w * E;
      Tacc[4] += r1.x * E; Tacc[5] += r1.y * E; Tacc[6] += r1.z * E; Tacc[7] += r1.w * E;
      Tacc[8] += r2.x * E; Tacc[9] += r2.y * E;
    }
    if (wv == 1) {
#pragma unroll
      for (int x = 0; x < 10; ++x) Tp[x][c] = Tacc[x];
    }
  }
  __syncthreads();
  {
    const int wv = tid >> 6, c = tid & 63;
    if (wv == 0) {
#pragma unroll
      for (int x = 0; x < 10; ++x) Ts[x][c] = (Tacc[x] + Tp[x][c]) * 0.05f; // /NORM
    }
  }
  __syncthreads();

  // ---- stage G: tensor algebra + store Gflat ----
  {
    const int c = tid & 63, ah = tid >> 6;
    const float tnc  = Ts[0][c] + Tbias[c];
    const float t3c0 = Ts[1][c], t3c1 = Ts[2][c], t3c2 = Ts[3][c];
    const float t6c0 = Ts[4][c], t6c1 = Ts[5][c], t6c2 = Ts[6][c];
    const float t6c3 = Ts[7][c], t6c4 = Ts[8][c], t6c5 = Ts[9][c];
    float* gp = Gout + (size_t)n * 1024;
#pragma unroll
    for (int q = 0; q < 8; ++q) {
      const int a = ah * 8 + q;
      float g = tnc * (Ts[0][a] + Tbias[a]);
      g += t3c0 * Ts[1][a] + t3c1 * Ts[2][a] + t3c2 * Ts[3][a];
      const float g1x = Ts[1][16 + a], g1y = Ts[2][16 + a], g1z = Ts[3][16 + a];
      g += (g1x * g1x + Ts[4][16 + a]) * t6c0;
      g += (g1y * g1y + Ts[5][16 + a]) * t6c1;
      g += (g1z * g1z + Ts[6][16 + a]) * t6c2;
      g += (1.4142135f * g1x * g1y + Ts[7][16 + a]) * t6c3;
      g += (1.4142135f * g1y * g1z + Ts[8][16 + a]) * t6c4;
      g += (1.4142135f * g1z * g1x + Ts[9][16 + a]) * t6c5;
      gp[a * 64 + c] = g;
    }
  }
}

// ---------------------------------------------------------------------------
// Kernel 2a: fitting layer 0 partial GEMM, K-split x4.
// grid = 64 atom-tiles * 4 ksplit; block 256 = 16 a-blocks x 16 j-blocks.
// ---------------------------------------------------------------------------
__global__ __launch_bounds__(256) void k_fit0(const float* __restrict__ G,
    const float* __restrict__ fW0, float* __restrict__ P)
{
  __shared__ float At[64][68];   // pad 68: b128 reads 2-way (free), aligned
  const int tid = threadIdx.x;
  const int tile = blockIdx.x >> 2;
  const int ks = blockIdx.x & 3;
  const int abase = tile * 64;
  const int t = (abase >= HALF_N) ? 1 : 0;
  const float* W = fW0 + (size_t)t * 1024 * 128;
  const int ab = tid & 15, jb = tid >> 4;
  const int a0 = ab * 4, j0 = jb * 8;
  float acc[4][8];
#pragma unroll
  for (int p = 0; p < 4; ++p)
#pragma unroll
    for (int q = 0; q < 8; ++q) acc[p][q] = 0.0f;

  for (int kc = 0; kc < 4; ++kc) {
    const int ibase = ks * 256 + kc * 64;
    __syncthreads();
    for (int u = 0; u < 16; ++u) {
      int idx = tid + u * 256;
      int a = idx >> 6, il = idx & 63;
      At[il][a] = G[(size_t)(abase + a) * 1024 + ibase + il];
    }
    __syncthreads();
    for (int i = 0; i < 64; ++i) {
      f4 av  = *(const f4*)&At[i][a0];
      f4 wLo = *(const f4*)&W[(size_t)(ibase + i) * 128 + j0];
      f4 wHi = *(const f4*)&W[(size_t)(ibase + i) * 128 + j0 + 4];
#pragma unroll
      for (int p = 0; p < 4; ++p) {
        acc[p][0] += av[p] * wLo.x; acc[p][1] += av[p] * wLo.y;
        acc[p][2] += av[p] * wLo.z; acc[p][3] += av[p] * wLo.w;
        acc[p][4] += av[p] * wHi.x; acc[p][5] += av[p] * wHi.y;
        acc[p][6] += av[p] * wHi.z; acc[p][7] += av[p] * wHi.w;
      }
    }
  }
  float* o = P + ((size_t)ks * 4096 + abase + a0) * 128 + j0;
#pragma unroll
  for (int p = 0; p < 4; ++p) {
    f4 lo = {acc[p][0], acc[p][1], acc[p][2], acc[p][3]};
    f4 hi = {acc[p][4], acc[p][5], acc[p][6], acc[p][7]};
    *(f4*)(o + (size_t)p * 128)     = lo;
    *(f4*)(o + (size_t)p * 128 + 4) = hi;
  }
}

// ---------------------------------------------------------------------------
// Kernel 2b: combine K-split partials + bias + tanh, layers 1-2, per-block
// energy partial. grid = 128 blocks x 32 atoms; block 128 threads.
// ---------------------------------------------------------------------------
__global__ __launch_bounds__(128) void k_fit1(const float* __restrict__ P,
    const float* __restrict__ fb0, const float* __restrict__ fW1,
    const float* __restrict__ fb1, const float* __restrict__ fW2,
    const float* __restrict__ fb2, const float* __restrict__ Ebias,
    float* __restrict__ BP)
{
  __shared__ float ht[128][36];   // transposed h1, pad 36 for aligned b128
  __shared__ float red[16][32];
  const int tid = threadIdx.x;
  const int abase = blockIdx.x * 32;
  const int t = (abase >= HALF_N) ? 1 : 0;

  for (int u = 0; u < 32; ++u) {
    int idx = tid + u * 128;
    int a = idx >> 7, jj = idx & 127;
    size_t base = ((size_t)(abase + a)) * 128 + jj;
    float s = P[base] + P[(size_t)4096 * 128 + base]
            + P[(size_t)2 * 4096 * 128 + base] + P[(size_t)3 * 4096 * 128 + base]
            + fb0[t * 128 + jj];
    ht[jj][a] = fast_tanh(s);
  }
  __syncthreads();

  const int ab = tid & 7, jb = tid >> 3;
  const int a0 = ab * 4, j0 = jb * 8;
  const float* W1 = fW1 + (size_t)t * 16384;
  float acc[4][8];
#pragma unroll
  for (int p = 0; p < 4; ++p)
#pragma unroll
    for (int q = 0; q < 8; ++q) acc[p][q] = fb1[t * 128 + j0 + q];
  for (int i = 0; i < 128; ++i) {
    f4 av  = *(const f4*)&ht[i][a0];
    f4 wLo = *(const f4*)&W1[i * 128 + j0];
    f4 wHi = *(const f4*)&W1[i * 128 + j0 + 4];
#pragma unroll
    for (int p = 0; p < 4; ++p) {
      acc[p][0] += av[p] * wLo.x; acc[p][1] += av[p] * wLo.y;
      acc[p][2] += av[p] * wLo.z; acc[p][3] += av[p] * wLo.w;
      acc[p][4] += av[p] * wHi.x; acc[p][5] += av[p] * wHi.y;
      acc[p][6] += av[p] * wHi.z; acc[p][7] += av[p] * wHi.w;
    }
  }
  float pq[4];
#pragma unroll
  for (int p = 0; p < 4; ++p) {
    float s = 0.0f;
#pragma unroll
    for (int x = 0; x < 8; ++x) s += fast_tanh(acc[p][x]) * fW2[t * 128 + j0 + x];
    pq[p] = s;
  }
#pragma unroll
  for (int p = 0; p < 4; ++p) red[jb][a0 + p] = pq[p];
  __syncthreads();
  if (tid < 32) {
    float s = 0.0f;
#pragma unroll
    for (int r = 0; r < 16; ++r) s += red[r][tid];
    s += fb2[t] + Ebias[t];
    s += __shfl_xor(s, 16);
    s += __shfl_xor(s, 8);
    s += __shfl_xor(s, 4);
    s += __shfl_xor(s, 2);
    s += __shfl_xor(s, 1);
    if (tid == 0) BP[blockIdx.x] = s;
  }
}

__global__ __launch_bounds__(64) void k_reduce(const float* __restrict__ BP,
                                               float* __restrict__ out)
{
  int tid = threadIdx.x;
  float s = BP[tid] + BP[tid + 64];
  s += __shfl_xor(s, 32);
  s += __shfl_xor(s, 16);
  s += __shfl_xor(s, 8);
  s += __shfl_xor(s, 4);
  s += __shfl_xor(s, 2);
  s += __shfl_xor(s, 1);
  if (tid == 0) out[0] = s;
}

extern "C" void kernel_launch(void* const* d_in, const int* in_sizes, int n_in,
                              void* d_out, int out_size, void* d_ws, size_t ws_size,
                              hipStream_t stream) {
  const float* coord = (const float*)d_in[0];
  const float* box   = (const float*)d_in[1];
  const int*   nbrs  = (const int*)d_in[2];
  const float* eW0   = (const float*)d_in[3];
  const float* eb0   = (const float*)d_in[4];
  const float* eW1   = (const float*)d_in[5];
  const float* eb1   = (const float*)d_in[6];
  const float* eW2   = (const float*)d_in[7];
  const float* eb2   = (const float*)d_in[8];
  const float* Tbias = (const float*)d_in[9];
  const float* fW0   = (const float*)d_in[10];
  const float* fb0   = (const float*)d_in[11];
  const float* fW1   = (const float*)d_in[12];
  const float* fb1   = (const float*)d_in[13];
  const float* fW2   = (const float*)d_in[14];
  const float* fb2   = (const float*)d_in[15];
  const float* Ebias = (const float*)d_in[16];

  float* G  = (float*)d_ws;                      // 4096*1024 f32 = 16 MB
  float* P  = G + (size_t)4096 * 1024;           // 4*4096*128 f32 = 8 MB
  float* BP = P + (size_t)4 * 4096 * 128;        // 128 f32

  k_embed<<<4096, 128, 0, stream>>>(coord, box, nbrs, eW0, eb0, eW1, eb1,
                                    eW2, eb2, Tbias, G);
  k_fit0<<<256, 256, 0, stream>>>(G, fW0, P);
  k_fit1<<<128, 128, 0, stream>>>(P, fb0, fW1, fb1, fW2, fb2, Ebias, BP);
  k_reduce<<<1, 64, 0, stream>>>(BP, (float*)d_out);
}

// Round 2
// 131.469 us; speedup vs baseline: 1.2230x; 1.2230x over previous
//
#include <hip/hip_runtime.h>
#include <hip/hip_fp16.h>
#include <hip/hip_bf16.h>

typedef _Float16 h16;
typedef h16 v2h __attribute__((ext_vector_type(2)));
typedef h16 v4h __attribute__((ext_vector_type(4)));
typedef h16 v8h __attribute__((ext_vector_type(8)));
typedef float f4 __attribute__((ext_vector_type(4)));

#define NATOM 4096
#define HALF_N 2048

__device__ __forceinline__ float rcp_fast(float x) {
#if __has_builtin(__builtin_amdgcn_rcpf)
  return __builtin_amdgcn_rcpf(x);
#else
  return 1.0f / x;
#endif
}

__device__ __forceinline__ float fast_tanh(float x) {
  float ax = fminf(fabsf(x), 12.0f);
  float e = __expf(2.0f * ax);
  float t = 1.0f - 2.0f * rcp_fast(e + 1.0f);
  return copysignf(t, x);
}

__device__ __forceinline__ float hdot2(v2h a, v2h b, float c) {
#if __has_builtin(__builtin_amdgcn_fdot2)
  return __builtin_amdgcn_fdot2(a, b, c, false);
#else
  return c + (float)a.x * (float)b.x + (float)a.y * (float)b.y;
#endif
}

__device__ __forceinline__ float lane_bcast(float v, int lane) {
#if __has_builtin(__builtin_amdgcn_readlane)
  return __builtin_bit_cast(float, __builtin_amdgcn_readlane(__builtin_bit_cast(int, v), lane));
#else
  return __shfl(v, lane, 64);
#endif
}

// ---------------------------------------------------------------------------
// Kernel 1: 256 threads = 2 atoms per block (128 thr each, tid2 = tid&127).
// R rows kept in registers (stage A lane m == stage C wave lane mm) and
// broadcast via v_readlane -> no Rs LDS array, no per-iter uniform b128 reads.
// h0 / W1 staged as fp16. LDS = 37.4 KB -> 4 blocks/CU (16 waves).
// ---------------------------------------------------------------------------
__global__ __launch_bounds__(256, 4) void k_embed(
    const float* __restrict__ coord, const float* __restrict__ box,
    const int* __restrict__ nbrs,
    const float* __restrict__ eW0, const float* __restrict__ eb0,
    const float* __restrict__ eW1, const float* __restrict__ eb1,
    const float* __restrict__ eW2, const float* __restrict__ eb2,
    const float* __restrict__ Tbias,
    __hip_bfloat16* __restrict__ Gout)
{
  __shared__ float sW0[2][16], sb0[2][16], sb1[2][32];
  __shared__ h16 sW1h[2][512];
  __shared__ h16 h0s[2][16][128];
  __shared__ h16 h1s[2][128][32];
  __shared__ float Tss[2][10][64];
  __shared__ float Tps[2][10][64];

  const int tid = threadIdx.x;
  const int sub = tid >> 7;
  const int tid2 = tid & 127;
  const int n = blockIdx.x * 2 + sub;
  const int ti = (n >= HALF_N) ? 1 : 0;   // both atoms in block share type
  const int wv = tid2 >> 6, c = tid2 & 63;

  // hoist global loads: neighbor index + W2 column for stage C
  const int jnb = nbrs[(size_t)n * 128 + tid2];
  const int kk2 = ti * 2 + wv;
  v2h w2[16];
#pragma unroll
  for (int jj = 0; jj < 16; ++jj) {
    float w0 = eW2[(size_t)kk2 * 2048 + (2 * jj) * 64 + c];
    float w1 = eW2[(size_t)kk2 * 2048 + (2 * jj + 1) * 64 + c];
    w2[jj].x = (h16)w0; w2[jj].y = (h16)w1;
  }
  const float b2c = eb2[kk2 * 64 + c];

  // ---- stage embedding weights ----
  for (int idx = tid; idx < 32; idx += 256) {
    int s = idx >> 4, i = idx & 15;
    sW0[s][i] = eW0[(ti * 2 + s) * 16 + i];
    sb0[s][i] = eb0[(ti * 2 + s) * 16 + i];
  }
  for (int idx = tid; idx < 64; idx += 256) {
    int s = idx >> 5, i = idx & 31;
    sb1[s][i] = eb1[(ti * 2 + s) * 32 + i];
  }
  for (int idx = tid; idx < 1024; idx += 256) {
    int s = idx >> 9, i = idx & 511;
    sW1h[s][i] = (h16)eW1[(ti * 2 + s) * 512 + i];
  }
  __syncthreads();

  // ---- stage A: geometry, R rows (registers!), h0 ----
  float R[10];
  {
    const int m = tid2;
    const float bx = box[0], by = box[1], bz = box[2];
    float dx = coord[jnb] - coord[n];
    float dy = coord[NATOM + jnb] - coord[NATOM + n];
    float dz = coord[2 * NATOM + jnb] - coord[2 * NATOM + n];
    dx -= bx * rintf(dx / bx);
    dy -= by * rintf(dy / by);
    dz -= bz * rintf(dz / bz);
    float r2 = dx * dx + dy * dy + dz * dz;
    bool mk = r2 > 1e-12f;
    float rs = sqrtf(mk ? r2 : 1.0f);
    float r  = mk ? rs : 0.0f;
    float sw = 0.5f * __cosf(0.52359878f * fminf(r, 6.0f)) + 0.5f;
    float invr = mk ? rcp_fast(rs) : 1.0f;
    float sr = (mk && r < 6.0f) ? sw * invr : 0.0f;
    float x0 = dx * invr, x1 = dy * invr, x2 = dz * invr;
    float srn  = sr * 20.0f;
    float srcn = (sr - 0.1f) * 20.0f;
    R[0] = srn;
    R[1] = 1.7320508f * srn * x0;
    R[2] = 1.7320508f * srn * x1;
    R[3] = 1.7320508f * srn * x2;
    R[4] = 3.0f * srn * (x0 * x0 - 0.33333334f);
    R[5] = 3.0f * srn * (x1 * x1 - 0.33333334f);
    R[6] = 3.0f * srn * (x2 * x2 - 0.33333334f);
    R[7] = 4.2426407f * srn * (x0 * x1);
    R[8] = 4.2426407f * srn * (x1 * x2);
    R[9] = 4.2426407f * srn * (x2 * x0);
    const int sl = m >> 6;
#pragma unroll
    for (int i = 0; i < 16; ++i)
      h0s[sub][i][m] = (h16)fast_tanh(srcn * sW0[sl][i] + sb0[sl][i]);
  }
  __syncthreads();

  // ---- stage B: h1 = tanh(h0 @ W1 + b1), 8m x 4j per thread, fp16 LDS ----
  {
    const int mb = tid2 & 15, jb = tid2 >> 4;
    const int m0 = mb * 8, j0 = jb * 4, sl = mb >> 3;
    float acc[8][4];
#pragma unroll
    for (int p = 0; p < 8; ++p)
#pragma unroll
      for (int q = 0; q < 4; ++q) acc[p][q] = sb1[sl][j0 + q];
#pragma unroll
    for (int i = 0; i < 16; ++i) {
      v8h h8 = *(const v8h*)&h0s[sub][i][m0];
      v4h w4 = *(const v4h*)&sW1h[sl][i * 32 + j0];
      float wf[4];
#pragma unroll
      for (int q = 0; q < 4; ++q) wf[q] = (float)w4[q];
#pragma unroll
      for (int p = 0; p < 8; ++p) {
        float hp = (float)h8[p];
#pragma unroll
        for (int q = 0; q < 4; ++q) acc[p][q] += hp * wf[q];
      }
    }
#pragma unroll
    for (int p = 0; p < 8; ++p) {
      v4h hv;
#pragma unroll
      for (int q = 0; q < 4; ++q) hv[q] = (h16)fast_tanh(acc[p][q]);
      *(v4h*)&h1s[sub][m0 + p][j0] = hv;
    }
  }
  __syncthreads();

  // ---- stage C+D: E = tanh(h1 @ W2 + b2) fused into T += R * E ----
  float Tacc[10];
  {
#pragma unroll
    for (int x = 0; x < 10; ++x) Tacc[x] = 0.0f;
    const int mbase = wv * 64;
#pragma unroll 4
    for (int mm = 0; mm < 64; ++mm) {
      const int m = mbase + mm;
      union UU { f4 f; v2h h[4]; };
      UU u0, u1, u2, u3;
      u0.f = *(const f4*)&h1s[sub][m][0];
      u1.f = *(const f4*)&h1s[sub][m][8];
      u2.f = *(const f4*)&h1s[sub][m][16];
      u3.f = *(const f4*)&h1s[sub][m][24];
      float d0 = hdot2(u0.h[0], w2[0], 0.0f);
      float d1 = hdot2(u0.h[1], w2[1], b2c);
      d0 = hdot2(u0.h[2], w2[2], d0);  d1 = hdot2(u0.h[3], w2[3], d1);
      d0 = hdot2(u1.h[0], w2[4], d0);  d1 = hdot2(u1.h[1], w2[5], d1);
      d0 = hdot2(u1.h[2], w2[6], d0);  d1 = hdot2(u1.h[3], w2[7], d1);
      d0 = hdot2(u2.h[0], w2[8], d0);  d1 = hdot2(u2.h[1], w2[9], d1);
      d0 = hdot2(u2.h[2], w2[10], d0); d1 = hdot2(u2.h[3], w2[11], d1);
      d0 = hdot2(u3.h[0], w2[12], d0); d1 = hdot2(u3.h[1], w2[13], d1);
      d0 = hdot2(u3.h[2], w2[14], d0); d1 = hdot2(u3.h[3], w2[15], d1);
      const float E = fast_tanh(d0 + d1);
#pragma unroll
      for (int x = 0; x < 10; ++x)
        Tacc[x] += lane_bcast(R[x], mm) * E;
    }
  }
  __syncthreads();
  if (wv == 1) {
#pragma unroll
    for (int x = 0; x < 10; ++x) Tps[sub][x][c] = Tacc[x];
  }
  __syncthreads();
  if (wv == 0) {
#pragma unroll
    for (int x = 0; x < 10; ++x)
      Tss[sub][x][c] = (Tacc[x] + Tps[sub][x][c]) * 0.05f;  // / NORM
  }
  __syncthreads();

  // ---- stage G: tensor algebra + store Gflat as bf16 ----
  {
    const int ah = tid2 >> 6;
    const float tnc  = Tss[sub][0][c] + Tbias[c];
    const float t3c0 = Tss[sub][1][c], t3c1 = Tss[sub][2][c], t3c2 = Tss[sub][3][c];
    const float t6c0 = Tss[sub][4][c], t6c1 = Tss[sub][5][c], t6c2 = Tss[sub][6][c];
    const float t6c3 = Tss[sub][7][c], t6c4 = Tss[sub][8][c], t6c5 = Tss[sub][9][c];
    __hip_bfloat16* gp = Gout + (size_t)n * 1024;
#pragma unroll
    for (int q = 0; q < 8; ++q) {
      const int a = ah * 8 + q;
      float g = tnc * (Tss[sub][0][a] + Tbias[a]);
      g += t3c0 * Tss[sub][1][a] + t3c1 * Tss[sub][2][a] + t3c2 * Tss[sub][3][a];
      const float g1x = Tss[sub][1][16 + a], g1y = Tss[sub][2][16 + a], g1z = Tss[sub][3][16 + a];
      g += (g1x * g1x + Tss[sub][4][16 + a]) * t6c0;
      g += (g1y * g1y + Tss[sub][5][16 + a]) * t6c1;
      g += (g1z * g1z + Tss[sub][6][16 + a]) * t6c2;
      g += (1.4142135f * g1x * g1y + Tss[sub][7][16 + a]) * t6c3;
      g += (1.4142135f * g1y * g1z + Tss[sub][8][16 + a]) * t6c4;
      g += (1.4142135f * g1z * g1x + Tss[sub][9][16 + a]) * t6c5;
      gp[a * 64 + c] = __float2bfloat16(g);
    }
  }
}

// ---------------------------------------------------------------------------
// Kernel 2a: fit layer-0 partial GEMM. grid = 32 atom-tiles(128) x 8 ksplit.
// block 256, thread tile 8a x 8j (64 FMA per 3 LDS b128). W staged in LDS.
// ---------------------------------------------------------------------------
__global__ __launch_bounds__(256, 2) void k_fit0(
    const __hip_bfloat16* __restrict__ G,
    const float* __restrict__ fW0, float* __restrict__ P)
{
  __shared__ float At[32][132];   // transposed A sub-tile (f32 after cvt)
  __shared__ float Ws[32][128];   // W sub-chunk
  const int tid = threadIdx.x;
  const int tile = blockIdx.x >> 3;
  const int ks = blockIdx.x & 7;
  const int abase = tile * 128;
  const int kbase = ks * 128;
  const int t = (abase >= HALF_N) ? 1 : 0;
  const int ab = tid & 15, jb = tid >> 4;
  const int a0 = ab * 8, j0 = jb * 8;

  float acc[8][8];
#pragma unroll
  for (int p = 0; p < 8; ++p)
#pragma unroll
    for (int q = 0; q < 8; ++q) acc[p][q] = 0.0f;

  for (int kc = 0; kc < 4; ++kc) {
    const int kb = kbase + kc * 32;
    __syncthreads();
    {
      const int a = tid >> 1, k0 = (tid & 1) * 16;
      const ushort* gs = (const ushort*)G + (size_t)(abase + a) * 1024 + kb + k0;
      uint4 v0 = *(const uint4*)gs;
      uint4 v1 = *(const uint4*)(gs + 8);
      union { uint4 u; ushort s[8]; } b0, b1;
      b0.u = v0; b1.u = v1;
#pragma unroll
      for (int q = 0; q < 8; ++q) {
        At[k0 + q][a]     = __builtin_bit_cast(float, (uint)b0.s[q] << 16);
        At[k0 + 8 + q][a] = __builtin_bit_cast(float, (uint)b1.s[q] << 16);
      }
    }
#pragma unroll
    for (int u = 0; u < 4; ++u) {
      int idx = (u * 256 + tid) * 4;
      int kk = idx >> 7, j = idx & 127;
      *(f4*)&Ws[kk][j] =
          *(const f4*)&fW0[(size_t)t * 131072 + (size_t)(kb + kk) * 128 + j];
    }
    __syncthreads();
    for (int kk = 0; kk < 32; ++kk) {
      f4 aLo = *(const f4*)&At[kk][a0];
      f4 aHi = *(const f4*)&At[kk][a0 + 4];
      f4 wLo = *(const f4*)&Ws[kk][j0];
      f4 wHi = *(const f4*)&Ws[kk][j0 + 4];
      float av[8] = {aLo.x, aLo.y, aLo.z, aLo.w, aHi.x, aHi.y, aHi.z, aHi.w};
      float wf[8] = {wLo.x, wLo.y, wLo.z, wLo.w, wHi.x, wHi.y, wHi.z, wHi.w};
#pragma unroll
      for (int p = 0; p < 8; ++p)
#pragma unroll
        for (int q = 0; q < 8; ++q) acc[p][q] += av[p] * wf[q];
    }
  }

#pragma unroll
  for (int p = 0; p < 8; ++p) {
    f4 lo = {acc[p][0], acc[p][1], acc[p][2], acc[p][3]};
    f4 hi = {acc[p][4], acc[p][5], acc[p][6], acc[p][7]};
    float* o = P + ((size_t)ks * 4096 + abase + a0 + p) * 128 + j0;
    *(f4*)o = lo;
    *(f4*)(o + 4) = hi;
  }
}

// ---------------------------------------------------------------------------
// Kernel 2b: combine 8 K-split partials + tanh, layers 1-2, per-block energy
// partial. grid = 512 blocks x 8 atoms; block 256. W1 staged in LDS.
// ---------------------------------------------------------------------------
__global__ __launch_bounds__(256, 4) void k_fit1(
    const float* __restrict__ P,
    const float* __restrict__ fb0, const float* __restrict__ fW1,
    const float* __restrict__ fb1, const float* __restrict__ fW2,
    const float* __restrict__ fb2, const float* __restrict__ Ebias,
    float* __restrict__ BP)
{
  __shared__ float ht[128][12];   // transposed h1 (8 atoms + pad)
  __shared__ float Ws1[32][128];
  __shared__ float red[8][33];
  const int tid = threadIdx.x;
  const int abase = blockIdx.x * 8;
  const int t = (abase >= HALF_N) ? 1 : 0;

  // combine K-split partials + bias, tanh -> ht
  {
    const int a = tid >> 5, j0 = (tid & 31) * 4;
    f4 s = *(const f4*)&fb0[t * 128 + j0];
#pragma unroll
    for (int ks = 0; ks < 8; ++ks)
      s += *(const f4*)&P[((size_t)ks * 4096 + abase + a) * 128 + j0];
    ht[j0 + 0][a] = fast_tanh(s.x);
    ht[j0 + 1][a] = fast_tanh(s.y);
    ht[j0 + 2][a] = fast_tanh(s.z);
    ht[j0 + 3][a] = fast_tanh(s.w);
  }

  const int ab = tid & 7, jb = tid >> 3;
  const int j0g = jb * 4;
  f4 acc = *(const f4*)&fb1[t * 128 + j0g];
  for (int kc = 0; kc < 4; ++kc) {
    __syncthreads();
#pragma unroll
    for (int u = 0; u < 2; ++u) {
      int idx = (u * 256 + tid) * 8;
      int kk = idx >> 7, j = idx & 127;
      *(f4*)&Ws1[kk][j] =
          *(const f4*)&fW1[(size_t)t * 16384 + (size_t)(kc * 32 + kk) * 128 + j];
      *(f4*)&Ws1[kk][j + 4] =
          *(const f4*)&fW1[(size_t)t * 16384 + (size_t)(kc * 32 + kk) * 128 + j + 4];
    }
    __syncthreads();
    for (int kk = 0; kk < 32; ++kk) {
      float av = ht[kc * 32 + kk][ab];
      f4 w = *(const f4*)&Ws1[kk][j0g];
      acc += av * w;
    }
  }

  float f = fast_tanh(acc.x) * fW2[t * 128 + j0g + 0]
          + fast_tanh(acc.y) * fW2[t * 128 + j0g + 1]
          + fast_tanh(acc.z) * fW2[t * 128 + j0g + 2]
          + fast_tanh(acc.w) * fW2[t * 128 + j0g + 3];
  red[ab][jb] = f;
  __syncthreads();
  if (tid < 64) {
    const int a = tid & 7, j4 = tid >> 3;
    float v = red[a][j4 * 4] + red[a][j4 * 4 + 1]
            + red[a][j4 * 4 + 2] + red[a][j4 * 4 + 3];
    v += __shfl_xor(v, 32);
    v += __shfl_xor(v, 16);
    v += __shfl_xor(v, 8);
    v += __shfl_xor(v, 4);
    v += __shfl_xor(v, 2);
    v += __shfl_xor(v, 1);
    if (tid == 0) BP[blockIdx.x] = v + 8.0f * (fb2[t] + Ebias[t]);
  }
}

__global__ __launch_bounds__(64) void k_reduce(const float* __restrict__ BP,
                                               float* __restrict__ out)
{
  int tid = threadIdx.x;
  float s = 0.0f;
#pragma unroll
  for (int u = 0; u < 8; ++u) s += BP[tid + 64 * u];
  s += __shfl_xor(s, 32);
  s += __shfl_xor(s, 16);
  s += __shfl_xor(s, 8);
  s += __shfl_xor(s, 4);
  s += __shfl_xor(s, 2);
  s += __shfl_xor(s, 1);
  if (tid == 0) out[0] = s;
}

extern "C" void kernel_launch(void* const* d_in, const int* in_sizes, int n_in,
                              void* d_out, int out_size, void* d_ws, size_t ws_size,
                              hipStream_t stream) {
  const float* coord = (const float*)d_in[0];
  const float* box   = (const float*)d_in[1];
  const int*   nbrs  = (const int*)d_in[2];
  const float* eW0   = (const float*)d_in[3];
  const float* eb0   = (const float*)d_in[4];
  const float* eW1   = (const float*)d_in[5];
  const float* eb1   = (const float*)d_in[6];
  const float* eW2   = (const float*)d_in[7];
  const float* eb2   = (const float*)d_in[8];
  const float* Tbias = (const float*)d_in[9];
  const float* fW0   = (const float*)d_in[10];
  const float* fb0   = (const float*)d_in[11];
  const float* fW1   = (const float*)d_in[12];
  const float* fb1   = (const float*)d_in[13];
  const float* fW2   = (const float*)d_in[14];
  const float* fb2   = (const float*)d_in[15];
  const float* Ebias = (const float*)d_in[16];

  __hip_bfloat16* G = (__hip_bfloat16*)d_ws;                  // 8 MB
  float* P  = (float*)((char*)d_ws + (size_t)8 * 1024 * 1024); // 16 MB
  float* BP = (float*)d_ws;  // overlaid on G (G dead once fit0 completes)

  k_embed<<<2048, 256, 0, stream>>>(coord, box, nbrs, eW0, eb0, eW1, eb1,
                                    eW2, eb2, Tbias, G);
  k_fit0<<<256, 256, 0, stream>>>(G, fW0, P);
  k_fit1<<<512, 256, 0, stream>>>(P, fb0, fW1, fb1, fW2, fb2, Ebias, BP);
  k_reduce<<<1, 64, 0, stream>>>(BP, (float*)d_out);
}

// Round 3
// 110.295 us; speedup vs baseline: 1.4578x; 1.1920x over previous
//
#include <hip/hip_runtime.h>
#include <hip/hip_fp16.h>
#include <hip/hip_bf16.h>

typedef _Float16 h16;
typedef h16 v2h __attribute__((ext_vector_type(2)));
typedef h16 v4h __attribute__((ext_vector_type(4)));
typedef h16 v8h __attribute__((ext_vector_type(8)));
typedef float f4 __attribute__((ext_vector_type(4)));

#define NATOM 4096
#define HALF_N 2048

__device__ __forceinline__ float rcp_fast(float x) {
#if __has_builtin(__builtin_amdgcn_rcpf)
  return __builtin_amdgcn_rcpf(x);
#else
  return 1.0f / x;
#endif
}

__device__ __forceinline__ float fast_tanh(float x) {
  float ax = fminf(fabsf(x), 12.0f);
  float e = __expf(2.0f * ax);
  float t = 1.0f - 2.0f * rcp_fast(e + 1.0f);
  return copysignf(t, x);
}

__device__ __forceinline__ float hdot2(v2h a, v2h b, float c) {
#if __has_builtin(__builtin_amdgcn_fdot2)
  return __builtin_amdgcn_fdot2(a, b, c, false);
#else
  return c + (float)a.x * (float)b.x + (float)a.y * (float)b.y;
#endif
}

__device__ __forceinline__ float lane_bcast(float v, int lane) {
#if __has_builtin(__builtin_amdgcn_readlane)
  return __builtin_bit_cast(float, __builtin_amdgcn_readlane(__builtin_bit_cast(int, v), lane));
#else
  return __shfl(v, lane, 64);
#endif
}

// ---------------------------------------------------------------------------
// Kernel 1: 256 threads = 2 atoms (sub = tid>>7). Wave (sub,wv) lane L owns
// neighbor m = wv*64+L through stages A and B: geometry/R and h0 stay in
// registers; lane computes the whole h1[m][0..31] row (fdot2 vs W1 pairs
// broadcast from LDS) and writes it once to a padded LDS row. Stage C reads
// rows uniformly (broadcast) and readlane-broadcasts R from the same wave.
// No spills: launch_bounds(256,2) -> 256-VGPR budget.
// ---------------------------------------------------------------------------
__global__ __launch_bounds__(256, 2) void k_embed(
    const float* __restrict__ coord, const float* __restrict__ box,
    const int* __restrict__ nbrs,
    const float* __restrict__ eW0, const float* __restrict__ eb0,
    const float* __restrict__ eW1, const float* __restrict__ eb1,
    const float* __restrict__ eW2, const float* __restrict__ eb2,
    const float* __restrict__ Tbias,
    __hip_bfloat16* __restrict__ Gout)
{
  __shared__ float sW0[2][16], sb0[2][16], sb1[2][32];
  __shared__ v2h   sW1p[2][8][32];      // [slot][i-pair][j] of W1
  __shared__ h16   h1s[2][128][40];     // 80B rows: 16B-aligned, pad kills
  __shared__ float Tps[2][10][64];      //   the write-bank degeneracy
  __shared__ float Tss[2][10][64];

  const int tid = threadIdx.x;
  const int sub = tid >> 7;
  const int tid2 = tid & 127;
  const int n = blockIdx.x * 2 + sub;
  const int ti = (n >= HALF_N) ? 1 : 0;
  const int wv = tid2 >> 6, c = tid2 & 63;   // c == lane within wave

  // ---- stage weights into LDS ----
  for (int idx = tid; idx < 32; idx += 256) {
    int s = idx >> 4, i = idx & 15;
    sW0[s][i] = eW0[(ti * 2 + s) * 16 + i];
    sb0[s][i] = eb0[(ti * 2 + s) * 16 + i];
  }
  for (int idx = tid; idx < 64; idx += 256) {
    int s = idx >> 5, i = idx & 31;
    sb1[s][i] = eb1[(ti * 2 + s) * 32 + i];
  }
  for (int idx = tid; idx < 512; idx += 256) {
    int s = idx >> 8, r = idx & 255, ip = r >> 5, j = r & 31;
    const float* src = &eW1[(size_t)(ti * 2 + s) * 512];
    v2h p; p.x = (h16)src[(2 * ip) * 32 + j]; p.y = (h16)src[(2 * ip + 1) * 32 + j];
    sW1p[s][ip][j] = p;
  }

  // hoist: neighbor index + W2 column (global, L2-resident)
  const int jnb = nbrs[(size_t)n * 128 + tid2];
  const int kk2 = ti * 2 + wv;
  v2h w2[16];
#pragma unroll
  for (int jj = 0; jj < 16; ++jj) {
    float w0 = eW2[(size_t)kk2 * 2048 + (2 * jj) * 64 + c];
    float w1 = eW2[(size_t)kk2 * 2048 + (2 * jj + 1) * 64 + c];
    w2[jj].x = (h16)w0; w2[jj].y = (h16)w1;
  }
  const float b2c = eb2[kk2 * 64 + c];
  __syncthreads();

  // ---- stage A: geometry, R (registers), h0 (registers) ----
  float R[10];
  v2h h0p[8];
  {
    const float bx = box[0], by = box[1], bz = box[2];
    float dx = coord[jnb] - coord[n];
    float dy = coord[NATOM + jnb] - coord[NATOM + n];
    float dz = coord[2 * NATOM + jnb] - coord[2 * NATOM + n];
    dx -= bx * rintf(dx / bx);
    dy -= by * rintf(dy / by);
    dz -= bz * rintf(dz / bz);
    float r2 = dx * dx + dy * dy + dz * dz;
    bool mk = r2 > 1e-12f;
    float rs = sqrtf(mk ? r2 : 1.0f);
    float r  = mk ? rs : 0.0f;
    float sw = 0.5f * __cosf(0.52359878f * fminf(r, 6.0f)) + 0.5f;
    float invr = mk ? rcp_fast(rs) : 1.0f;
    float sr = (mk && r < 6.0f) ? sw * invr : 0.0f;
    float x0 = dx * invr, x1 = dy * invr, x2 = dz * invr;
    float srn  = sr * 20.0f;
    float srcn = (sr - 0.1f) * 20.0f;
    R[0] = srn;
    R[1] = 1.7320508f * srn * x0;
    R[2] = 1.7320508f * srn * x1;
    R[3] = 1.7320508f * srn * x2;
    R[4] = 3.0f * srn * (x0 * x0 - 0.33333334f);
    R[5] = 3.0f * srn * (x1 * x1 - 0.33333334f);
    R[6] = 3.0f * srn * (x2 * x2 - 0.33333334f);
    R[7] = 4.2426407f * srn * (x0 * x1);
    R[8] = 4.2426407f * srn * (x1 * x2);
    R[9] = 4.2426407f * srn * (x2 * x0);
#pragma unroll
    for (int ip = 0; ip < 8; ++ip) {
      v2h p;
      p.x = (h16)fast_tanh(srcn * sW0[wv][2 * ip]     + sb0[wv][2 * ip]);
      p.y = (h16)fast_tanh(srcn * sW0[wv][2 * ip + 1] + sb0[wv][2 * ip + 1]);
      h0p[ip] = p;
    }
  }

  // ---- stage B: lane computes full h1[m][0..31]; one LDS write ----
  {
    float acc[32];
#pragma unroll
    for (int j = 0; j < 32; ++j) acc[j] = sb1[wv][j];
    union WU { v8h v; v2h p[4]; };
#pragma unroll
    for (int ip = 0; ip < 8; ++ip) {
#pragma unroll
      for (int rr = 0; rr < 8; ++rr) {
        WU w; w.v = *(const v8h*)&sW1p[wv][ip][rr * 4];
#pragma unroll
        for (int q = 0; q < 4; ++q)
          acc[rr * 4 + q] = hdot2(h0p[ip], w.p[q], acc[rr * 4 + q]);
      }
    }
    union HU { v8h v; h16 e[8]; };
    h16* row = &h1s[sub][tid2][0];
#pragma unroll
    for (int ch = 0; ch < 4; ++ch) {
      HU o;
#pragma unroll
      for (int q = 0; q < 8; ++q) o.e[q] = (h16)fast_tanh(acc[ch * 8 + q]);
      *(v8h*)&row[ch * 8] = o.v;
    }
  }
  __syncthreads();

  // ---- stage C+D: E = tanh(h1 @ W2 + b2) fused into T += R * E ----
  float Tacc[10];
  {
#pragma unroll
    for (int x = 0; x < 10; ++x) Tacc[x] = 0.0f;
    const int mbase = wv * 64;
#pragma unroll 4
    for (int mm = 0; mm < 64; ++mm) {
      const h16* row = &h1s[sub][mbase + mm][0];
      union UU { v8h v; v2h h[4]; };
      UU u0, u1, u2, u3;
      u0.v = *(const v8h*)&row[0];
      u1.v = *(const v8h*)&row[8];
      u2.v = *(const v8h*)&row[16];
      u3.v = *(const v8h*)&row[24];
      float d0 = hdot2(u0.h[0], w2[0], 0.0f);
      float d1 = hdot2(u0.h[1], w2[1], b2c);
      d0 = hdot2(u0.h[2], w2[2], d0);  d1 = hdot2(u0.h[3], w2[3], d1);
      d0 = hdot2(u1.h[0], w2[4], d0);  d1 = hdot2(u1.h[1], w2[5], d1);
      d0 = hdot2(u1.h[2], w2[6], d0);  d1 = hdot2(u1.h[3], w2[7], d1);
      d0 = hdot2(u2.h[0], w2[8], d0);  d1 = hdot2(u2.h[1], w2[9], d1);
      d0 = hdot2(u2.h[2], w2[10], d0); d1 = hdot2(u2.h[3], w2[11], d1);
      d0 = hdot2(u3.h[0], w2[12], d0); d1 = hdot2(u3.h[1], w2[13], d1);
      d0 = hdot2(u3.h[2], w2[14], d0); d1 = hdot2(u3.h[3], w2[15], d1);
      const float E = fast_tanh(d0 + d1);
#pragma unroll
      for (int x = 0; x < 10; ++x)
        Tacc[x] += lane_bcast(R[x], mm) * E;
    }
  }
  __syncthreads();
  if (wv == 1) {
#pragma unroll
    for (int x = 0; x < 10; ++x) Tps[sub][x][c] = Tacc[x];
  }
  __syncthreads();
  if (wv == 0) {
#pragma unroll
    for (int x = 0; x < 10; ++x)
      Tss[sub][x][c] = (Tacc[x] + Tps[sub][x][c]) * 0.05f;  // / NORM
  }
  __syncthreads();

  // ---- stage G: tensor algebra + store Gflat as bf16 ----
  {
    const int ah = tid2 >> 6;
    const float tnc  = Tss[sub][0][c] + Tbias[c];
    const float t3c0 = Tss[sub][1][c], t3c1 = Tss[sub][2][c], t3c2 = Tss[sub][3][c];
    const float t6c0 = Tss[sub][4][c], t6c1 = Tss[sub][5][c], t6c2 = Tss[sub][6][c];
    const float t6c3 = Tss[sub][7][c], t6c4 = Tss[sub][8][c], t6c5 = Tss[sub][9][c];
    __hip_bfloat16* gp = Gout + (size_t)n * 1024;
#pragma unroll
    for (int q = 0; q < 8; ++q) {
      const int a = ah * 8 + q;
      float g = tnc * (Tss[sub][0][a] + Tbias[a]);
      g += t3c0 * Tss[sub][1][a] + t3c1 * Tss[sub][2][a] + t3c2 * Tss[sub][3][a];
      const float g1x = Tss[sub][1][16 + a], g1y = Tss[sub][2][16 + a], g1z = Tss[sub][3][16 + a];
      g += (g1x * g1x + Tss[sub][4][16 + a]) * t6c0;
      g += (g1y * g1y + Tss[sub][5][16 + a]) * t6c1;
      g += (g1z * g1z + Tss[sub][6][16 + a]) * t6c2;
      g += (1.4142135f * g1x * g1y + Tss[sub][7][16 + a]) * t6c3;
      g += (1.4142135f * g1y * g1z + Tss[sub][8][16 + a]) * t6c4;
      g += (1.4142135f * g1z * g1x + Tss[sub][9][16 + a]) * t6c5;
      gp[a * 64 + c] = __float2bfloat16(g);
    }
  }
}

// ---------------------------------------------------------------------------
// Kernel 2a: fit layer-0 partial GEMM. grid = 32 atom-tiles(128) x 8 ksplit.
// block 256, thread tile 8a x 8j. W staged in LDS.
// ---------------------------------------------------------------------------
__global__ __launch_bounds__(256, 2) void k_fit0(
    const __hip_bfloat16* __restrict__ G,
    const float* __restrict__ fW0, float* __restrict__ P)
{
  __shared__ float At[32][132];
  __shared__ float Ws[32][128];
  const int tid = threadIdx.x;
  const int tile = blockIdx.x >> 3;
  const int ks = blockIdx.x & 7;
  const int abase = tile * 128;
  const int kbase = ks * 128;
  const int t = (abase >= HALF_N) ? 1 : 0;
  const int ab = tid & 15, jb = tid >> 4;
  const int a0 = ab * 8, j0 = jb * 8;

  float acc[8][8];
#pragma unroll
  for (int p = 0; p < 8; ++p)
#pragma unroll
    for (int q = 0; q < 8; ++q) acc[p][q] = 0.0f;

  for (int kc = 0; kc < 4; ++kc) {
    const int kb = kbase + kc * 32;
    __syncthreads();
    {
      const int a = tid >> 1, k0 = (tid & 1) * 16;
      const ushort* gs = (const ushort*)G + (size_t)(abase + a) * 1024 + kb + k0;
      uint4 v0 = *(const uint4*)gs;
      uint4 v1 = *(const uint4*)(gs + 8);
      union { uint4 u; ushort s[8]; } b0, b1;
      b0.u = v0; b1.u = v1;
#pragma unroll
      for (int q = 0; q < 8; ++q) {
        At[k0 + q][a]     = __builtin_bit_cast(float, (uint)b0.s[q] << 16);
        At[k0 + 8 + q][a] = __builtin_bit_cast(float, (uint)b1.s[q] << 16);
      }
    }
#pragma unroll
    for (int u = 0; u < 4; ++u) {
      int idx = (u * 256 + tid) * 4;
      int kk = idx >> 7, j = idx & 127;
      *(f4*)&Ws[kk][j] =
          *(const f4*)&fW0[(size_t)t * 131072 + (size_t)(kb + kk) * 128 + j];
    }
    __syncthreads();
    for (int kk = 0; kk < 32; ++kk) {
      f4 aLo = *(const f4*)&At[kk][a0];
      f4 aHi = *(const f4*)&At[kk][a0 + 4];
      f4 wLo = *(const f4*)&Ws[kk][j0];
      f4 wHi = *(const f4*)&Ws[kk][j0 + 4];
      float av[8] = {aLo.x, aLo.y, aLo.z, aLo.w, aHi.x, aHi.y, aHi.z, aHi.w};
      float wf[8] = {wLo.x, wLo.y, wLo.z, wLo.w, wHi.x, wHi.y, wHi.z, wHi.w};
#pragma unroll
      for (int p = 0; p < 8; ++p)
#pragma unroll
        for (int q = 0; q < 8; ++q) acc[p][q] += av[p] * wf[q];
    }
  }

#pragma unroll
  for (int p = 0; p < 8; ++p) {
    f4 lo = {acc[p][0], acc[p][1], acc[p][2], acc[p][3]};
    f4 hi = {acc[p][4], acc[p][5], acc[p][6], acc[p][7]};
    float* o = P + ((size_t)ks * 4096 + abase + a0 + p) * 128 + j0;
    *(f4*)o = lo;
    *(f4*)(o + 4) = hi;
  }
}

// ---------------------------------------------------------------------------
// Kernel 2b: combine 8 K-split partials + tanh, layers 1-2, per-block energy
// partial. grid = 512 blocks x 8 atoms; block 256. W1 staged in LDS.
// ---------------------------------------------------------------------------
__global__ __launch_bounds__(256, 4) void k_fit1(
    const float* __restrict__ P,
    const float* __restrict__ fb0, const float* __restrict__ fW1,
    const float* __restrict__ fb1, const float* __restrict__ fW2,
    const float* __restrict__ fb2, const float* __restrict__ Ebias,
    float* __restrict__ BP)
{
  __shared__ float ht[128][12];
  __shared__ float Ws1[32][128];
  __shared__ float red[8][33];
  const int tid = threadIdx.x;
  const int abase = blockIdx.x * 8;
  const int t = (abase >= HALF_N) ? 1 : 0;

  {
    const int a = tid >> 5, j0 = (tid & 31) * 4;
    f4 s = *(const f4*)&fb0[t * 128 + j0];
#pragma unroll
    for (int ks = 0; ks < 8; ++ks)
      s += *(const f4*)&P[((size_t)ks * 4096 + abase + a) * 128 + j0];
    ht[j0 + 0][a] = fast_tanh(s.x);
    ht[j0 + 1][a] = fast_tanh(s.y);
    ht[j0 + 2][a] = fast_tanh(s.z);
    ht[j0 + 3][a] = fast_tanh(s.w);
  }

  const int ab = tid & 7, jb = tid >> 3;
  const int j0g = jb * 4;
  f4 acc = *(const f4*)&fb1[t * 128 + j0g];
  for (int kc = 0; kc < 4; ++kc) {
    __syncthreads();
#pragma unroll
    for (int u = 0; u < 2; ++u) {
      int idx = (u * 256 + tid) * 8;
      int kk = idx >> 7, j = idx & 127;
      *(f4*)&Ws1[kk][j] =
          *(const f4*)&fW1[(size_t)t * 16384 + (size_t)(kc * 32 + kk) * 128 + j];
      *(f4*)&Ws1[kk][j + 4] =
          *(const f4*)&fW1[(size_t)t * 16384 + (size_t)(kc * 32 + kk) * 128 + j + 4];
    }
    __syncthreads();
    for (int kk = 0; kk < 32; ++kk) {
      float av = ht[kc * 32 + kk][ab];
      f4 w = *(const f4*)&Ws1[kk][j0g];
      acc += av * w;
    }
  }

  float f = fast_tanh(acc.x) * fW2[t * 128 + j0g + 0]
          + fast_tanh(acc.y) * fW2[t * 128 + j0g + 1]
          + fast_tanh(acc.z) * fW2[t * 128 + j0g + 2]
          + fast_tanh(acc.w) * fW2[t * 128 + j0g + 3];
  red[ab][jb] = f;
  __syncthreads();
  if (tid < 64) {
    const int a = tid & 7, j4 = tid >> 3;
    float v = red[a][j4 * 4] + red[a][j4 * 4 + 1]
            + red[a][j4 * 4 + 2] + red[a][j4 * 4 + 3];
    v += __shfl_xor(v, 32);
    v += __shfl_xor(v, 16);
    v += __shfl_xor(v, 8);
    v += __shfl_xor(v, 4);
    v += __shfl_xor(v, 2);
    v += __shfl_xor(v, 1);
    if (tid == 0) BP[blockIdx.x] = v + 8.0f * (fb2[t] + Ebias[t]);
  }
}

__global__ __launch_bounds__(64) void k_reduce(const float* __restrict__ BP,
                                               float* __restrict__ out)
{
  int tid = threadIdx.x;
  float s = 0.0f;
#pragma unroll
  for (int u = 0; u < 8; ++u) s += BP[tid + 64 * u];
  s += __shfl_xor(s, 32);
  s += __shfl_xor(s, 16);
  s += __shfl_xor(s, 8);
  s += __shfl_xor(s, 4);
  s += __shfl_xor(s, 2);
  s += __shfl_xor(s, 1);
  if (tid == 0) out[0] = s;
}

extern "C" void kernel_launch(void* const* d_in, const int* in_sizes, int n_in,
                              void* d_out, int out_size, void* d_ws, size_t ws_size,
                              hipStream_t stream) {
  const float* coord = (const float*)d_in[0];
  const float* box   = (const float*)d_in[1];
  const int*   nbrs  = (const int*)d_in[2];
  const float* eW0   = (const float*)d_in[3];
  const float* eb0   = (const float*)d_in[4];
  const float* eW1   = (const float*)d_in[5];
  const float* eb1   = (const float*)d_in[6];
  const float* eW2   = (const float*)d_in[7];
  const float* eb2   = (const float*)d_in[8];
  const float* Tbias = (const float*)d_in[9];
  const float* fW0   = (const float*)d_in[10];
  const float* fb0   = (const float*)d_in[11];
  const float* fW1   = (const float*)d_in[12];
  const float* fb1   = (const float*)d_in[13];
  const float* fW2   = (const float*)d_in[14];
  const float* fb2   = (const float*)d_in[15];
  const float* Ebias = (const float*)d_in[16];

  __hip_bfloat16* G = (__hip_bfloat16*)d_ws;                   // 8 MB
  float* P  = (float*)((char*)d_ws + (size_t)8 * 1024 * 1024); // 16 MB
  float* BP = (float*)d_ws;  // overlaid on G (G dead once fit0 completes)

  k_embed<<<2048, 256, 0, stream>>>(coord, box, nbrs, eW0, eb0, eW1, eb1,
                                    eW2, eb2, Tbias, G);
  k_fit0<<<256, 256, 0, stream>>>(G, fW0, P);
  k_fit1<<<512, 256, 0, stream>>>(P, fb0, fW1, fb1, fW2, fb2, Ebias, BP);
  k_reduce<<<1, 64, 0, stream>>>(BP, (float*)d_out);
}

// Round 5
// 77.204 us; speedup vs baseline: 2.0826x; 1.4286x over previous
//
#include <hip/hip_runtime.h>
#include <hip/hip_fp16.h>
#include <hip/hip_bf16.h>

typedef _Float16 h16;
typedef h16 v2h __attribute__((ext_vector_type(2)));
typedef h16 v8h __attribute__((ext_vector_type(8)));
typedef float f4 __attribute__((ext_vector_type(4)));

#define NATOM 4096
#define HALF_N 2048

__device__ __forceinline__ float rcp_fast(float x) {
#if __has_builtin(__builtin_amdgcn_rcpf)
  return __builtin_amdgcn_rcpf(x);
#else
  return 1.0f / x;
#endif
}

// tanh(x) = 1 - 2/(1+e^{2x}); inf-safe at both ends (exp->inf => 1, exp->0 => -1)
__device__ __forceinline__ float tanh2(float x) {
  float r = rcp_fast(1.0f + __expf(x + x));
  return fmaf(-2.0f, r, 1.0f);
}

__device__ __forceinline__ float hdot2(v2h a, v2h b, float c) {
#if __has_builtin(__builtin_amdgcn_fdot2)
  return __builtin_amdgcn_fdot2(a, b, c, false);
#else
  return c + (float)a.x * (float)b.x + (float)a.y * (float)b.y;
#endif
}

__device__ __forceinline__ v2h pk2h(float lo, float hi) {
  return __builtin_bit_cast(v2h, __builtin_amdgcn_cvt_pkrtz(lo, hi));
}

// ---------------------------------------------------------------------------
// Kernel 1: 256 threads = 4 waves = 4 atoms (wave wv owns atom blockIdx*4+wv).
// Per wave: lane L owns neighbors m=L and m=64+L (geometry/R/h0/h1 per-lane),
// then E = tanh(h1@W2+b2) and T = Rp@E on the MATRIX pipe:
//   E: 32x mfma_f32_16x16x32_f16 (A=h1 from LDS, B=W2 staged transposed)
//   D-frag -> B-frag relayout in-register: cvt_pkrtz + ds_bpermute + cndmask
//   T: 16x mfma accumulating over K=128; rows<10 -> T_lds -> G stage.
// No barriers after weight staging (per-atom LDS arrays are wave-private).
// ---------------------------------------------------------------------------
__global__ __launch_bounds__(256, 2) void k_embed(
    const float* __restrict__ coord, const float* __restrict__ box,
    const int* __restrict__ nbrs,
    const float* __restrict__ eW0, const float* __restrict__ eb0,
    const float* __restrict__ eW1, const float* __restrict__ eb1,
    const float* __restrict__ eW2, const float* __restrict__ eb2,
    const float* __restrict__ Tbias,
    __hip_bfloat16* __restrict__ Gout)
{
  __shared__ float sW0[2][16], sb0[2][16], sb1[2][32];
  __shared__ v2h   sW1p[2][8][32];                 // W1 as i-pairs
  __shared__ h16   W2t[2][64][40] __attribute__((aligned(16)));  // W2 transposed [c][j]
  __shared__ h16   h1s[4][128][40] __attribute__((aligned(16))); // per-atom h1 rows
  __shared__ h16   Rls[4][11][136] __attribute__((aligned(16))); // per-atom Rp (row 10 = 0)
  __shared__ float Tls[4][10][68];                 // per-atom T

  const int tid = threadIdx.x;
  const int wv = tid >> 6;
  const int lane = tid & 63;
  const int n = blockIdx.x * 4 + wv;
  const int ti = (n >= HALF_N) ? 1 : 0;
  const int c15 = lane & 15, g4 = lane >> 4;

  // ---- stage weights (block-shared; all 4 atoms share ti) ----
  for (int idx = tid; idx < 32; idx += 256) {
    int s = idx >> 4, i = idx & 15;
    sW0[s][i] = eW0[(ti * 2 + s) * 16 + i];
    sb0[s][i] = eb0[(ti * 2 + s) * 16 + i];
  }
  for (int idx = tid; idx < 64; idx += 256) {
    int s = idx >> 5, i = idx & 31;
    sb1[s][i] = eb1[(ti * 2 + s) * 32 + i];
  }
  for (int idx = tid; idx < 512; idx += 256) {
    int s = idx >> 8, r = idx & 255, ip = r >> 5, j = r & 31;
    const float* src = &eW1[(size_t)(ti * 2 + s) * 512];
    v2h p; p.x = (h16)src[(2 * ip) * 32 + j]; p.y = (h16)src[(2 * ip + 1) * 32 + j];
    sW1p[s][ip][j] = p;
  }
  for (int idx = tid; idx < 4096; idx += 256) {
    int s = idx >> 11, r = idx & 2047, j = r >> 6, cc = r & 63;
    W2t[s][cc][j] = (h16)eW2[(size_t)(ti * 2 + s) * 2048 + j * 64 + cc];
  }
  for (int col = lane; col < 136; col += 64) Rls[wv][10][col] = (h16)0.0f;
  __syncthreads();

  // ---- stage A: geometry + R (write fp16 to LDS) + srcn, 2 neighbors/lane ----
  float srcn[2];
  {
    const float bx = box[0], by = box[1], bz = box[2];
    const float cx = coord[n], cy = coord[NATOM + n], cz = coord[2 * NATOM + n];
#pragma unroll
    for (int nb = 0; nb < 2; ++nb) {
      const int m = nb * 64 + lane;
      const int j = nbrs[(size_t)n * 128 + m];
      float dx = coord[j] - cx;
      float dy = coord[NATOM + j] - cy;
      float dz = coord[2 * NATOM + j] - cz;
      dx -= bx * rintf(dx / bx);
      dy -= by * rintf(dy / by);
      dz -= bz * rintf(dz / bz);
      float r2 = dx * dx + dy * dy + dz * dz;
      bool mk = r2 > 1e-12f;
      float rs = sqrtf(mk ? r2 : 1.0f);
      float r  = mk ? rs : 0.0f;
      float sw = 0.5f * __cosf(0.52359878f * fminf(r, 6.0f)) + 0.5f;
      float invr = mk ? rcp_fast(rs) : 1.0f;
      float sr = (mk && r < 6.0f) ? sw * invr : 0.0f;
      float x0 = dx * invr, x1 = dy * invr, x2 = dz * invr;
      float srn = sr * 20.0f;
      srcn[nb] = (sr - 0.1f) * 20.0f;
      Rls[wv][0][m] = (h16)srn;
      Rls[wv][1][m] = (h16)(1.7320508f * srn * x0);
      Rls[wv][2][m] = (h16)(1.7320508f * srn * x1);
      Rls[wv][3][m] = (h16)(1.7320508f * srn * x2);
      Rls[wv][4][m] = (h16)(3.0f * srn * (x0 * x0 - 0.33333334f));
      Rls[wv][5][m] = (h16)(3.0f * srn * (x1 * x1 - 0.33333334f));
      Rls[wv][6][m] = (h16)(3.0f * srn * (x2 * x2 - 0.33333334f));
      Rls[wv][7][m] = (h16)(4.2426407f * srn * (x0 * x1));
      Rls[wv][8][m] = (h16)(4.2426407f * srn * (x1 * x2));
      Rls[wv][9][m] = (h16)(4.2426407f * srn * (x2 * x0));
    }
  }

  // ---- stage B: h0 (regs) -> h1 rows (fdot2), write fp16 rows to LDS ----
#pragma unroll
  for (int nb = 0; nb < 2; ++nb) {
    v2h h0p[8];
#pragma unroll
    for (int ip = 0; ip < 8; ++ip) {
      h16 plo = (h16)tanh2(srcn[nb] * sW0[nb][2 * ip]     + sb0[nb][2 * ip]);
      h16 phi = (h16)tanh2(srcn[nb] * sW0[nb][2 * ip + 1] + sb0[nb][2 * ip + 1]);
      v2h p; p.x = plo; p.y = phi;
      h0p[ip] = p;
    }
    float acc[32];
#pragma unroll
    for (int j = 0; j < 32; ++j) acc[j] = sb1[nb][j];
    union WU { v8h v; v2h p[4]; };
#pragma unroll
    for (int ip = 0; ip < 8; ++ip) {
#pragma unroll
      for (int rr = 0; rr < 8; ++rr) {
        WU w; w.v = *(const v8h*)&sW1p[nb][ip][rr * 4];
#pragma unroll
        for (int q = 0; q < 4; ++q)
          acc[rr * 4 + q] = hdot2(h0p[ip], w.p[q], acc[rr * 4 + q]);
      }
    }
    h16* row = &h1s[wv][nb * 64 + lane][0];
#pragma unroll
    for (int ch = 0; ch < 4; ++ch) {
      union { v8h v; v2h p[4]; } o;
#pragma unroll
      for (int q = 0; q < 4; ++q)
        o.p[q] = pk2h(tanh2(acc[ch * 8 + 2 * q]), tanh2(acc[ch * 8 + 2 * q + 1]));
      *(v8h*)&row[ch * 8] = o.v;
    }
  }

  // ---- stage C+D: E via MFMA, in-register relayout, T via MFMA ----
  v8h bw[2][4];
  float b2v[2][4];
#pragma unroll
  for (int s = 0; s < 2; ++s)
#pragma unroll
    for (int nt = 0; nt < 4; ++nt) {
      bw[s][nt] = *(const v8h*)&W2t[s][nt * 16 + c15][g4 * 8];
      b2v[s][nt] = eb2[(ti * 2 + s) * 64 + nt * 16 + c15];
    }

  const int addr0 = ((((lane >> 4) & 1) * 2) * 16 + c15) * 4;  // src lane*4, q<2
  const int addr1 = addr0 + 64;                                 // q>=2 (+16 lanes)
  const bool hi = lane >= 32;                                   // upper half reads tile 2ks+1

  f4 tac[4];
#pragma unroll
  for (int nt = 0; nt < 4; ++nt) tac[nt] = (f4){0.f, 0.f, 0.f, 0.f};

  const int rrow = (c15 < 10) ? c15 : 10;  // rows 10-15 read the zero row
#pragma unroll
  for (int ks = 0; ks < 4; ++ks) {
    const int slot = ks >> 1;
    v8h a0 = *(const v8h*)&h1s[wv][(2 * ks) * 16 + c15][g4 * 8];
    v8h a1 = *(const v8h*)&h1s[wv][(2 * ks + 1) * 16 + c15][g4 * 8];
    v8h ra = *(const v8h*)&Rls[wv][rrow][32 * ks + g4 * 8];
#pragma unroll
    for (int nt = 0; nt < 4; ++nt) {
      f4 cb = (f4){b2v[slot][nt], b2v[slot][nt], b2v[slot][nt], b2v[slot][nt]};
      f4 e0 = __builtin_amdgcn_mfma_f32_16x16x32_f16(a0, bw[slot][nt], cb, 0, 0, 0);
      f4 e1 = __builtin_amdgcn_mfma_f32_16x16x32_f16(a1, bw[slot][nt], cb, 0, 0, 0);
      int w0a = __builtin_bit_cast(int, pk2h(tanh2(e0[0]), tanh2(e0[1])));
      int w1a = __builtin_bit_cast(int, pk2h(tanh2(e0[2]), tanh2(e0[3])));
      int w0b = __builtin_bit_cast(int, pk2h(tanh2(e1[0]), tanh2(e1[1])));
      int w1b = __builtin_bit_cast(int, pk2h(tanh2(e1[2]), tanh2(e1[3])));
      int pA0 = __builtin_amdgcn_ds_bpermute(addr0, w0a);
      int pB0 = __builtin_amdgcn_ds_bpermute(addr0, w0b);
      int pA1 = __builtin_amdgcn_ds_bpermute(addr0, w1a);
      int pB1 = __builtin_amdgcn_ds_bpermute(addr0, w1b);
      int pA2 = __builtin_amdgcn_ds_bpermute(addr1, w0a);
      int pB2 = __builtin_amdgcn_ds_bpermute(addr1, w0b);
      int pA3 = __builtin_amdgcn_ds_bpermute(addr1, w1a);
      int pB3 = __builtin_amdgcn_ds_bpermute(addr1, w1b);
      union { int u[4]; v8h v; } bf;
      bf.u[0] = hi ? pB0 : pA0;
      bf.u[1] = hi ? pB1 : pA1;
      bf.u[2] = hi ? pB2 : pA2;
      bf.u[3] = hi ? pB3 : pA3;
      tac[nt] = __builtin_amdgcn_mfma_f32_16x16x32_f16(ra, bf.v, tac[nt], 0, 0, 0);
    }
  }

  // ---- store T rows < 10 (with /NORM) ----
#pragma unroll
  for (int nt = 0; nt < 4; ++nt)
#pragma unroll
    for (int r = 0; r < 4; ++r) {
      int x = g4 * 4 + r;
      if (x < 10) Tls[wv][x][nt * 16 + c15] = tac[nt][r] * 0.05f;
    }

  // ---- stage G: tensor algebra + store Gflat as bf16 (lane = channel c) ----
  {
    const int c = lane;
    const float tnc  = Tls[wv][0][c] + Tbias[c];
    const float t3c0 = Tls[wv][1][c], t3c1 = Tls[wv][2][c], t3c2 = Tls[wv][3][c];
    const float t6c0 = Tls[wv][4][c], t6c1 = Tls[wv][5][c], t6c2 = Tls[wv][6][c];
    const float t6c3 = Tls[wv][7][c], t6c4 = Tls[wv][8][c], t6c5 = Tls[wv][9][c];
    __hip_bfloat16* gp = Gout + (size_t)n * 1024;
#pragma unroll
    for (int a = 0; a < 16; ++a) {
      float g = tnc * (Tls[wv][0][a] + Tbias[a]);
      g += t3c0 * Tls[wv][1][a] + t3c1 * Tls[wv][2][a] + t3c2 * Tls[wv][3][a];
      const float g1x = Tls[wv][1][16 + a], g1y = Tls[wv][2][16 + a], g1z = Tls[wv][3][16 + a];
      g += (g1x * g1x + Tls[wv][4][16 + a]) * t6c0;
      g += (g1y * g1y + Tls[wv][5][16 + a]) * t6c1;
      g += (g1z * g1z + Tls[wv][6][16 + a]) * t6c2;
      g += (1.4142135f * g1x * g1y + Tls[wv][7][16 + a]) * t6c3;
      g += (1.4142135f * g1y * g1z + Tls[wv][8][16 + a]) * t6c4;
      g += (1.4142135f * g1z * g1x + Tls[wv][9][16 + a]) * t6c5;
      gp[a * 64 + c] = __float2bfloat16(g);
    }
  }
}

// ---------------------------------------------------------------------------
// Kernel 2a: fit layer-0 partial GEMM. grid = 32 atom-tiles(128) x 8 ksplit.
// block 256, thread tile 8a x 8j. W staged in LDS.
// ---------------------------------------------------------------------------
__global__ __launch_bounds__(256, 2) void k_fit0(
    const __hip_bfloat16* __restrict__ G,
    const float* __restrict__ fW0, float* __restrict__ P)
{
  __shared__ float At[32][132];
  __shared__ float Ws[32][128];
  const int tid = threadIdx.x;
  const int tile = blockIdx.x >> 3;
  const int ks = blockIdx.x & 7;
  const int abase = tile * 128;
  const int kbase = ks * 128;
  const int t = (abase >= HALF_N) ? 1 : 0;
  const int ab = tid & 15, jb = tid >> 4;
  const int a0 = ab * 8, j0 = jb * 8;

  float acc[8][8];
#pragma unroll
  for (int p = 0; p < 8; ++p)
#pragma unroll
    for (int q = 0; q < 8; ++q) acc[p][q] = 0.0f;

  for (int kc = 0; kc < 4; ++kc) {
    const int kb = kbase + kc * 32;
    __syncthreads();
    {
      const int a = tid >> 1, k0 = (tid & 1) * 16;
      const ushort* gs = (const ushort*)G + (size_t)(abase + a) * 1024 + kb + k0;
      uint4 v0 = *(const uint4*)gs;
      uint4 v1 = *(const uint4*)(gs + 8);
      union { uint4 u; ushort s[8]; } b0, b1;
      b0.u = v0; b1.u = v1;
#pragma unroll
      for (int q = 0; q < 8; ++q) {
        At[k0 + q][a]     = __builtin_bit_cast(float, (uint)b0.s[q] << 16);
        At[k0 + 8 + q][a] = __builtin_bit_cast(float, (uint)b1.s[q] << 16);
      }
    }
#pragma unroll
    for (int u = 0; u < 4; ++u) {
      int idx = (u * 256 + tid) * 4;
      int kk = idx >> 7, j = idx & 127;
      *(f4*)&Ws[kk][j] =
          *(const f4*)&fW0[(size_t)t * 131072 + (size_t)(kb + kk) * 128 + j];
    }
    __syncthreads();
    for (int kk = 0; kk < 32; ++kk) {
      f4 aLo = *(const f4*)&At[kk][a0];
      f4 aHi = *(const f4*)&At[kk][a0 + 4];
      f4 wLo = *(const f4*)&Ws[kk][j0];
      f4 wHi = *(const f4*)&Ws[kk][j0 + 4];
      float av[8] = {aLo.x, aLo.y, aLo.z, aLo.w, aHi.x, aHi.y, aHi.z, aHi.w};
      float wf[8] = {wLo.x, wLo.y, wLo.z, wLo.w, wHi.x, wHi.y, wHi.z, wHi.w};
#pragma unroll
      for (int p = 0; p < 8; ++p)
#pragma unroll
        for (int q = 0; q < 8; ++q) acc[p][q] += av[p] * wf[q];
    }
  }

#pragma unroll
  for (int p = 0; p < 8; ++p) {
    f4 lo = {acc[p][0], acc[p][1], acc[p][2], acc[p][3]};
    f4 hi = {acc[p][4], acc[p][5], acc[p][6], acc[p][7]};
    float* o = P + ((size_t)ks * 4096 + abase + a0 + p) * 128 + j0;
    *(f4*)o = lo;
    *(f4*)(o + 4) = hi;
  }
}

// ---------------------------------------------------------------------------
// Kernel 2b: combine 8 K-split partials + tanh, layers 1-2, per-block energy
// partial. grid = 512 blocks x 8 atoms; block 256. W1 staged in LDS.
// ---------------------------------------------------------------------------
__global__ __launch_bounds__(256, 4) void k_fit1(
    const float* __restrict__ P,
    const float* __restrict__ fb0, const float* __restrict__ fW1,
    const float* __restrict__ fb1, const float* __restrict__ fW2,
    const float* __restrict__ fb2, const float* __restrict__ Ebias,
    float* __restrict__ BP)
{
  __shared__ float ht[128][12];
  __shared__ float Ws1[32][128];
  __shared__ float red[8][33];
  const int tid = threadIdx.x;
  const int abase = blockIdx.x * 8;
  const int t = (abase >= HALF_N) ? 1 : 0;

  {
    const int a = tid >> 5, j0 = (tid & 31) * 4;
    f4 s = *(const f4*)&fb0[t * 128 + j0];
#pragma unroll
    for (int ks = 0; ks < 8; ++ks)
      s += *(const f4*)&P[((size_t)ks * 4096 + abase + a) * 128 + j0];
    ht[j0 + 0][a] = tanh2(s.x);
    ht[j0 + 1][a] = tanh2(s.y);
    ht[j0 + 2][a] = tanh2(s.z);
    ht[j0 + 3][a] = tanh2(s.w);
  }

  const int ab = tid & 7, jb = tid >> 3;
  const int j0g = jb * 4;
  f4 acc = *(const f4*)&fb1[t * 128 + j0g];
  for (int kc = 0; kc < 4; ++kc) {
    __syncthreads();
#pragma unroll
    for (int u = 0; u < 2; ++u) {
      int idx = (u * 256 + tid) * 8;
      int kk = idx >> 7, j = idx & 127;
      *(f4*)&Ws1[kk][j] =
          *(const f4*)&fW1[(size_t)t * 16384 + (size_t)(kc * 32 + kk) * 128 + j];
      *(f4*)&Ws1[kk][j + 4] =
          *(const f4*)&fW1[(size_t)t * 16384 + (size_t)(kc * 32 + kk) * 128 + j + 4];
    }
    __syncthreads();
    for (int kk = 0; kk < 32; ++kk) {
      float av = ht[kc * 32 + kk][ab];
      f4 w = *(const f4*)&Ws1[kk][j0g];
      acc += av * w;
    }
  }

  float f = tanh2(acc.x) * fW2[t * 128 + j0g + 0]
          + tanh2(acc.y) * fW2[t * 128 + j0g + 1]
          + tanh2(acc.z) * fW2[t * 128 + j0g + 2]
          + tanh2(acc.w) * fW2[t * 128 + j0g + 3];
  red[ab][jb] = f;
  __syncthreads();
  if (tid < 64) {
    const int a = tid & 7, j4 = tid >> 3;
    float v = red[a][j4 * 4] + red[a][j4 * 4 + 1]
            + red[a][j4 * 4 + 2] + red[a][j4 * 4 + 3];
    v += __shfl_xor(v, 32);
    v += __shfl_xor(v, 16);
    v += __shfl_xor(v, 8);
    v += __shfl_xor(v, 4);
    v += __shfl_xor(v, 2);
    v += __shfl_xor(v, 1);
    if (tid == 0) BP[blockIdx.x] = v + 8.0f * (fb2[t] + Ebias[t]);
  }
}

__global__ __launch_bounds__(64) void k_reduce(const float* __restrict__ BP,
                                               float* __restrict__ out)
{
  int tid = threadIdx.x;
  float s = 0.0f;
#pragma unroll
  for (int u = 0; u < 8; ++u) s += BP[tid + 64 * u];
  s += __shfl_xor(s, 32);
  s += __shfl_xor(s, 16);
  s += __shfl_xor(s, 8);
  s += __shfl_xor(s, 4);
  s += __shfl_xor(s, 2);
  s += __shfl_xor(s, 1);
  if (tid == 0) out[0] = s;
}

extern "C" void kernel_launch(void* const* d_in, const int* in_sizes, int n_in,
                              void* d_out, int out_size, void* d_ws, size_t ws_size,
                              hipStream_t stream) {
  const float* coord = (const float*)d_in[0];
  const float* box   = (const float*)d_in[1];
  const int*   nbrs  = (const int*)d_in[2];
  const float* eW0   = (const float*)d_in[3];
  const float* eb0   = (const float*)d_in[4];
  const float* eW1   = (const float*)d_in[5];
  const float* eb1   = (const float*)d_in[6];
  const float* eW2   = (const float*)d_in[7];
  const float* eb2   = (const float*)d_in[8];
  const float* Tbias = (const float*)d_in[9];
  const float* fW0   = (const float*)d_in[10];
  const float* fb0   = (const float*)d_in[11];
  const float* fW1   = (const float*)d_in[12];
  const float* fb1   = (const float*)d_in[13];
  const float* fW2   = (const float*)d_in[14];
  const float* fb2   = (const float*)d_in[15];
  const float* Ebias = (const float*)d_in[16];

  __hip_bfloat16* G = (__hip_bfloat16*)d_ws;                   // 8 MB
  float* P  = (float*)((char*)d_ws + (size_t)8 * 1024 * 1024); // 16 MB
  float* BP = (float*)d_ws;  // overlaid on G (G dead once fit0 completes)

  k_embed<<<1024, 256, 0, stream>>>(coord, box, nbrs, eW0, eb0, eW1, eb1,
                                    eW2, eb2, Tbias, G);
  k_fit0<<<256, 256, 0, stream>>>(G, fW0, P);
  k_fit1<<<512, 256, 0, stream>>>(P, fb0, fW1, fb1, fW2, fb2, Ebias, BP);
  k_reduce<<<1, 64, 0, stream>>>(BP, (float*)d_out);
}

// Round 6
// 60.900 us; speedup vs baseline: 2.6402x; 1.2677x over previous
//
#include <hip/hip_runtime.h>
#include <hip/hip_fp16.h>

typedef _Float16 h16;
typedef h16 v2h __attribute__((ext_vector_type(2)));
typedef h16 v8h __attribute__((ext_vector_type(8)));
typedef float f4 __attribute__((ext_vector_type(4)));

#define NATOM 4096
#define HALF_N 2048
#define K2 2.885390081777927f      // 2/ln2: tanh(x) = 1 - 2/(1+exp2(K2*x))
#define GSCL 0.015625f             // G stored as fp16 * 1/64
#define W0SCL (64.0f * K2)         // W0t staged as fp16 * 64 * K2

__device__ __forceinline__ float rcp_fast(float x) {
#if __has_builtin(__builtin_amdgcn_rcpf)
  return __builtin_amdgcn_rcpf(x);
#else
  return 1.0f / x;
#endif
}

__device__ __forceinline__ float exp2_fast(float x) {
#if __has_builtin(__builtin_amdgcn_exp2f)
  return __builtin_amdgcn_exp2f(x);
#else
  return exp2f(x);
#endif
}

// input d is already pre-scaled by K2=2/ln2: returns tanh(d/K2)
__device__ __forceinline__ float tanh_e2(float d) {
  float r = rcp_fast(1.0f + exp2_fast(d));
  return fmaf(-2.0f, r, 1.0f);
}

__device__ __forceinline__ float hdot2(v2h a, v2h b, float c) {
#if __has_builtin(__builtin_amdgcn_fdot2)
  return __builtin_amdgcn_fdot2(a, b, c, false);
#else
  return c + (float)a.x * (float)b.x + (float)a.y * (float)b.y;
#endif
}

__device__ __forceinline__ v2h pk2h(float lo, float hi) {
  return __builtin_bit_cast(v2h, __builtin_amdgcn_cvt_pkrtz(lo, hi));
}

__device__ __forceinline__ v8h lds_v8h(const h16* base, int byte) {
  return *(const v8h*)((const char*)base + byte);
}

// ---------------------------------------------------------------------------
// Kernel 1: 256 thr = 4 waves = 4 atoms. 2-phase h1 buffer (rows 0-63 then
// 64-127 reuse the same 5KB/atom LDS), all tanh in 4-op exp2 form (weights
// pre-scaled by 2/ln2 at staging), E and T on the matrix pipe. LDS 51.1 KB
// -> 3 blocks/CU.
// ---------------------------------------------------------------------------
__global__ __launch_bounds__(256, 3) void k_embed(
    const float* __restrict__ coord, const float* __restrict__ box,
    const int* __restrict__ nbrs,
    const float* __restrict__ eW0, const float* __restrict__ eb0,
    const float* __restrict__ eW1, const float* __restrict__ eb1,
    const float* __restrict__ eW2, const float* __restrict__ eb2,
    const float* __restrict__ Tbias,
    h16* __restrict__ Gout)
{
  __shared__ float sW0[2][16], sb0[2][16], sb1[2][32];
  __shared__ v2h   sW1p[2][8][32];                                   // 2 KB
  __shared__ h16   W2t[2][4][64][8] __attribute__((aligned(16)));    // 8 KB
  __shared__ h16   h1s[4][64][40] __attribute__((aligned(16)));      // 20 KB
  __shared__ h16   Rls[4][10][136] __attribute__((aligned(16)));     // 10.6 KB
  __shared__ float Tls[4][10][64];                                   // 10 KB

  const int tid = threadIdx.x;
  const int wv = tid >> 6;
  const int lane = tid & 63;
  const int n = blockIdx.x * 4 + wv;
  const int ti = (n >= HALF_N) ? 1 : 0;
  const int c15 = lane & 15, g4 = lane >> 4;

  // ---- stage weights, all pre-scaled by K2 ----
  for (int idx = tid; idx < 32; idx += 256) {
    int s = idx >> 4, i = idx & 15;
    sW0[s][i] = K2 * eW0[(ti * 2 + s) * 16 + i];
    sb0[s][i] = K2 * eb0[(ti * 2 + s) * 16 + i];
  }
  for (int idx = tid; idx < 64; idx += 256) {
    int s = idx >> 5, i = idx & 31;
    sb1[s][i] = K2 * eb1[(ti * 2 + s) * 32 + i];
  }
  for (int idx = tid; idx < 512; idx += 256) {
    int s = idx >> 8, r = idx & 255, ip = r >> 5, j = r & 31;
    const float* src = &eW1[(size_t)(ti * 2 + s) * 512];
    v2h p;
    p.x = (h16)(K2 * src[(2 * ip) * 32 + j]);
    p.y = (h16)(K2 * src[(2 * ip + 1) * 32 + j]);
    sW1p[s][ip][j] = p;
  }
  for (int idx = tid; idx < 4096; idx += 256) {
    int cc = idx & 63, j = (idx >> 6) & 7, g = (idx >> 9) & 3, s = idx >> 11;
    W2t[s][g][cc][j] = (h16)(K2 * eW2[(size_t)(ti * 2 + s) * 2048 + (g * 8 + j) * 64 + cc]);
  }

  // hoisted globals
  float b2v[2][4];
#pragma unroll
  for (int s = 0; s < 2; ++s)
#pragma unroll
    for (int nt = 0; nt < 4; ++nt)
      b2v[s][nt] = K2 * eb2[(ti * 2 + s) * 64 + nt * 16 + c15];
  __syncthreads();

  v8h bw[2][4];
#pragma unroll
  for (int s = 0; s < 2; ++s)
#pragma unroll
    for (int nt = 0; nt < 4; ++nt)
      bw[s][nt] = *(const v8h*)&W2t[s][g4][nt * 16 + c15][0];

  // ---- stage A: geometry + R rows (fp16 LDS) + srcn, 2 neighbors/lane ----
  float srcn_[2];
  {
    const float bx = box[0], by = box[1], bz = box[2];
    const float rbx = rcp_fast(bx), rby = rcp_fast(by), rbz = rcp_fast(bz);
    const float cx = coord[n], cy = coord[NATOM + n], cz = coord[2 * NATOM + n];
#pragma unroll
    for (int nb = 0; nb < 2; ++nb) {
      const int m = nb * 64 + lane;
      const int j = nbrs[(size_t)n * 128 + m];
      float dx = coord[j] - cx;
      float dy = coord[NATOM + j] - cy;
      float dz = coord[2 * NATOM + j] - cz;
      dx -= bx * rintf(dx * rbx);
      dy -= by * rintf(dy * rby);
      dz -= bz * rintf(dz * rbz);
      float r2 = dx * dx + dy * dy + dz * dz;
      bool mk = r2 > 1e-12f;
      float rs = sqrtf(mk ? r2 : 1.0f);
      float r  = mk ? rs : 0.0f;
      float sw = 0.5f * __cosf(0.52359878f * fminf(r, 6.0f)) + 0.5f;
      float invr = mk ? rcp_fast(rs) : 1.0f;
      float sr = (mk && r < 6.0f) ? sw * invr : 0.0f;
      float x0 = dx * invr, x1 = dy * invr, x2 = dz * invr;
      float srn = sr * 20.0f;
      srcn_[nb] = (sr - 0.1f) * 20.0f;
      Rls[wv][0][m] = (h16)srn;
      Rls[wv][1][m] = (h16)(1.7320508f * srn * x0);
      Rls[wv][2][m] = (h16)(1.7320508f * srn * x1);
      Rls[wv][3][m] = (h16)(1.7320508f * srn * x2);
      Rls[wv][4][m] = (h16)(3.0f * srn * (x0 * x0 - 0.33333334f));
      Rls[wv][5][m] = (h16)(3.0f * srn * (x1 * x1 - 0.33333334f));
      Rls[wv][6][m] = (h16)(3.0f * srn * (x2 * x2 - 0.33333334f));
      Rls[wv][7][m] = (h16)(4.2426407f * srn * (x0 * x1));
      Rls[wv][8][m] = (h16)(4.2426407f * srn * (x1 * x2));
      Rls[wv][9][m] = (h16)(4.2426407f * srn * (x2 * x0));
    }
  }

  const int addr0 = (((lane >> 4) & 1) * 32 + c15) * 4;  // bpermute src, q<2
  const int addr1 = addr0 + 64;                           // q>=2
  const bool hi = lane >= 32;
  const int rrow = (c15 < 10) ? c15 : 9;
  const v8h rzero = {};

  f4 tac[4];
#pragma unroll
  for (int nt = 0; nt < 4; ++nt) tac[nt] = (f4){0.f, 0.f, 0.f, 0.f};

  // ================= 2-phase: stage B (h1) then 2 E/T k-steps ==============
#pragma unroll
  for (int ph = 0; ph < 2; ++ph) {
    // ---- stage B: lane computes h1[row lane] of this 64-row half ----
    {
      v2h h0p[8];
#pragma unroll
      for (int ip = 0; ip < 8; ++ip) {
        h16 plo = (h16)tanh_e2(fmaf(srcn_[ph], sW0[ph][2 * ip],     sb0[ph][2 * ip]));
        h16 phi = (h16)tanh_e2(fmaf(srcn_[ph], sW0[ph][2 * ip + 1], sb0[ph][2 * ip + 1]));
        v2h p; p.x = plo; p.y = phi;
        h0p[ip] = p;
      }
      float acc[32];
#pragma unroll
      for (int j = 0; j < 32; ++j) acc[j] = sb1[ph][j];
      union WU { v8h v; v2h p[4]; };
#pragma unroll
      for (int ip = 0; ip < 8; ++ip) {
#pragma unroll
        for (int rr = 0; rr < 8; ++rr) {
          WU w; w.v = *(const v8h*)&sW1p[ph][ip][rr * 4];
#pragma unroll
          for (int q = 0; q < 4; ++q)
            acc[rr * 4 + q] = hdot2(h0p[ip], w.p[q], acc[rr * 4 + q]);
        }
      }
      h16* row = &h1s[wv][lane][0];
#pragma unroll
      for (int ch = 0; ch < 4; ++ch) {
        union { v8h v; v2h p[4]; } o;
#pragma unroll
        for (int q = 0; q < 4; ++q)
          o.p[q] = pk2h(tanh_e2(acc[ch * 8 + 2 * q]), tanh_e2(acc[ch * 8 + 2 * q + 1]));
        *(v8h*)&row[ch * 8] = o.v;
      }
    }

    // ---- E = tanh(h1@W2+b2) via MFMA, relayout, T += Rp@E via MFMA ----
#pragma unroll
    for (int kl = 0; kl < 2; ++kl) {
      const int ks = ph * 2 + kl;
      v8h a0 = *(const v8h*)&h1s[wv][kl * 32 + c15][g4 * 8];
      v8h a1 = *(const v8h*)&h1s[wv][kl * 32 + 16 + c15][g4 * 8];
      v8h ra = *(const v8h*)&Rls[wv][rrow][32 * ks + g4 * 8];
      if (c15 >= 10) ra = rzero;
#pragma unroll
      for (int nt = 0; nt < 4; ++nt) {
        f4 cb = (f4){b2v[ph][nt], b2v[ph][nt], b2v[ph][nt], b2v[ph][nt]};
        f4 e0 = __builtin_amdgcn_mfma_f32_16x16x32_f16(a0, bw[ph][nt], cb, 0, 0, 0);
        f4 e1 = __builtin_amdgcn_mfma_f32_16x16x32_f16(a1, bw[ph][nt], cb, 0, 0, 0);
        int w0a = __builtin_bit_cast(int, pk2h(tanh_e2(e0[0]), tanh_e2(e0[1])));
        int w1a = __builtin_bit_cast(int, pk2h(tanh_e2(e0[2]), tanh_e2(e0[3])));
        int w0b = __builtin_bit_cast(int, pk2h(tanh_e2(e1[0]), tanh_e2(e1[1])));
        int w1b = __builtin_bit_cast(int, pk2h(tanh_e2(e1[2]), tanh_e2(e1[3])));
        int pA0 = __builtin_amdgcn_ds_bpermute(addr0, w0a);
        int pB0 = __builtin_amdgcn_ds_bpermute(addr0, w0b);
        int pA1 = __builtin_amdgcn_ds_bpermute(addr0, w1a);
        int pB1 = __builtin_amdgcn_ds_bpermute(addr0, w1b);
        int pA2 = __builtin_amdgcn_ds_bpermute(addr1, w0a);
        int pB2 = __builtin_amdgcn_ds_bpermute(addr1, w0b);
        int pA3 = __builtin_amdgcn_ds_bpermute(addr1, w1a);
        int pB3 = __builtin_amdgcn_ds_bpermute(addr1, w1b);
        union { int u[4]; v8h v; } bf;
        bf.u[0] = hi ? pB0 : pA0;
        bf.u[1] = hi ? pB1 : pA1;
        bf.u[2] = hi ? pB2 : pA2;
        bf.u[3] = hi ? pB3 : pA3;
        tac[nt] = __builtin_amdgcn_mfma_f32_16x16x32_f16(ra, bf.v, tac[nt], 0, 0, 0);
      }
    }
  }

  // ---- store T rows < 10 (with /NORM) ----
#pragma unroll
  for (int nt = 0; nt < 4; ++nt)
#pragma unroll
    for (int r = 0; r < 4; ++r) {
      int x = g4 * 4 + r;
      if (x < 10) Tls[wv][x][nt * 16 + c15] = tac[nt][r] * 0.05f;
    }

  // ---- stage G: tensor algebra + store Gflat as fp16/64 ----
  {
    const int c = lane;
    const float tnc  = Tls[wv][0][c] + Tbias[c];
    const float t3c0 = Tls[wv][1][c], t3c1 = Tls[wv][2][c], t3c2 = Tls[wv][3][c];
    const float t6c0 = Tls[wv][4][c], t6c1 = Tls[wv][5][c], t6c2 = Tls[wv][6][c];
    const float t6c3 = Tls[wv][7][c], t6c4 = Tls[wv][8][c], t6c5 = Tls[wv][9][c];
    h16* gp = Gout + (size_t)n * 1024;
#pragma unroll
    for (int a = 0; a < 16; ++a) {
      float g = tnc * (Tls[wv][0][a] + Tbias[a]);
      g += t3c0 * Tls[wv][1][a] + t3c1 * Tls[wv][2][a] + t3c2 * Tls[wv][3][a];
      const float g1x = Tls[wv][1][16 + a], g1y = Tls[wv][2][16 + a], g1z = Tls[wv][3][16 + a];
      g += (g1x * g1x + Tls[wv][4][16 + a]) * t6c0;
      g += (g1y * g1y + Tls[wv][5][16 + a]) * t6c1;
      g += (g1z * g1z + Tls[wv][6][16 + a]) * t6c2;
      g += (1.4142135f * g1x * g1y + Tls[wv][7][16 + a]) * t6c3;
      g += (1.4142135f * g1y * g1z + Tls[wv][8][16 + a]) * t6c4;
      g += (1.4142135f * g1z * g1x + Tls[wv][9][16 + a]) * t6c5;
      gp[a * 64 + c] = (h16)(g * GSCL);
    }
  }
}

// ---------------------------------------------------------------------------
// Prep: W0t[t][n][k] = fW0[t][k][n] * 64 * K2 as fp16. grid 128 x 256.
// ---------------------------------------------------------------------------
__global__ __launch_bounds__(256) void k_prep(const float* __restrict__ fW0,
                                              h16* __restrict__ W0t)
{
  int idx = blockIdx.x * 256 + threadIdx.x;     // 0..32767
  int t = idx >> 14, n = idx & 127, k8 = (idx >> 7) & 127;
  union { v8h v; h16 e[8]; } o;
#pragma unroll
  for (int i = 0; i < 8; ++i)
    o.e[i] = (h16)(W0SCL * fW0[(size_t)t * 131072 + (size_t)(k8 * 8 + i) * 128 + n]);
  *(v8h*)&W0t[((size_t)t * 128 + n) * 1024 + k8 * 8] = o.v;
}

// ---------------------------------------------------------------------------
// Kernel 2a: fit layer-0 GEMM on MFMA. grid = 64 atom-tiles x 4 ksplit.
// A = G16 (fp16/64), B = W0t (fp16*64*K2) -> P = K2*(G@W0). XOR-swizzled LDS.
// ---------------------------------------------------------------------------
__global__ __launch_bounds__(256, 2) void k_fit0(
    const h16* __restrict__ G16, const h16* __restrict__ W0t,
    float* __restrict__ P)
{
  __shared__ h16 As[64][64]  __attribute__((aligned(16)));   // 8 KB, swizzled
  __shared__ h16 Bts[128][64] __attribute__((aligned(16)));  // 16 KB, swizzled
  const int tid = threadIdx.x;
  const int atile = blockIdx.x >> 2;
  const int ks = blockIdx.x & 3;
  const int abase = atile * 64;
  const int kbase = ks * 256;
  const int t = (abase >= HALF_N) ? 1 : 0;
  const int lane = tid & 63, w = tid >> 6;
  const int c15 = lane & 15, g4 = lane >> 4;

  f4 acc[8];
#pragma unroll
  for (int nt = 0; nt < 8; ++nt) acc[nt] = (f4){0.f, 0.f, 0.f, 0.f};

  for (int kc = 0; kc < 4; ++kc) {
    const int kb = kbase + kc * 64;
    __syncthreads();
#pragma unroll
    for (int u = 0; u < 2; ++u) {
      int idx = u * 256 + tid;                  // 0..511
      int r = idx >> 3, c8 = idx & 7;
      v8h v = *(const v8h*)&G16[(size_t)(abase + r) * 1024 + kb + c8 * 8];
      int byte = r * 128 + ((c8 * 16) ^ ((r & 7) << 4));
      *(v8h*)((char*)&As[0][0] + byte) = v;
    }
#pragma unroll
    for (int u = 0; u < 4; ++u) {
      int idx = u * 256 + tid;                  // 0..1023
      int nr = idx >> 3, c8 = idx & 7;
      v8h v = *(const v8h*)&W0t[((size_t)t * 128 + nr) * 1024 + kb + c8 * 8];
      int byte = nr * 128 + ((c8 * 16) ^ ((nr & 7) << 4));
      *(v8h*)((char*)&Bts[0][0] + byte) = v;
    }
    __syncthreads();
#pragma unroll
    for (int ksub = 0; ksub < 2; ++ksub) {
      const int ar = 16 * w + c15;
      const int koff = (ksub * 32 + g4 * 8) * 2;
      v8h a = lds_v8h(&As[0][0], ar * 128 + (koff ^ ((ar & 7) << 4)));
#pragma unroll
      for (int nt = 0; nt < 8; ++nt) {
        const int br = nt * 16 + c15;
        v8h b = lds_v8h(&Bts[0][0], br * 128 + (koff ^ ((br & 7) << 4)));
        acc[nt] = __builtin_amdgcn_mfma_f32_16x16x32_f16(a, b, acc[nt], 0, 0, 0);
      }
    }
  }

  float* Pk = P + (size_t)ks * 4096 * 128;
#pragma unroll
  for (int nt = 0; nt < 8; ++nt)
#pragma unroll
    for (int r = 0; r < 4; ++r)
      Pk[(size_t)(abase + 16 * w + g4 * 4 + r) * 128 + nt * 16 + c15] = acc[nt][r];
}

// ---------------------------------------------------------------------------
// Kernel 2b: combine 4 K-split partials (already K2-scaled) + layers 1-2 +
// per-block energy partial. grid = 512 x 8 atoms.
// ---------------------------------------------------------------------------
__global__ __launch_bounds__(256, 4) void k_fit1(
    const float* __restrict__ P,
    const float* __restrict__ fb0, const float* __restrict__ fW1,
    const float* __restrict__ fb1, const float* __restrict__ fW2,
    const float* __restrict__ fb2, const float* __restrict__ Ebias,
    float* __restrict__ BP)
{
  __shared__ float ht[128][12];
  __shared__ float Ws1[32][128];
  __shared__ float red[8][33];
  const int tid = threadIdx.x;
  const int abase = blockIdx.x * 8;
  const int t = (abase >= HALF_N) ? 1 : 0;

  {
    const int a = tid >> 5, j0 = (tid & 31) * 4;
    f4 s = K2 * (*(const f4*)&fb0[t * 128 + j0]);
#pragma unroll
    for (int ks = 0; ks < 4; ++ks)
      s += *(const f4*)&P[((size_t)ks * 4096 + abase + a) * 128 + j0];
    ht[j0 + 0][a] = tanh_e2(s.x);
    ht[j0 + 1][a] = tanh_e2(s.y);
    ht[j0 + 2][a] = tanh_e2(s.z);
    ht[j0 + 3][a] = tanh_e2(s.w);
  }

  const int ab = tid & 7, jb = tid >> 3;
  const int j0g = jb * 4;
  f4 acc = K2 * (*(const f4*)&fb1[t * 128 + j0g]);
  for (int kc = 0; kc < 4; ++kc) {
    __syncthreads();
#pragma unroll
    for (int u = 0; u < 2; ++u) {
      int idx = (u * 256 + tid) * 8;
      int kk = idx >> 7, j = idx & 127;
      *(f4*)&Ws1[kk][j] =
          K2 * (*(const f4*)&fW1[(size_t)t * 16384 + (size_t)(kc * 32 + kk) * 128 + j]);
      *(f4*)&Ws1[kk][j + 4] =
          K2 * (*(const f4*)&fW1[(size_t)t * 16384 + (size_t)(kc * 32 + kk) * 128 + j + 4]);
    }
    __syncthreads();
    for (int kk = 0; kk < 32; ++kk) {
      float av = ht[kc * 32 + kk][ab];
      f4 w = *(const f4*)&Ws1[kk][j0g];
      acc += av * w;
    }
  }

  float f = tanh_e2(acc.x) * fW2[t * 128 + j0g + 0]
          + tanh_e2(acc.y) * fW2[t * 128 + j0g + 1]
          + tanh_e2(acc.z) * fW2[t * 128 + j0g + 2]
          + tanh_e2(acc.w) * fW2[t * 128 + j0g + 3];
  red[ab][jb] = f;
  __syncthreads();
  if (tid < 64) {
    const int a = tid & 7, j4 = tid >> 3;
    float v = red[a][j4 * 4] + red[a][j4 * 4 + 1]
            + red[a][j4 * 4 + 2] + red[a][j4 * 4 + 3];
    v += __shfl_xor(v, 32);
    v += __shfl_xor(v, 16);
    v += __shfl_xor(v, 8);
    v += __shfl_xor(v, 4);
    v += __shfl_xor(v, 2);
    v += __shfl_xor(v, 1);
    if (tid == 0) BP[blockIdx.x] = v + 8.0f * (fb2[t] + Ebias[t]);
  }
}

__global__ __launch_bounds__(64) void k_reduce(const float* __restrict__ BP,
                                               float* __restrict__ out)
{
  int tid = threadIdx.x;
  float s = 0.0f;
#pragma unroll
  for (int u = 0; u < 8; ++u) s += BP[tid + 64 * u];
  s += __shfl_xor(s, 32);
  s += __shfl_xor(s, 16);
  s += __shfl_xor(s, 8);
  s += __shfl_xor(s, 4);
  s += __shfl_xor(s, 2);
  s += __shfl_xor(s, 1);
  if (tid == 0) out[0] = s;
}

extern "C" void kernel_launch(void* const* d_in, const int* in_sizes, int n_in,
                              void* d_out, int out_size, void* d_ws, size_t ws_size,
                              hipStream_t stream) {
  const float* coord = (const float*)d_in[0];
  const float* box   = (const float*)d_in[1];
  const int*   nbrs  = (const int*)d_in[2];
  const float* eW0   = (const float*)d_in[3];
  const float* eb0   = (const float*)d_in[4];
  const float* eW1   = (const float*)d_in[5];
  const float* eb1   = (const float*)d_in[6];
  const float* eW2   = (const float*)d_in[7];
  const float* eb2   = (const float*)d_in[8];
  const float* Tbias = (const float*)d_in[9];
  const float* fW0   = (const float*)d_in[10];
  const float* fb0   = (const float*)d_in[11];
  const float* fW1   = (const float*)d_in[12];
  const float* fb1   = (const float*)d_in[13];
  const float* fW2   = (const float*)d_in[14];
  const float* fb2   = (const float*)d_in[15];
  const float* Ebias = (const float*)d_in[16];

  h16*   G16 = (h16*)d_ws;                                          // 8 MB
  float* P   = (float*)((char*)d_ws + (size_t)8 * 1024 * 1024);     // 8 MB
  h16*   W0t = (h16*)((char*)d_ws + (size_t)16 * 1024 * 1024);      // 512 KB
  float* BP  = (float*)((char*)d_ws + (size_t)17 * 1024 * 1024);    // 2 KB

  k_prep<<<128, 256, 0, stream>>>(fW0, W0t);
  k_embed<<<1024, 256, 0, stream>>>(coord, box, nbrs, eW0, eb0, eW1, eb1,
                                    eW2, eb2, Tbias, G16);
  k_fit0<<<256, 256, 0, stream>>>(G16, W0t, P);
  k_fit1<<<512, 256, 0, stream>>>(P, fb0, fW1, fb1, fW2, fb2, Ebias, BP);
  k_reduce<<<1, 64, 0, stream>>>(BP, (float*)d_out);
}

// Round 7
// 60.838 us; speedup vs baseline: 2.6429x; 1.0010x over previous
//
#include <hip/hip_runtime.h>
#include <hip/hip_fp16.h>

typedef _Float16 h16;
typedef h16 v2h __attribute__((ext_vector_type(2)));
typedef h16 v8h __attribute__((ext_vector_type(8)));
typedef float f4 __attribute__((ext_vector_type(4)));

#define NATOM 4096
#define HALF_N 2048
#define K2 2.885390081777927f      // 2/ln2: tanh(x) = 1 - 2/(1+exp2(K2*x))
#define GSCL 0.015625f             // G stored as fp16 * 1/64
#define W0SCL (64.0f * K2)         // W0t staged as fp16 * 64 * K2

__device__ __forceinline__ float rcp_fast(float x) {
#if __has_builtin(__builtin_amdgcn_rcpf)
  return __builtin_amdgcn_rcpf(x);
#else
  return 1.0f / x;
#endif
}

__device__ __forceinline__ float exp2_fast(float x) {
#if __has_builtin(__builtin_amdgcn_exp2f)
  return __builtin_amdgcn_exp2f(x);
#else
  return exp2f(x);
#endif
}

// input d is already pre-scaled by K2=2/ln2: returns tanh(d/K2)
__device__ __forceinline__ float tanh_e2(float d) {
  float r = rcp_fast(1.0f + exp2_fast(d));
  return fmaf(-2.0f, r, 1.0f);
}

__device__ __forceinline__ float hdot2(v2h a, v2h b, float c) {
#if __has_builtin(__builtin_amdgcn_fdot2)
  return __builtin_amdgcn_fdot2(a, b, c, false);
#else
  return c + (float)a.x * (float)b.x + (float)a.y * (float)b.y;
#endif
}

__device__ __forceinline__ v2h pk2h(float lo, float hi) {
  return __builtin_bit_cast(v2h, __builtin_amdgcn_cvt_pkrtz(lo, hi));
}

__device__ __forceinline__ v8h lds_v8h(const h16* base, int byte) {
  return *(const v8h*)((const char*)base + byte);
}

// ---------------------------------------------------------------------------
// Kernel 1: 256 thr = 4 waves = 4 atoms. 2-phase h1 buffer, exp2-form tanh
// (weights pre-scaled by 2/ln2), E and T on the matrix pipe. Register diet:
// per-phase W2-fragment loads + 16-channel stage-B halves keep peak VGPR
// within the (256,3) budget (no spills). h1s XOR-swizzled (8-way -> 2-way
// write conflicts). LDS 51.6 KB -> 3 blocks/CU.
// ---------------------------------------------------------------------------
__global__ __launch_bounds__(256, 3) void k_embed(
    const float* __restrict__ coord, const float* __restrict__ box,
    const int* __restrict__ nbrs,
    const float* __restrict__ eW0, const float* __restrict__ eb0,
    const float* __restrict__ eW1, const float* __restrict__ eb1,
    const float* __restrict__ eW2, const float* __restrict__ eb2,
    const float* __restrict__ Tbias,
    h16* __restrict__ Gout)
{
  __shared__ float sW0[2][16], sb0[2][16], sb1[2][32], sb2[2][64];
  __shared__ v2h   sW1p[2][8][32];                                   // 2 KB
  __shared__ h16   W2t[2][4][64][8] __attribute__((aligned(16)));    // 8 KB
  __shared__ h16   h1s[4][64][40] __attribute__((aligned(16)));      // 20 KB (swz)
  __shared__ h16   Rls[4][10][136] __attribute__((aligned(16)));     // 10.6 KB
  __shared__ float Tls[4][10][64];                                   // 10 KB

  const int tid = threadIdx.x;
  const int wv = tid >> 6;
  const int lane = tid & 63;
  const int n = blockIdx.x * 4 + wv;
  const int ti = (n >= HALF_N) ? 1 : 0;
  const int c15 = lane & 15, g4 = lane >> 4;

  // prefetch neighbor indices (hide gather latency under weight staging)
  const int jnb0 = nbrs[(size_t)n * 128 + lane];
  const int jnb1 = nbrs[(size_t)n * 128 + 64 + lane];

  // ---- stage weights, all pre-scaled by K2 ----
  for (int idx = tid; idx < 32; idx += 256) {
    int s = idx >> 4, i = idx & 15;
    sW0[s][i] = K2 * eW0[(ti * 2 + s) * 16 + i];
    sb0[s][i] = K2 * eb0[(ti * 2 + s) * 16 + i];
  }
  for (int idx = tid; idx < 64; idx += 256) {
    int s = idx >> 5, i = idx & 31;
    sb1[s][i] = K2 * eb1[(ti * 2 + s) * 32 + i];
  }
  for (int idx = tid; idx < 128; idx += 256) {
    int s = idx >> 6, i = idx & 63;
    sb2[s][i] = K2 * eb2[(ti * 2 + s) * 64 + i];
  }
  for (int idx = tid; idx < 512; idx += 256) {
    int s = idx >> 8, r = idx & 255, ip = r >> 5, j = r & 31;
    const float* src = &eW1[(size_t)(ti * 2 + s) * 512];
    v2h p;
    p.x = (h16)(K2 * src[(2 * ip) * 32 + j]);
    p.y = (h16)(K2 * src[(2 * ip + 1) * 32 + j]);
    sW1p[s][ip][j] = p;
  }
  for (int idx = tid; idx < 4096; idx += 256) {
    int cc = idx & 63, j = (idx >> 6) & 7, g = (idx >> 9) & 3, s = idx >> 11;
    W2t[s][g][cc][j] = (h16)(K2 * eW2[(size_t)(ti * 2 + s) * 2048 + (g * 8 + j) * 64 + cc]);
  }
  __syncthreads();

  // ---- stage A: geometry + R rows (fp16 LDS) + srcn, 2 neighbors/lane ----
  float srcn_[2];
  {
    const float bx = box[0], by = box[1], bz = box[2];
    const float rbx = rcp_fast(bx), rby = rcp_fast(by), rbz = rcp_fast(bz);
    const float cx = coord[n], cy = coord[NATOM + n], cz = coord[2 * NATOM + n];
#pragma unroll
    for (int nb = 0; nb < 2; ++nb) {
      const int m = nb * 64 + lane;
      const int j = nb ? jnb1 : jnb0;
      float dx = coord[j] - cx;
      float dy = coord[NATOM + j] - cy;
      float dz = coord[2 * NATOM + j] - cz;
      dx -= bx * rintf(dx * rbx);
      dy -= by * rintf(dy * rby);
      dz -= bz * rintf(dz * rbz);
      float r2 = dx * dx + dy * dy + dz * dz;
      bool mk = r2 > 1e-12f;
      float rs = sqrtf(mk ? r2 : 1.0f);
      float r  = mk ? rs : 0.0f;
      float sw = 0.5f * __cosf(0.52359878f * fminf(r, 6.0f)) + 0.5f;
      float invr = mk ? rcp_fast(rs) : 1.0f;
      float sr = (mk && r < 6.0f) ? sw * invr : 0.0f;
      float x0 = dx * invr, x1 = dy * invr, x2 = dz * invr;
      float srn = sr * 20.0f;
      srcn_[nb] = (sr - 0.1f) * 20.0f;
      Rls[wv][0][m] = (h16)srn;
      Rls[wv][1][m] = (h16)(1.7320508f * srn * x0);
      Rls[wv][2][m] = (h16)(1.7320508f * srn * x1);
      Rls[wv][3][m] = (h16)(1.7320508f * srn * x2);
      Rls[wv][4][m] = (h16)(3.0f * srn * (x0 * x0 - 0.33333334f));
      Rls[wv][5][m] = (h16)(3.0f * srn * (x1 * x1 - 0.33333334f));
      Rls[wv][6][m] = (h16)(3.0f * srn * (x2 * x2 - 0.33333334f));
      Rls[wv][7][m] = (h16)(4.2426407f * srn * (x0 * x1));
      Rls[wv][8][m] = (h16)(4.2426407f * srn * (x1 * x2));
      Rls[wv][9][m] = (h16)(4.2426407f * srn * (x2 * x0));
    }
  }

  const int addr0 = (((lane >> 4) & 1) * 32 + c15) * 4;  // bpermute src, q<2
  const int addr1 = addr0 + 64;                           // q>=2
  const bool hi = lane >= 32;
  const int rrow = (c15 < 10) ? c15 : 9;
  const v8h rzero = {};

  f4 tac[4];
#pragma unroll
  for (int nt = 0; nt < 4; ++nt) tac[nt] = (f4){0.f, 0.f, 0.f, 0.f};

  // ================= 2-phase: stage B (h1) then 2 E/T k-steps ==============
#pragma unroll
  for (int ph = 0; ph < 2; ++ph) {
    // ---- stage B: lane computes h1[row lane]; two 16-channel halves ----
    {
      v2h h0p[8];
#pragma unroll
      for (int ip = 0; ip < 8; ++ip) {
        h16 plo = (h16)tanh_e2(fmaf(srcn_[ph], sW0[ph][2 * ip],     sb0[ph][2 * ip]));
        h16 phi = (h16)tanh_e2(fmaf(srcn_[ph], sW0[ph][2 * ip + 1], sb0[ph][2 * ip + 1]));
        v2h p; p.x = plo; p.y = phi;
        h0p[ip] = p;
      }
      h16* row = &h1s[wv][lane][0];
      const int key = ((lane >> 3) & 3) << 4;   // XOR swizzle key (byte units)
#pragma unroll
      for (int half = 0; half < 2; ++half) {
        float acc[16];
#pragma unroll
        for (int j = 0; j < 16; ++j) acc[j] = sb1[ph][half * 16 + j];
        union WU { v8h v; v2h p[4]; };
#pragma unroll
        for (int ip = 0; ip < 8; ++ip) {
#pragma unroll
          for (int rr = 0; rr < 4; ++rr) {
            WU w; w.v = *(const v8h*)&sW1p[ph][ip][half * 16 + rr * 4];
#pragma unroll
            for (int q = 0; q < 4; ++q)
              acc[rr * 4 + q] = hdot2(h0p[ip], w.p[q], acc[rr * 4 + q]);
          }
        }
#pragma unroll
        for (int ch = 0; ch < 2; ++ch) {
          union { v8h v; v2h p[4]; } o;
#pragma unroll
          for (int q = 0; q < 4; ++q)
            o.p[q] = pk2h(tanh_e2(acc[ch * 8 + 2 * q]), tanh_e2(acc[ch * 8 + 2 * q + 1]));
          int byte = (((half * 2 + ch) * 16) ^ key);
          *(v8h*)((char*)row + byte) = o.v;
        }
      }
    }

    // ---- per-phase W2 fragments (register diet: one slot live at a time) --
    v8h bwp[4];
    float b2p[4];
#pragma unroll
    for (int nt = 0; nt < 4; ++nt) {
      bwp[nt] = *(const v8h*)&W2t[ph][g4][nt * 16 + c15][0];
      b2p[nt] = sb2[ph][nt * 16 + c15];
    }

    // ---- E = tanh(h1@W2+b2) via MFMA, relayout, T += Rp@E via MFMA ----
#pragma unroll
    for (int kl = 0; kl < 2; ++kl) {
      const int ks = ph * 2 + kl;
      const int r0 = kl * 32 + c15, r1 = kl * 32 + 16 + c15;
      v8h a0 = lds_v8h(&h1s[wv][0][0],
                       r0 * 80 + ((g4 * 16) ^ ((((r0 >> 3) & 3)) << 4)));
      v8h a1 = lds_v8h(&h1s[wv][0][0],
                       r1 * 80 + ((g4 * 16) ^ ((((r1 >> 3) & 3)) << 4)));
      v8h ra = *(const v8h*)&Rls[wv][rrow][32 * ks + g4 * 8];
      if (c15 >= 10) ra = rzero;
#pragma unroll
      for (int nt = 0; nt < 4; ++nt) {
        f4 cb = (f4){b2p[nt], b2p[nt], b2p[nt], b2p[nt]};
        f4 e0 = __builtin_amdgcn_mfma_f32_16x16x32_f16(a0, bwp[nt], cb, 0, 0, 0);
        f4 e1 = __builtin_amdgcn_mfma_f32_16x16x32_f16(a1, bwp[nt], cb, 0, 0, 0);
        int w0a = __builtin_bit_cast(int, pk2h(tanh_e2(e0[0]), tanh_e2(e0[1])));
        int w1a = __builtin_bit_cast(int, pk2h(tanh_e2(e0[2]), tanh_e2(e0[3])));
        int w0b = __builtin_bit_cast(int, pk2h(tanh_e2(e1[0]), tanh_e2(e1[1])));
        int w1b = __builtin_bit_cast(int, pk2h(tanh_e2(e1[2]), tanh_e2(e1[3])));
        int pA0 = __builtin_amdgcn_ds_bpermute(addr0, w0a);
        int pB0 = __builtin_amdgcn_ds_bpermute(addr0, w0b);
        int pA1 = __builtin_amdgcn_ds_bpermute(addr0, w1a);
        int pB1 = __builtin_amdgcn_ds_bpermute(addr0, w1b);
        int pA2 = __builtin_amdgcn_ds_bpermute(addr1, w0a);
        int pB2 = __builtin_amdgcn_ds_bpermute(addr1, w0b);
        int pA3 = __builtin_amdgcn_ds_bpermute(addr1, w1a);
        int pB3 = __builtin_amdgcn_ds_bpermute(addr1, w1b);
        union { int u[4]; v8h v; } bf;
        bf.u[0] = hi ? pB0 : pA0;
        bf.u[1] = hi ? pB1 : pA1;
        bf.u[2] = hi ? pB2 : pA2;
        bf.u[3] = hi ? pB3 : pA3;
        tac[nt] = __builtin_amdgcn_mfma_f32_16x16x32_f16(ra, bf.v, tac[nt], 0, 0, 0);
      }
    }
  }

  // ---- store T rows < 10 (with /NORM) ----
#pragma unroll
  for (int nt = 0; nt < 4; ++nt)
#pragma unroll
    for (int r = 0; r < 4; ++r) {
      int x = g4 * 4 + r;
      if (x < 10) Tls[wv][x][nt * 16 + c15] = tac[nt][r] * 0.05f;
    }

  // ---- stage G: tensor algebra + store Gflat as fp16/64 ----
  {
    const int c = lane;
    const float tnc  = Tls[wv][0][c] + Tbias[c];
    const float t3c0 = Tls[wv][1][c], t3c1 = Tls[wv][2][c], t3c2 = Tls[wv][3][c];
    const float t6c0 = Tls[wv][4][c], t6c1 = Tls[wv][5][c], t6c2 = Tls[wv][6][c];
    const float t6c3 = Tls[wv][7][c], t6c4 = Tls[wv][8][c], t6c5 = Tls[wv][9][c];
    h16* gp = Gout + (size_t)n * 1024;
#pragma unroll
    for (int a = 0; a < 16; ++a) {
      float g = tnc * (Tls[wv][0][a] + Tbias[a]);
      g += t3c0 * Tls[wv][1][a] + t3c1 * Tls[wv][2][a] + t3c2 * Tls[wv][3][a];
      const float g1x = Tls[wv][1][16 + a], g1y = Tls[wv][2][16 + a], g1z = Tls[wv][3][16 + a];
      g += (g1x * g1x + Tls[wv][4][16 + a]) * t6c0;
      g += (g1y * g1y + Tls[wv][5][16 + a]) * t6c1;
      g += (g1z * g1z + Tls[wv][6][16 + a]) * t6c2;
      g += (1.4142135f * g1x * g1y + Tls[wv][7][16 + a]) * t6c3;
      g += (1.4142135f * g1y * g1z + Tls[wv][8][16 + a]) * t6c4;
      g += (1.4142135f * g1z * g1x + Tls[wv][9][16 + a]) * t6c5;
      gp[a * 64 + c] = (h16)(g * GSCL);
    }
  }
}

// ---------------------------------------------------------------------------
// Prep: W0t[t][n][k] = fW0[t][k][n] * 64 * K2 as fp16. grid 128 x 256.
// ---------------------------------------------------------------------------
__global__ __launch_bounds__(256) void k_prep(const float* __restrict__ fW0,
                                              h16* __restrict__ W0t)
{
  int idx = blockIdx.x * 256 + threadIdx.x;     // 0..32767
  int t = idx >> 14, n = idx & 127, k8 = (idx >> 7) & 127;
  union { v8h v; h16 e[8]; } o;
#pragma unroll
  for (int i = 0; i < 8; ++i)
    o.e[i] = (h16)(W0SCL * fW0[(size_t)t * 131072 + (size_t)(k8 * 8 + i) * 128 + n]);
  *(v8h*)&W0t[((size_t)t * 128 + n) * 1024 + k8 * 8] = o.v;
}

// ---------------------------------------------------------------------------
// Kernel 2a: fit layer-0 GEMM on MFMA. grid = 64 atom-tiles x 4 ksplit.
// A = G16 (fp16/64), B = W0t (fp16*64*K2) -> P = K2*(G@W0). XOR-swizzled LDS.
// ---------------------------------------------------------------------------
__global__ __launch_bounds__(256, 2) void k_fit0(
    const h16* __restrict__ G16, const h16* __restrict__ W0t,
    float* __restrict__ P)
{
  __shared__ h16 As[64][64]  __attribute__((aligned(16)));   // 8 KB, swizzled
  __shared__ h16 Bts[128][64] __attribute__((aligned(16)));  // 16 KB, swizzled
  const int tid = threadIdx.x;
  const int atile = blockIdx.x >> 2;
  const int ks = blockIdx.x & 3;
  const int abase = atile * 64;
  const int kbase = ks * 256;
  const int t = (abase >= HALF_N) ? 1 : 0;
  const int lane = tid & 63, w = tid >> 6;
  const int c15 = lane & 15, g4 = lane >> 4;

  f4 acc[8];
#pragma unroll
  for (int nt = 0; nt < 8; ++nt) acc[nt] = (f4){0.f, 0.f, 0.f, 0.f};

  for (int kc = 0; kc < 4; ++kc) {
    const int kb = kbase + kc * 64;
    __syncthreads();
#pragma unroll
    for (int u = 0; u < 2; ++u) {
      int idx = u * 256 + tid;                  // 0..511
      int r = idx >> 3, c8 = idx & 7;
      v8h v = *(const v8h*)&G16[(size_t)(abase + r) * 1024 + kb + c8 * 8];
      int byte = r * 128 + ((c8 * 16) ^ ((r & 7) << 4));
      *(v8h*)((char*)&As[0][0] + byte) = v;
    }
#pragma unroll
    for (int u = 0; u < 4; ++u) {
      int idx = u * 256 + tid;                  // 0..1023
      int nr = idx >> 3, c8 = idx & 7;
      v8h v = *(const v8h*)&W0t[((size_t)t * 128 + nr) * 1024 + kb + c8 * 8];
      int byte = nr * 128 + ((c8 * 16) ^ ((nr & 7) << 4));
      *(v8h*)((char*)&Bts[0][0] + byte) = v;
    }
    __syncthreads();
#pragma unroll
    for (int ksub = 0; ksub < 2; ++ksub) {
      const int ar = 16 * w + c15;
      const int koff = (ksub * 32 + g4 * 8) * 2;
      v8h a = lds_v8h(&As[0][0], ar * 128 + (koff ^ ((ar & 7) << 4)));
#pragma unroll
      for (int nt = 0; nt < 8; ++nt) {
        const int br = nt * 16 + c15;
        v8h b = lds_v8h(&Bts[0][0], br * 128 + (koff ^ ((br & 7) << 4)));
        acc[nt] = __builtin_amdgcn_mfma_f32_16x16x32_f16(a, b, acc[nt], 0, 0, 0);
      }
    }
  }

  float* Pk = P + (size_t)ks * 4096 * 128;
#pragma unroll
  for (int nt = 0; nt < 8; ++nt)
#pragma unroll
    for (int r = 0; r < 4; ++r)
      Pk[(size_t)(abase + 16 * w + g4 * 4 + r) * 128 + nt * 16 + c15] = acc[nt][r];
}

// ---------------------------------------------------------------------------
// Kernel 2b: combine 4 K-split partials (already K2-scaled) + layers 1-2 +
// per-block energy partial. grid = 512 x 8 atoms.
// ---------------------------------------------------------------------------
__global__ __launch_bounds__(256, 4) void k_fit1(
    const float* __restrict__ P,
    const float* __restrict__ fb0, const float* __restrict__ fW1,
    const float* __restrict__ fb1, const float* __restrict__ fW2,
    const float* __restrict__ fb2, const float* __restrict__ Ebias,
    float* __restrict__ BP)
{
  __shared__ float ht[128][12];
  __shared__ float Ws1[32][128];
  __shared__ float red[8][33];
  const int tid = threadIdx.x;
  const int abase = blockIdx.x * 8;
  const int t = (abase >= HALF_N) ? 1 : 0;

  {
    const int a = tid >> 5, j0 = (tid & 31) * 4;
    f4 s = K2 * (*(const f4*)&fb0[t * 128 + j0]);
#pragma unroll
    for (int ks = 0; ks < 4; ++ks)
      s += *(const f4*)&P[((size_t)ks * 4096 + abase + a) * 128 + j0];
    ht[j0 + 0][a] = tanh_e2(s.x);
    ht[j0 + 1][a] = tanh_e2(s.y);
    ht[j0 + 2][a] = tanh_e2(s.z);
    ht[j0 + 3][a] = tanh_e2(s.w);
  }

  const int ab = tid & 7, jb = tid >> 3;
  const int j0g = jb * 4;
  f4 acc = K2 * (*(const f4*)&fb1[t * 128 + j0g]);
  for (int kc = 0; kc < 4; ++kc) {
    __syncthreads();
#pragma unroll
    for (int u = 0; u < 2; ++u) {
      int idx = (u * 256 + tid) * 8;
      int kk = idx >> 7, j = idx & 127;
      *(f4*)&Ws1[kk][j] =
          K2 * (*(const f4*)&fW1[(size_t)t * 16384 + (size_t)(kc * 32 + kk) * 128 + j]);
      *(f4*)&Ws1[kk][j + 4] =
          K2 * (*(const f4*)&fW1[(size_t)t * 16384 + (size_t)(kc * 32 + kk) * 128 + j + 4]);
    }
    __syncthreads();
    for (int kk = 0; kk < 32; ++kk) {
      float av = ht[kc * 32 + kk][ab];
      f4 w = *(const f4*)&Ws1[kk][j0g];
      acc += av * w;
    }
  }

  float f = tanh_e2(acc.x) * fW2[t * 128 + j0g + 0]
          + tanh_e2(acc.y) * fW2[t * 128 + j0g + 1]
          + tanh_e2(acc.z) * fW2[t * 128 + j0g + 2]
          + tanh_e2(acc.w) * fW2[t * 128 + j0g + 3];
  red[ab][jb] = f;
  __syncthreads();
  if (tid < 64) {
    const int a = tid & 7, j4 = tid >> 3;
    float v = red[a][j4 * 4] + red[a][j4 * 4 + 1]
            + red[a][j4 * 4 + 2] + red[a][j4 * 4 + 3];
    v += __shfl_xor(v, 32);
    v += __shfl_xor(v, 16);
    v += __shfl_xor(v, 8);
    v += __shfl_xor(v, 4);
    v += __shfl_xor(v, 2);
    v += __shfl_xor(v, 1);
    if (tid == 0) BP[blockIdx.x] = v + 8.0f * (fb2[t] + Ebias[t]);
  }
}

__global__ __launch_bounds__(64) void k_reduce(const float* __restrict__ BP,
                                               float* __restrict__ out)
{
  int tid = threadIdx.x;
  float s = 0.0f;
#pragma unroll
  for (int u = 0; u < 8; ++u) s += BP[tid + 64 * u];
  s += __shfl_xor(s, 32);
  s += __shfl_xor(s, 16);
  s += __shfl_xor(s, 8);
  s += __shfl_xor(s, 4);
  s += __shfl_xor(s, 2);
  s += __shfl_xor(s, 1);
  if (tid == 0) out[0] = s;
}

extern "C" void kernel_launch(void* const* d_in, const int* in_sizes, int n_in,
                              void* d_out, int out_size, void* d_ws, size_t ws_size,
                              hipStream_t stream) {
  const float* coord = (const float*)d_in[0];
  const float* box   = (const float*)d_in[1];
  const int*   nbrs  = (const int*)d_in[2];
  const float* eW0   = (const float*)d_in[3];
  const float* eb0   = (const float*)d_in[4];
  const float* eW1   = (const float*)d_in[5];
  const float* eb1   = (const float*)d_in[6];
  const float* eW2   = (const float*)d_in[7];
  const float* eb2   = (const float*)d_in[8];
  const float* Tbias = (const float*)d_in[9];
  const float* fW0   = (const float*)d_in[10];
  const float* fb0   = (const float*)d_in[11];
  const float* fW1   = (const float*)d_in[12];
  const float* fb1   = (const float*)d_in[13];
  const float* fW2   = (const float*)d_in[14];
  const float* fb2   = (const float*)d_in[15];
  const float* Ebias = (const float*)d_in[16];

  h16*   G16 = (h16*)d_ws;                                          // 8 MB
  float* P   = (float*)((char*)d_ws + (size_t)8 * 1024 * 1024);     // 8 MB
  h16*   W0t = (h16*)((char*)d_ws + (size_t)16 * 1024 * 1024);      // 512 KB
  float* BP  = (float*)((char*)d_ws + (size_t)17 * 1024 * 1024);    // 2 KB

  k_prep<<<128, 256, 0, stream>>>(fW0, W0t);
  k_embed<<<1024, 256, 0, stream>>>(coord, box, nbrs, eW0, eb0, eW1, eb1,
                                    eW2, eb2, Tbias, G16);
  k_fit0<<<256, 256, 0, stream>>>(G16, W0t, P);
  k_fit1<<<512, 256, 0, stream>>>(P, fb0, fW1, fb1, fW2, fb2, Ebias, BP);
  k_reduce<<<1, 64, 0, stream>>>(BP, (float*)d_out);
}

// Round 8
// 48.527 us; speedup vs baseline: 3.3134x; 1.2537x over previous
//
#include <hip/hip_runtime.h>
#include <hip/hip_fp16.h>

typedef _Float16 h16;
typedef h16 v2h __attribute__((ext_vector_type(2)));
typedef h16 v8h __attribute__((ext_vector_type(8)));
typedef float f4 __attribute__((ext_vector_type(4)));

#define NATOM 4096
#define HALF_N 2048
#define K2 2.885390081777927f      // 2/ln2: tanh(x) = 1 - 2/(1+exp2(K2*x))
#define GSCL 0.015625f             // G stored as fp16 * 1/64
#define W0SCL (64.0f * K2)         // W0t staged as fp16 * 64 * K2

// ---- embedding table: E(srcn) tabulated on w = s/(8+|s|), uniform in w ----
#define TBL_N 2048
#define W0MIN_ (-0.201f)
#define DW_ (1.2005f / 2047.0f)
#define RSCALE_ (2047.0f / 1.2005f)

__device__ __forceinline__ float rcp_fast(float x) {
#if __has_builtin(__builtin_amdgcn_rcpf)
  return __builtin_amdgcn_rcpf(x);
#else
  return 1.0f / x;
#endif
}

__device__ __forceinline__ float exp2_fast(float x) {
#if __has_builtin(__builtin_amdgcn_exp2f)
  return __builtin_amdgcn_exp2f(x);
#else
  return exp2f(x);
#endif
}

// input d is already pre-scaled by K2=2/ln2: returns tanh(d/K2)
__device__ __forceinline__ float tanh_e2(float d) {
  float r = rcp_fast(1.0f + exp2_fast(d));
  return fmaf(-2.0f, r, 1.0f);
}

// ---------------------------------------------------------------------------
// Setup kernel. Blocks 0..511: build embedding table tbl[net][entry][ch]
// (thread = (net, entry, ch-quad); full 1->16->32->64 MLP, weights in LDS).
// Blocks 512..639: transpose fW0 -> W0t (fp16 * 64 * K2) for the fit GEMM.
// ---------------------------------------------------------------------------
__global__ __launch_bounds__(256) void k_setup(
    const float* __restrict__ eW0, const float* __restrict__ eb0,
    const float* __restrict__ eW1, const float* __restrict__ eb1,
    const float* __restrict__ eW2, const float* __restrict__ eb2,
    const float* __restrict__ fW0,
    h16* __restrict__ tbl, h16* __restrict__ W0t)
{
  const int bid = blockIdx.x, tid = threadIdx.x;
  if (bid < 512) {
    __shared__ float sW1[512];
    __shared__ float sW2[2048];
    __shared__ float sW0s[16], sb0s[16], sb1s[32], sb2s[64];
    const int net = bid >> 7;
    for (int i = tid; i < 512; i += 256) sW1[i] = eW1[net * 512 + i];
    for (int i = tid; i < 2048; i += 256) sW2[i] = eW2[net * 2048 + i];
    if (tid < 16) { sW0s[tid] = eW0[net * 16 + tid]; sb0s[tid] = eb0[net * 16 + tid]; }
    else if (tid >= 32 && tid < 64) sb1s[tid - 32] = eb1[net * 32 + tid - 32];
    else if (tid >= 64 && tid < 128) sb2s[tid - 64] = eb2[net * 64 + tid - 64];
    __syncthreads();

    const int u = (bid & 127) * 256 + tid;     // 0..32767
    const int e = u >> 4, cq = u & 15;
    const float w = W0MIN_ + (float)e * DW_;
    const float s = 8.0f * w * rcp_fast(1.0f - fabsf(w));
    float h0[16];
#pragma unroll
    for (int i = 0; i < 16; ++i)
      h0[i] = tanh_e2(K2 * fmaf(s, sW0s[i], sb0s[i]));
    float h1[32];
#pragma unroll
    for (int j = 0; j < 32; ++j) {
      float a = sb1s[j];
#pragma unroll
      for (int i = 0; i < 16; ++i) a = fmaf(h0[i], sW1[i * 32 + j], a);
      h1[j] = tanh_e2(K2 * a);
    }
    f4 a4 = *(const f4*)&sb2s[cq * 4];
    for (int j = 0; j < 32; ++j) {
      f4 wv4 = *(const f4*)&sW2[j * 64 + cq * 4];
      a4 += h1[j] * wv4;
    }
    union { h16 e4[4]; unsigned long long q; } o;
#pragma unroll
    for (int q = 0; q < 4; ++q) o.e4[q] = (h16)tanh_e2(K2 * a4[q]);
    *(unsigned long long*)&tbl[((size_t)(net * TBL_N + e)) * 64 + cq * 4] = o.q;
  } else {
    int idx = (bid - 512) * 256 + tid;          // 0..32767
    int t = idx >> 14, n = idx & 127, k8 = (idx >> 7) & 127;
    union { v8h v; h16 e[8]; } o;
#pragma unroll
    for (int i = 0; i < 8; ++i)
      o.e[i] = (h16)(W0SCL * fW0[(size_t)t * 131072 + (size_t)(k8 * 8 + i) * 128 + n]);
    *(v8h*)&W0t[((size_t)t * 128 + n) * 1024 + k8 * 8] = o.v;
  }
}

// ---------------------------------------------------------------------------
// Kernel 1: 256 thr = 4 waves = 4 atoms. Embedding MLP replaced by table
// lookup: per neighbor gather 2 contiguous 128B rows (lerp in packed fp16),
// transpose-store to E32t, then T = Rp@E as 16 MFMAs. Zero barriers (all
// per-atom LDS is wave-private). LDS 42.6 KB -> 3 blocks/CU.
// ---------------------------------------------------------------------------
__global__ __launch_bounds__(256, 3) void k_embed(
    const float* __restrict__ coord, const float* __restrict__ box,
    const int* __restrict__ nbrs, const float* __restrict__ Tbias,
    const h16* __restrict__ tbl, h16* __restrict__ Gout)
{
  __shared__ h16   E32t[4][64][40] __attribute__((aligned(16)));  // [wv][ch][m] 5 KB
  __shared__ h16   Rls[4][10][136] __attribute__((aligned(16)));  // 2.72 KB
  __shared__ float Tls[4][10][64];                                 // 2.5 KB
  __shared__ unsigned int ifx[4][128];                             // 0.5 KB

  const int tid = threadIdx.x;
  const int wv = tid >> 6;
  const int lane = tid & 63;
  const int n = blockIdx.x * 4 + wv;
  const int ti = (n >= HALF_N) ? 1 : 0;
  const int c15 = lane & 15, g4 = lane >> 4;

  // ---- stage A: geometry + R rows + table index/frac, 2 neighbors/lane ----
  {
    const float bx = box[0], by = box[1], bz = box[2];
    const float rbx = rcp_fast(bx), rby = rcp_fast(by), rbz = rcp_fast(bz);
    const float cx = coord[n], cy = coord[NATOM + n], cz = coord[2 * NATOM + n];
#pragma unroll
    for (int nb = 0; nb < 2; ++nb) {
      const int m = nb * 64 + lane;
      const int j = nbrs[(size_t)n * 128 + m];
      float dx = coord[j] - cx;
      float dy = coord[NATOM + j] - cy;
      float dz = coord[2 * NATOM + j] - cz;
      dx -= bx * rintf(dx * rbx);
      dy -= by * rintf(dy * rby);
      dz -= bz * rintf(dz * rbz);
      float r2 = dx * dx + dy * dy + dz * dz;
      bool mk = r2 > 1e-12f;
      float rs = sqrtf(mk ? r2 : 1.0f);
      float r  = mk ? rs : 0.0f;
      float sw = 0.5f * __cosf(0.52359878f * fminf(r, 6.0f)) + 0.5f;
      float invr = mk ? rcp_fast(rs) : 1.0f;
      float sr = (mk && r < 6.0f) ? sw * invr : 0.0f;
      float x0 = dx * invr, x1 = dy * invr, x2 = dz * invr;
      float srn = sr * 20.0f;
      float s   = (sr - 0.1f) * 20.0f;          // srcn
      Rls[wv][0][m] = (h16)srn;
      Rls[wv][1][m] = (h16)(1.7320508f * srn * x0);
      Rls[wv][2][m] = (h16)(1.7320508f * srn * x1);
      Rls[wv][3][m] = (h16)(1.7320508f * srn * x2);
      Rls[wv][4][m] = (h16)(3.0f * srn * (x0 * x0 - 0.33333334f));
      Rls[wv][5][m] = (h16)(3.0f * srn * (x1 * x1 - 0.33333334f));
      Rls[wv][6][m] = (h16)(3.0f * srn * (x2 * x2 - 0.33333334f));
      Rls[wv][7][m] = (h16)(4.2426407f * srn * (x0 * x1));
      Rls[wv][8][m] = (h16)(4.2426407f * srn * (x1 * x2));
      Rls[wv][9][m] = (h16)(4.2426407f * srn * (x2 * x0));
      // table coordinate: w = s/(8+|s|), uniform grid in w
      float wr = s * rcp_fast(8.0f + fabsf(s));
      float fidx = (wr - W0MIN_) * RSCALE_;
      fidx = fminf(fmaxf(fidx, 0.0f), 2045.99f);
      float i0f = floorf(fidx);
      h16 frh = (h16)(fidx - i0f);
      ifx[wv][m] = ((unsigned int)i0f << 16) |
                   (unsigned int)__builtin_bit_cast(unsigned short, frh);
    }
  }

  // ---- T = Rp @ E via MFMA, E gathered+lerped from table per 32-m chunk ----
  f4 tac[4];
#pragma unroll
  for (int nt = 0; nt < 4; ++nt) tac[nt] = (f4){0.f, 0.f, 0.f, 0.f};
  const int rrow = (c15 < 10) ? c15 : 9;
  const v8h vzero = {};

  for (int ks = 0; ks < 4; ++ks) {
    // gather: lane pair (2 lanes) per m-row; each lane does one 32-ch half
    {
      const int mloc = lane >> 1, h = lane & 1;
      const int m = ks * 32 + mloc;
      const unsigned int u = ifx[wv][m];
      const int i0 = (int)(u >> 16);
      const h16 fh = __builtin_bit_cast(h16, (unsigned short)(u & 0xffffu));
      v2h fr2; fr2.x = fh; fr2.y = fh;
      const int net = ti * 2 + (m >> 6);
      const h16* rp = tbl + ((size_t)(net * TBL_N + i0)) * 64 + h * 32;
      union U8 { v8h v; v2h p[4]; h16 e[8]; };
      U8 r0[4], r1[4];
#pragma unroll
      for (int q = 0; q < 4; ++q) {
        r0[q].v = *(const v8h*)(rp + q * 8);
        r1[q].v = *(const v8h*)(rp + 64 + q * 8);
      }
      h16 ev[32];
#pragma unroll
      for (int q = 0; q < 4; ++q) {
#pragma unroll
        for (int p = 0; p < 4; ++p) {
          v2h d = r1[q].p[p] - r0[q].p[p];
          v2h e2 = r0[q].p[p] + fr2 * d;
          ev[q * 8 + p * 2]     = e2.x;
          ev[q * 8 + p * 2 + 1] = e2.y;
        }
      }
#pragma unroll
      for (int i = 0; i < 32; ++i)
        E32t[wv][h * 32 + i][mloc] = ev[i];
    }
    // MFMA: A = R-fragment (row rrow), B = E32t fragment
    {
      v8h ra = *(const v8h*)&Rls[wv][rrow][ks * 32 + g4 * 8];
      if (c15 >= 10) ra = vzero;
#pragma unroll
      for (int nt = 0; nt < 4; ++nt) {
        v8h bf = *(const v8h*)&E32t[wv][nt * 16 + c15][g4 * 8];
        tac[nt] = __builtin_amdgcn_mfma_f32_16x16x32_f16(ra, bf, tac[nt], 0, 0, 0);
      }
    }
  }

  // ---- store T rows < 10 (with /NORM) ----
#pragma unroll
  for (int nt = 0; nt < 4; ++nt)
#pragma unroll
    for (int r = 0; r < 4; ++r) {
      int x = g4 * 4 + r;
      if (x < 10) Tls[wv][x][nt * 16 + c15] = tac[nt][r] * 0.05f;
    }

  // ---- stage G: tensor algebra + store Gflat as fp16/64 ----
  {
    const int c = lane;
    const float tnc  = Tls[wv][0][c] + Tbias[c];
    const float t3c0 = Tls[wv][1][c], t3c1 = Tls[wv][2][c], t3c2 = Tls[wv][3][c];
    const float t6c0 = Tls[wv][4][c], t6c1 = Tls[wv][5][c], t6c2 = Tls[wv][6][c];
    const float t6c3 = Tls[wv][7][c], t6c4 = Tls[wv][8][c], t6c5 = Tls[wv][9][c];
    h16* gp = Gout + (size_t)n * 1024;
#pragma unroll
    for (int a = 0; a < 16; ++a) {
      float g = tnc * (Tls[wv][0][a] + Tbias[a]);
      g += t3c0 * Tls[wv][1][a] + t3c1 * Tls[wv][2][a] + t3c2 * Tls[wv][3][a];
      const float g1x = Tls[wv][1][16 + a], g1y = Tls[wv][2][16 + a], g1z = Tls[wv][3][16 + a];
      g += (g1x * g1x + Tls[wv][4][16 + a]) * t6c0;
      g += (g1y * g1y + Tls[wv][5][16 + a]) * t6c1;
      g += (g1z * g1z + Tls[wv][6][16 + a]) * t6c2;
      g += (1.4142135f * g1x * g1y + Tls[wv][7][16 + a]) * t6c3;
      g += (1.4142135f * g1y * g1z + Tls[wv][8][16 + a]) * t6c4;
      g += (1.4142135f * g1z * g1x + Tls[wv][9][16 + a]) * t6c5;
      gp[a * 64 + c] = (h16)(g * GSCL);
    }
  }
}

// ---------------------------------------------------------------------------
// Kernel 2a: fit layer-0 GEMM on MFMA. grid = 64 atom-tiles x 4 ksplit.
// A = G16 (fp16/64), B = W0t (fp16*64*K2) -> P = K2*(G@W0). XOR-swizzled LDS.
// ---------------------------------------------------------------------------
__device__ __forceinline__ v8h lds_v8h(const h16* base, int byte) {
  return *(const v8h*)((const char*)base + byte);
}

__global__ __launch_bounds__(256, 2) void k_fit0(
    const h16* __restrict__ G16, const h16* __restrict__ W0t,
    float* __restrict__ P)
{
  __shared__ h16 As[64][64]  __attribute__((aligned(16)));
  __shared__ h16 Bts[128][64] __attribute__((aligned(16)));
  const int tid = threadIdx.x;
  const int atile = blockIdx.x >> 2;
  const int ks = blockIdx.x & 3;
  const int abase = atile * 64;
  const int kbase = ks * 256;
  const int t = (abase >= HALF_N) ? 1 : 0;
  const int lane = tid & 63, w = tid >> 6;
  const int c15 = lane & 15, g4 = lane >> 4;

  f4 acc[8];
#pragma unroll
  for (int nt = 0; nt < 8; ++nt) acc[nt] = (f4){0.f, 0.f, 0.f, 0.f};

  for (int kc = 0; kc < 4; ++kc) {
    const int kb = kbase + kc * 64;
    __syncthreads();
#pragma unroll
    for (int u = 0; u < 2; ++u) {
      int idx = u * 256 + tid;
      int r = idx >> 3, c8 = idx & 7;
      v8h v = *(const v8h*)&G16[(size_t)(abase + r) * 1024 + kb + c8 * 8];
      int byte = r * 128 + ((c8 * 16) ^ ((r & 7) << 4));
      *(v8h*)((char*)&As[0][0] + byte) = v;
    }
#pragma unroll
    for (int u = 0; u < 4; ++u) {
      int idx = u * 256 + tid;
      int nr = idx >> 3, c8 = idx & 7;
      v8h v = *(const v8h*)&W0t[((size_t)t * 128 + nr) * 1024 + kb + c8 * 8];
      int byte = nr * 128 + ((c8 * 16) ^ ((nr & 7) << 4));
      *(v8h*)((char*)&Bts[0][0] + byte) = v;
    }
    __syncthreads();
#pragma unroll
    for (int ksub = 0; ksub < 2; ++ksub) {
      const int ar = 16 * w + c15;
      const int koff = (ksub * 32 + g4 * 8) * 2;
      v8h a = lds_v8h(&As[0][0], ar * 128 + (koff ^ ((ar & 7) << 4)));
#pragma unroll
      for (int nt = 0; nt < 8; ++nt) {
        const int br = nt * 16 + c15;
        v8h b = lds_v8h(&Bts[0][0], br * 128 + (koff ^ ((br & 7) << 4)));
        acc[nt] = __builtin_amdgcn_mfma_f32_16x16x32_f16(a, b, acc[nt], 0, 0, 0);
      }
    }
  }

  float* Pk = P + (size_t)ks * 4096 * 128;
#pragma unroll
  for (int nt = 0; nt < 8; ++nt)
#pragma unroll
    for (int r = 0; r < 4; ++r)
      Pk[(size_t)(abase + 16 * w + g4 * 4 + r) * 128 + nt * 16 + c15] = acc[nt][r];
}

// ---------------------------------------------------------------------------
// Kernel 2b: combine 4 K-split partials (already K2-scaled) + layers 1-2 +
// per-block energy partial. grid = 512 x 8 atoms.
// ---------------------------------------------------------------------------
__global__ __launch_bounds__(256, 4) void k_fit1(
    const float* __restrict__ P,
    const float* __restrict__ fb0, const float* __restrict__ fW1,
    const float* __restrict__ fb1, const float* __restrict__ fW2,
    const float* __restrict__ fb2, const float* __restrict__ Ebias,
    float* __restrict__ BP)
{
  __shared__ float ht[128][12];
  __shared__ float Ws1[32][128];
  __shared__ float red[8][33];
  const int tid = threadIdx.x;
  const int abase = blockIdx.x * 8;
  const int t = (abase >= HALF_N) ? 1 : 0;

  {
    const int a = tid >> 5, j0 = (tid & 31) * 4;
    f4 s = K2 * (*(const f4*)&fb0[t * 128 + j0]);
#pragma unroll
    for (int ks = 0; ks < 4; ++ks)
      s += *(const f4*)&P[((size_t)ks * 4096 + abase + a) * 128 + j0];
    ht[j0 + 0][a] = tanh_e2(s.x);
    ht[j0 + 1][a] = tanh_e2(s.y);
    ht[j0 + 2][a] = tanh_e2(s.z);
    ht[j0 + 3][a] = tanh_e2(s.w);
  }

  const int ab = tid & 7, jb = tid >> 3;
  const int j0g = jb * 4;
  f4 acc = K2 * (*(const f4*)&fb1[t * 128 + j0g]);
  for (int kc = 0; kc < 4; ++kc) {
    __syncthreads();
#pragma unroll
    for (int u = 0; u < 2; ++u) {
      int idx = (u * 256 + tid) * 8;
      int kk = idx >> 7, j = idx & 127;
      *(f4*)&Ws1[kk][j] =
          K2 * (*(const f4*)&fW1[(size_t)t * 16384 + (size_t)(kc * 32 + kk) * 128 + j]);
      *(f4*)&Ws1[kk][j + 4] =
          K2 * (*(const f4*)&fW1[(size_t)t * 16384 + (size_t)(kc * 32 + kk) * 128 + j + 4]);
    }
    __syncthreads();
    for (int kk = 0; kk < 32; ++kk) {
      float av = ht[kc * 32 + kk][ab];
      f4 w = *(const f4*)&Ws1[kk][j0g];
      acc += av * w;
    }
  }

  float f = tanh_e2(acc.x) * fW2[t * 128 + j0g + 0]
          + tanh_e2(acc.y) * fW2[t * 128 + j0g + 1]
          + tanh_e2(acc.z) * fW2[t * 128 + j0g + 2]
          + tanh_e2(acc.w) * fW2[t * 128 + j0g + 3];
  red[ab][jb] = f;
  __syncthreads();
  if (tid < 64) {
    const int a = tid & 7, j4 = tid >> 3;
    float v = red[a][j4 * 4] + red[a][j4 * 4 + 1]
            + red[a][j4 * 4 + 2] + red[a][j4 * 4 + 3];
    v += __shfl_xor(v, 32);
    v += __shfl_xor(v, 16);
    v += __shfl_xor(v, 8);
    v += __shfl_xor(v, 4);
    v += __shfl_xor(v, 2);
    v += __shfl_xor(v, 1);
    if (tid == 0) BP[blockIdx.x] = v + 8.0f * (fb2[t] + Ebias[t]);
  }
}

__global__ __launch_bounds__(64) void k_reduce(const float* __restrict__ BP,
                                               float* __restrict__ out)
{
  int tid = threadIdx.x;
  float s = 0.0f;
#pragma unroll
  for (int u = 0; u < 8; ++u) s += BP[tid + 64 * u];
  s += __shfl_xor(s, 32);
  s += __shfl_xor(s, 16);
  s += __shfl_xor(s, 8);
  s += __shfl_xor(s, 4);
  s += __shfl_xor(s, 2);
  s += __shfl_xor(s, 1);
  if (tid == 0) out[0] = s;
}

extern "C" void kernel_launch(void* const* d_in, const int* in_sizes, int n_in,
                              void* d_out, int out_size, void* d_ws, size_t ws_size,
                              hipStream_t stream) {
  const float* coord = (const float*)d_in[0];
  const float* box   = (const float*)d_in[1];
  const int*   nbrs  = (const int*)d_in[2];
  const float* eW0   = (const float*)d_in[3];
  const float* eb0   = (const float*)d_in[4];
  const float* eW1   = (const float*)d_in[5];
  const float* eb1   = (const float*)d_in[6];
  const float* eW2   = (const float*)d_in[7];
  const float* eb2   = (const float*)d_in[8];
  const float* Tbias = (const float*)d_in[9];
  const float* fW0   = (const float*)d_in[10];
  const float* fb0   = (const float*)d_in[11];
  const float* fW1   = (const float*)d_in[12];
  const float* fb1   = (const float*)d_in[13];
  const float* fW2   = (const float*)d_in[14];
  const float* fb2   = (const float*)d_in[15];
  const float* Ebias = (const float*)d_in[16];

  h16*   G16 = (h16*)d_ws;                                          // 8 MB
  float* P   = (float*)((char*)d_ws + (size_t)8 * 1024 * 1024);     // 8 MB
  h16*   W0t = (h16*)((char*)d_ws + (size_t)16 * 1024 * 1024);      // 512 KB
  float* BP  = (float*)((char*)d_ws + (size_t)17 * 1024 * 1024);    // 2 KB
  h16*   tbl = (h16*)((char*)d_ws + (size_t)18 * 1024 * 1024);      // 1 MB

  k_setup<<<640, 256, 0, stream>>>(eW0, eb0, eW1, eb1, eW2, eb2, fW0, tbl, W0t);
  k_embed<<<1024, 256, 0, stream>>>(coord, box, nbrs, Tbias, tbl, G16);
  k_fit0<<<256, 256, 0, stream>>>(G16, W0t, P);
  k_fit1<<<512, 256, 0, stream>>>(P, fb0, fW1, fb1, fW2, fb2, Ebias, BP);
  k_reduce<<<1, 64, 0, stream>>>(BP, (float*)d_out);
}

// Round 9
// 45.867 us; speedup vs baseline: 3.5056x; 1.0580x over previous
//
#include <hip/hip_runtime.h>
#include <hip/hip_fp16.h>

typedef _Float16 h16;
typedef h16 v2h __attribute__((ext_vector_type(2)));
typedef h16 v8h __attribute__((ext_vector_type(8)));
typedef float f4 __attribute__((ext_vector_type(4)));

#define NATOM 4096
#define HALF_N 2048
#define K2 2.885390081777927f      // 2/ln2: tanh(x) = 1 - 2/(1+exp2(K2*x))
#define GSCL 0.015625f             // G stored as fp16 * 1/64
#define W0SCL (64.0f * K2)         // W0t staged as fp16 * 64 * K2

// ---- embedding table: E(srcn) tabulated on w = s/(8+|s|), uniform in w ----
#define TBL_N 2048
#define W0MIN_ (-0.201f)
#define DW_ (1.2005f / 2047.0f)
#define RSCALE_ (2047.0f / 1.2005f)

__device__ __forceinline__ float rcp_fast(float x) {
#if __has_builtin(__builtin_amdgcn_rcpf)
  return __builtin_amdgcn_rcpf(x);
#else
  return 1.0f / x;
#endif
}

__device__ __forceinline__ float exp2_fast(float x) {
#if __has_builtin(__builtin_amdgcn_exp2f)
  return __builtin_amdgcn_exp2f(x);
#else
  return exp2f(x);
#endif
}

// input d is already pre-scaled by K2=2/ln2: returns tanh(d/K2)
__device__ __forceinline__ float tanh_e2(float d) {
  float r = rcp_fast(1.0f + exp2_fast(d));
  return fmaf(-2.0f, r, 1.0f);
}

__device__ __forceinline__ v8h lds_v8h(const h16* base, int byte) {
  return *(const v8h*)((const char*)base + byte);
}

// ---------------------------------------------------------------------------
// Setup. Blocks 0..511: embedding table tbl[net][entry][ch] (full MLP).
// Blocks 512..639: transpose fW0 -> W0t (fp16 * 64 * K2).
// Blocks 640..655: pack coords into float4 (one gather per neighbor later).
// ---------------------------------------------------------------------------
__global__ __launch_bounds__(256) void k_setup(
    const float* __restrict__ eW0, const float* __restrict__ eb0,
    const float* __restrict__ eW1, const float* __restrict__ eb1,
    const float* __restrict__ eW2, const float* __restrict__ eb2,
    const float* __restrict__ fW0, const float* __restrict__ coord,
    h16* __restrict__ tbl, h16* __restrict__ W0t, f4* __restrict__ coordP)
{
  const int bid = blockIdx.x, tid = threadIdx.x;
  if (bid < 512) {
    __shared__ float sW1[512];
    __shared__ float sW2[2048];
    __shared__ float sW0s[16], sb0s[16], sb1s[32], sb2s[64];
    const int net = bid >> 7;
    for (int i = tid; i < 512; i += 256) sW1[i] = eW1[net * 512 + i];
    for (int i = tid; i < 2048; i += 256) sW2[i] = eW2[net * 2048 + i];
    if (tid < 16) { sW0s[tid] = eW0[net * 16 + tid]; sb0s[tid] = eb0[net * 16 + tid]; }
    else if (tid >= 32 && tid < 64) sb1s[tid - 32] = eb1[net * 32 + tid - 32];
    else if (tid >= 64 && tid < 128) sb2s[tid - 64] = eb2[net * 64 + tid - 64];
    __syncthreads();

    const int u = (bid & 127) * 256 + tid;     // 0..32767
    const int e = u >> 4, cq = u & 15;
    const float w = W0MIN_ + (float)e * DW_;
    const float s = 8.0f * w * rcp_fast(1.0f - fabsf(w));
    float h0[16];
#pragma unroll
    for (int i = 0; i < 16; ++i)
      h0[i] = tanh_e2(K2 * fmaf(s, sW0s[i], sb0s[i]));
    float h1[32];
#pragma unroll
    for (int j = 0; j < 32; ++j) {
      float a = sb1s[j];
#pragma unroll
      for (int i = 0; i < 16; ++i) a = fmaf(h0[i], sW1[i * 32 + j], a);
      h1[j] = tanh_e2(K2 * a);
    }
    f4 a4 = *(const f4*)&sb2s[cq * 4];
    for (int j = 0; j < 32; ++j) {
      f4 wv4 = *(const f4*)&sW2[j * 64 + cq * 4];
      a4 += h1[j] * wv4;
    }
    union { h16 e4[4]; unsigned long long q; } o;
#pragma unroll
    for (int q = 0; q < 4; ++q) o.e4[q] = (h16)tanh_e2(K2 * a4[q]);
    *(unsigned long long*)&tbl[((size_t)(net * TBL_N + e)) * 64 + cq * 4] = o.q;
  } else if (bid < 640) {
    int idx = (bid - 512) * 256 + tid;          // 0..32767
    int t = idx >> 14, n = idx & 127, k8 = (idx >> 7) & 127;
    union { v8h v; h16 e[8]; } o;
#pragma unroll
    for (int i = 0; i < 8; ++i)
      o.e[i] = (h16)(W0SCL * fW0[(size_t)t * 131072 + (size_t)(k8 * 8 + i) * 128 + n]);
    *(v8h*)&W0t[((size_t)t * 128 + n) * 1024 + k8 * 8] = o.v;
  } else {
    int idx = (bid - 640) * 256 + tid;          // 0..4095
    f4 c;
    c.x = coord[idx]; c.y = coord[NATOM + idx]; c.z = coord[2 * NATOM + idx];
    c.w = 0.0f;
    coordP[idx] = c;
  }
}

// ---------------------------------------------------------------------------
// Kernel 1: 256 thr = 4 waves = 4 atoms. Table-lookup embedding with
// h-interleaved gathers (adjacent lanes -> adjacent 16B), 2-deep software
// pipeline (next chunk's loads issued before current chunk's lerp/MFMA),
// bpermute index broadcast (no ifx LDS). T = Rp@E on the matrix pipe.
// ---------------------------------------------------------------------------
__global__ __launch_bounds__(256, 3) void k_embed(
    const f4* __restrict__ coordP, const float* __restrict__ box,
    const int* __restrict__ nbrs, const float* __restrict__ Tbias,
    const h16* __restrict__ tbl, h16* __restrict__ Gout)
{
  __shared__ h16   E32t[4][64][40] __attribute__((aligned(16)));  // [wv][ch][m]
  __shared__ h16   Rls[4][10][136] __attribute__((aligned(16)));
  __shared__ float Tls[4][10][64];

  const int tid = threadIdx.x;
  const int wv = tid >> 6;
  const int lane = tid & 63;
  const int n = blockIdx.x * 4 + wv;
  const int ti = (n >= HALF_N) ? 1 : 0;
  const int c15 = lane & 15, g4 = lane >> 4;
  const int mloc = lane >> 1, hh = lane & 1;

  // prefetch neighbor indices
  const int jnb0 = nbrs[(size_t)n * 128 + lane];
  const int jnb1 = nbrs[(size_t)n * 128 + 64 + lane];

  // ---- stage A: geometry + R rows + per-lane table index/frac regs ----
  int uf0 = 0, uf1 = 0;
  {
    const float bx = box[0], by = box[1], bz = box[2];
    const float rbx = rcp_fast(bx), rby = rcp_fast(by), rbz = rcp_fast(bz);
    const f4 cme = coordP[n];
#pragma unroll
    for (int nb = 0; nb < 2; ++nb) {
      const int m = nb * 64 + lane;
      const f4 cj = coordP[nb ? jnb1 : jnb0];
      float dx = cj.x - cme.x;
      float dy = cj.y - cme.y;
      float dz = cj.z - cme.z;
      dx -= bx * rintf(dx * rbx);
      dy -= by * rintf(dy * rby);
      dz -= bz * rintf(dz * rbz);
      float r2 = dx * dx + dy * dy + dz * dz;
      bool mk = r2 > 1e-12f;
      float rs = sqrtf(mk ? r2 : 1.0f);
      float r  = mk ? rs : 0.0f;
      float sw = 0.5f * __cosf(0.52359878f * fminf(r, 6.0f)) + 0.5f;
      float invr = mk ? rcp_fast(rs) : 1.0f;
      float sr = (mk && r < 6.0f) ? sw * invr : 0.0f;
      float x0 = dx * invr, x1 = dy * invr, x2 = dz * invr;
      float srn = sr * 20.0f;
      float s   = (sr - 0.1f) * 20.0f;
      Rls[wv][0][m] = (h16)srn;
      Rls[wv][1][m] = (h16)(1.7320508f * srn * x0);
      Rls[wv][2][m] = (h16)(1.7320508f * srn * x1);
      Rls[wv][3][m] = (h16)(1.7320508f * srn * x2);
      Rls[wv][4][m] = (h16)(3.0f * srn * (x0 * x0 - 0.33333334f));
      Rls[wv][5][m] = (h16)(3.0f * srn * (x1 * x1 - 0.33333334f));
      Rls[wv][6][m] = (h16)(3.0f * srn * (x2 * x2 - 0.33333334f));
      Rls[wv][7][m] = (h16)(4.2426407f * srn * (x0 * x1));
      Rls[wv][8][m] = (h16)(4.2426407f * srn * (x1 * x2));
      Rls[wv][9][m] = (h16)(4.2426407f * srn * (x2 * x0));
      float wr = s * rcp_fast(8.0f + fabsf(s));
      float fidx = (wr - W0MIN_) * RSCALE_;
      fidx = fminf(fmaxf(fidx, 0.0f), 2045.99f);
      float i0f = floorf(fidx);
      h16 frh = (h16)(fidx - i0f);
      int uf = ((int)i0f << 16) |
               (int)__builtin_bit_cast(unsigned short, frh);
      if (nb == 0) uf0 = uf; else uf1 = uf;
    }
  }

  union U8 { v8h v; v2h p[4]; h16 e[8]; };
  const int rrow = (c15 < 10) ? c15 : 9;
  const v8h vzero = {};
  f4 tac[4];
#pragma unroll
  for (int nt = 0; nt < 4; ++nt) tac[nt] = (f4){0.f, 0.f, 0.f, 0.f};

  // issue: gather chunk ks's 8 v8h into buf, return frac
  auto issue = [&](int ks, U8* buf) -> float {
    unsigned uu = (unsigned)__builtin_amdgcn_ds_bpermute(
        (((ks & 1) * 32) + mloc) * 4, (ks < 2) ? uf0 : uf1);
    int i0 = (int)(uu >> 16);
    float fr = (float)__builtin_bit_cast(h16, (unsigned short)(uu & 0xffffu));
    const int net = ti * 2 + (ks >> 1);
    const h16* rp = tbl + ((size_t)net * TBL_N + i0) * 64 + hh * 8;
#pragma unroll
    for (int q = 0; q < 4; ++q) {
      buf[q].v     = *(const v8h*)(rp + q * 16);       // row i0
      buf[4 + q].v = *(const v8h*)(rp + 64 + q * 16);  // row i0+1
    }
    return fr;
  };

  // proc: lerp buf -> E32t (transposed), then 4 T-MFMAs for chunk ks
  auto proc = [&](int ks, U8* buf, float fr) {
    v2h fr2; fr2.x = (h16)fr; fr2.y = (h16)fr;
#pragma unroll
    for (int q = 0; q < 4; ++q) {
#pragma unroll
      for (int p = 0; p < 4; ++p) {
        v2h d = buf[4 + q].p[p] - buf[q].p[p];
        v2h e2 = buf[q].p[p] + fr2 * d;
        const int ch = q * 16 + hh * 8 + p * 2;
        E32t[wv][ch][mloc]     = e2.x;
        E32t[wv][ch + 1][mloc] = e2.y;
      }
    }
    v8h ra = *(const v8h*)&Rls[wv][rrow][ks * 32 + g4 * 8];
    if (c15 >= 10) ra = vzero;
#pragma unroll
    for (int nt = 0; nt < 4; ++nt) {
      v8h bf = *(const v8h*)&E32t[wv][nt * 16 + c15][g4 * 8];
      tac[nt] = __builtin_amdgcn_mfma_f32_16x16x32_f16(ra, bf, tac[nt], 0, 0, 0);
    }
  };

  // 2-deep pipeline over the 4 chunks
  U8 bA[8], bB[8];
  float frA = issue(0, bA);
  float frB = issue(1, bB);
  proc(0, bA, frA);
  frA = issue(2, bA);
  proc(1, bB, frB);
  frB = issue(3, bB);
  proc(2, bA, frA);
  proc(3, bB, frB);

  // ---- store T rows < 10 (with /NORM) ----
#pragma unroll
  for (int nt = 0; nt < 4; ++nt)
#pragma unroll
    for (int r = 0; r < 4; ++r) {
      int x = g4 * 4 + r;
      if (x < 10) Tls[wv][x][nt * 16 + c15] = tac[nt][r] * 0.05f;
    }

  // ---- stage G: tensor algebra + store Gflat as fp16/64 ----
  {
    const int c = lane;
    const float tnc  = Tls[wv][0][c] + Tbias[c];
    const float t3c0 = Tls[wv][1][c], t3c1 = Tls[wv][2][c], t3c2 = Tls[wv][3][c];
    const float t6c0 = Tls[wv][4][c], t6c1 = Tls[wv][5][c], t6c2 = Tls[wv][6][c];
    const float t6c3 = Tls[wv][7][c], t6c4 = Tls[wv][8][c], t6c5 = Tls[wv][9][c];
    h16* gp = Gout + (size_t)n * 1024;
#pragma unroll
    for (int a = 0; a < 16; ++a) {
      float g = tnc * (Tls[wv][0][a] + Tbias[a]);
      g += t3c0 * Tls[wv][1][a] + t3c1 * Tls[wv][2][a] + t3c2 * Tls[wv][3][a];
      const float g1x = Tls[wv][1][16 + a], g1y = Tls[wv][2][16 + a], g1z = Tls[wv][3][16 + a];
      g += (g1x * g1x + Tls[wv][4][16 + a]) * t6c0;
      g += (g1y * g1y + Tls[wv][5][16 + a]) * t6c1;
      g += (g1z * g1z + Tls[wv][6][16 + a]) * t6c2;
      g += (1.4142135f * g1x * g1y + Tls[wv][7][16 + a]) * t6c3;
      g += (1.4142135f * g1y * g1z + Tls[wv][8][16 + a]) * t6c4;
      g += (1.4142135f * g1z * g1x + Tls[wv][9][16 + a]) * t6c5;
      gp[a * 64 + c] = (h16)(g * GSCL);
    }
  }
}

// ---------------------------------------------------------------------------
// Kernel 2a: fit layer-0 GEMM on MFMA. grid = 128 atom-tiles(32) x 4 ksplit
// = 512 blocks (2/CU). Wave = 16a x 64n quadrant. XOR-swizzled LDS.
// ---------------------------------------------------------------------------
__global__ __launch_bounds__(256, 2) void k_fit0(
    const h16* __restrict__ G16, const h16* __restrict__ W0t,
    float* __restrict__ P)
{
  __shared__ h16 As[32][64]  __attribute__((aligned(16)));
  __shared__ h16 Bts[128][64] __attribute__((aligned(16)));
  const int tid = threadIdx.x;
  const int tile = blockIdx.x >> 2;
  const int ks = blockIdx.x & 3;
  const int abase = tile * 32;
  const int kbase = ks * 256;
  const int t = (abase >= HALF_N) ? 1 : 0;
  const int lane = tid & 63, w = tid >> 6;
  const int c15 = lane & 15, g4 = lane >> 4;
  const int mrow = (w & 1) * 16, nh = (w >> 1) * 64;

  f4 acc[4];
#pragma unroll
  for (int nt = 0; nt < 4; ++nt) acc[nt] = (f4){0.f, 0.f, 0.f, 0.f};

  for (int kc = 0; kc < 4; ++kc) {
    const int kb = kbase + kc * 64;
    __syncthreads();
    {
      int r = tid >> 3, c8 = tid & 7;
      v8h v = *(const v8h*)&G16[(size_t)(abase + r) * 1024 + kb + c8 * 8];
      int byte = r * 128 + ((c8 * 16) ^ ((r & 7) << 4));
      *(v8h*)((char*)&As[0][0] + byte) = v;
    }
#pragma unroll
    for (int u = 0; u < 4; ++u) {
      int idx = u * 256 + tid;
      int nr = idx >> 3, c8 = idx & 7;
      v8h v = *(const v8h*)&W0t[((size_t)t * 128 + nr) * 1024 + kb + c8 * 8];
      int byte = nr * 128 + ((c8 * 16) ^ ((nr & 7) << 4));
      *(v8h*)((char*)&Bts[0][0] + byte) = v;
    }
    __syncthreads();
#pragma unroll
    for (int ksub = 0; ksub < 2; ++ksub) {
      const int ar = mrow + c15;
      const int koff = (ksub * 32 + g4 * 8) * 2;
      v8h a = lds_v8h(&As[0][0], ar * 128 + (koff ^ ((ar & 7) << 4)));
#pragma unroll
      for (int nt = 0; nt < 4; ++nt) {
        const int br = nh + nt * 16 + c15;
        v8h b = lds_v8h(&Bts[0][0], br * 128 + (koff ^ ((br & 7) << 4)));
        acc[nt] = __builtin_amdgcn_mfma_f32_16x16x32_f16(a, b, acc[nt], 0, 0, 0);
      }
    }
  }

  float* Pk = P + (size_t)ks * 4096 * 128;
#pragma unroll
  for (int nt = 0; nt < 4; ++nt)
#pragma unroll
    for (int r = 0; r < 4; ++r)
      Pk[(size_t)(abase + mrow + g4 * 4 + r) * 128 + nh + nt * 16 + c15] = acc[nt][r];
}

// ---------------------------------------------------------------------------
// Kernel 2b: combine 4 K-split partials (already K2-scaled) + layers 1-2 +
// per-block energy partial. grid = 512 x 8 atoms.
// ---------------------------------------------------------------------------
__global__ __launch_bounds__(256, 4) void k_fit1(
    const float* __restrict__ P,
    const float* __restrict__ fb0, const float* __restrict__ fW1,
    const float* __restrict__ fb1, const float* __restrict__ fW2,
    const float* __restrict__ fb2, const float* __restrict__ Ebias,
    float* __restrict__ BP)
{
  __shared__ float ht[128][12];
  __shared__ float Ws1[32][128];
  __shared__ float red[8][33];
  const int tid = threadIdx.x;
  const int abase = blockIdx.x * 8;
  const int t = (abase >= HALF_N) ? 1 : 0;

  {
    const int a = tid >> 5, j0 = (tid & 31) * 4;
    f4 s = K2 * (*(const f4*)&fb0[t * 128 + j0]);
#pragma unroll
    for (int ks = 0; ks < 4; ++ks)
      s += *(const f4*)&P[((size_t)ks * 4096 + abase + a) * 128 + j0];
    ht[j0 + 0][a] = tanh_e2(s.x);
    ht[j0 + 1][a] = tanh_e2(s.y);
    ht[j0 + 2][a] = tanh_e2(s.z);
    ht[j0 + 3][a] = tanh_e2(s.w);
  }

  const int ab = tid & 7, jb = tid >> 3;
  const int j0g = jb * 4;
  f4 acc = K2 * (*(const f4*)&fb1[t * 128 + j0g]);
  for (int kc = 0; kc < 4; ++kc) {
    __syncthreads();
#pragma unroll
    for (int u = 0; u < 2; ++u) {
      int idx = (u * 256 + tid) * 8;
      int kk = idx >> 7, j = idx & 127;
      *(f4*)&Ws1[kk][j] =
          K2 * (*(const f4*)&fW1[(size_t)t * 16384 + (size_t)(kc * 32 + kk) * 128 + j]);
      *(f4*)&Ws1[kk][j + 4] =
          K2 * (*(const f4*)&fW1[(size_t)t * 16384 + (size_t)(kc * 32 + kk) * 128 + j + 4]);
    }
    __syncthreads();
    for (int kk = 0; kk < 32; ++kk) {
      float av = ht[kc * 32 + kk][ab];
      f4 w = *(const f4*)&Ws1[kk][j0g];
      acc += av * w;
    }
  }

  float f = tanh_e2(acc.x) * fW2[t * 128 + j0g + 0]
          + tanh_e2(acc.y) * fW2[t * 128 + j0g + 1]
          + tanh_e2(acc.z) * fW2[t * 128 + j0g + 2]
          + tanh_e2(acc.w) * fW2[t * 128 + j0g + 3];
  red[ab][jb] = f;
  __syncthreads();
  if (tid < 64) {
    const int a = tid & 7, j4 = tid >> 3;
    float v = red[a][j4 * 4] + red[a][j4 * 4 + 1]
            + red[a][j4 * 4 + 2] + red[a][j4 * 4 + 3];
    v += __shfl_xor(v, 32);
    v += __shfl_xor(v, 16);
    v += __shfl_xor(v, 8);
    v += __shfl_xor(v, 4);
    v += __shfl_xor(v, 2);
    v += __shfl_xor(v, 1);
    if (tid == 0) BP[blockIdx.x] = v + 8.0f * (fb2[t] + Ebias[t]);
  }
}

__global__ __launch_bounds__(64) void k_reduce(const float* __restrict__ BP,
                                               float* __restrict__ out)
{
  int tid = threadIdx.x;
  float s = 0.0f;
#pragma unroll
  for (int u = 0; u < 8; ++u) s += BP[tid + 64 * u];
  s += __shfl_xor(s, 32);
  s += __shfl_xor(s, 16);
  s += __shfl_xor(s, 8);
  s += __shfl_xor(s, 4);
  s += __shfl_xor(s, 2);
  s += __shfl_xor(s, 1);
  if (tid == 0) out[0] = s;
}

extern "C" void kernel_launch(void* const* d_in, const int* in_sizes, int n_in,
                              void* d_out, int out_size, void* d_ws, size_t ws_size,
                              hipStream_t stream) {
  const float* coord = (const float*)d_in[0];
  const float* box   = (const float*)d_in[1];
  const int*   nbrs  = (const int*)d_in[2];
  const float* eW0   = (const float*)d_in[3];
  const float* eb0   = (const float*)d_in[4];
  const float* eW1   = (const float*)d_in[5];
  const float* eb1   = (const float*)d_in[6];
  const float* eW2   = (const float*)d_in[7];
  const float* eb2   = (const float*)d_in[8];
  const float* Tbias = (const float*)d_in[9];
  const float* fW0   = (const float*)d_in[10];
  const float* fb0   = (const float*)d_in[11];
  const float* fW1   = (const float*)d_in[12];
  const float* fb1   = (const float*)d_in[13];
  const float* fW2   = (const float*)d_in[14];
  const float* fb2   = (const float*)d_in[15];
  const float* Ebias = (const float*)d_in[16];

  h16*   G16 = (h16*)d_ws;                                           // 8 MB
  float* P   = (float*)((char*)d_ws + (size_t)8 * 1024 * 1024);      // 8 MB
  h16*   W0t = (h16*)((char*)d_ws + (size_t)16 * 1024 * 1024);       // 512 KB
  float* BP  = (float*)((char*)d_ws + (size_t)17 * 1024 * 1024);     // 2 KB
  h16*   tbl = (h16*)((char*)d_ws + (size_t)18 * 1024 * 1024);       // 1 MB
  f4*    cP  = (f4*)((char*)d_ws + (size_t)19 * 1024 * 1024);        // 64 KB

  k_setup<<<656, 256, 0, stream>>>(eW0, eb0, eW1, eb1, eW2, eb2, fW0, coord,
                                   tbl, W0t, cP);
  k_embed<<<1024, 256, 0, stream>>>(cP, box, nbrs, Tbias, tbl, G16);
  k_fit0<<<512, 256, 0, stream>>>(G16, W0t, P);
  k_fit1<<<512, 256, 0, stream>>>(P, fb0, fW1, fb1, fW2, fb2, Ebias, BP);
  k_reduce<<<1, 64, 0, stream>>>(BP, (float*)d_out);
}

// Round 10
// 44.842 us; speedup vs baseline: 3.5856x; 1.0228x over previous
//
#include <hip/hip_runtime.h>
#include <hip/hip_fp16.h>

typedef _Float16 h16;
typedef h16 v2h __attribute__((ext_vector_type(2)));
typedef h16 v8h __attribute__((ext_vector_type(8)));
typedef float f4 __attribute__((ext_vector_type(4)));

#define NATOM 4096
#define HALF_N 2048
#define K2 2.885390081777927f      // 2/ln2: tanh(x) = 1 - 2/(1+exp2(K2*x))
#define GSCL 0.015625f             // G stored as fp16 * 1/64
#define W0SCL (64.0f * K2)         // W0t staged as fp16 * 64 * K2

// ---- embedding table: E(srcn) tabulated on w = s/(8+|s|), uniform in w ----
#define TBL_N 2048
#define W0MIN_ (-0.201f)
#define DW_ (1.2005f / 2047.0f)
#define RSCALE_ (2047.0f / 1.2005f)

__device__ __forceinline__ float rcp_fast(float x) {
#if __has_builtin(__builtin_amdgcn_rcpf)
  return __builtin_amdgcn_rcpf(x);
#else
  return 1.0f / x;
#endif
}

__device__ __forceinline__ float exp2_fast(float x) {
#if __has_builtin(__builtin_amdgcn_exp2f)
  return __builtin_amdgcn_exp2f(x);
#else
  return exp2f(x);
#endif
}

// input d is already pre-scaled by K2=2/ln2: returns tanh(d/K2)
__device__ __forceinline__ float tanh_e2(float d) {
  float r = rcp_fast(1.0f + exp2_fast(d));
  return fmaf(-2.0f, r, 1.0f);
}

__device__ __forceinline__ v8h lds_v8h(const h16* base, int byte) {
  return *(const v8h*)((const char*)base + byte);
}

// ---------------------------------------------------------------------------
// Setup. Blocks 0..511: embedding table tbl[net][entry][ch] (full MLP).
// Blocks 512..639: transpose fW0 -> W0t (fp16 * 64 * K2).
// Blocks 640..655: pack coords into float4.
// Blocks 656..671: transpose fW1 -> W1t (fp16 * K2) for fused fit layer 1.
// ---------------------------------------------------------------------------
__global__ __launch_bounds__(256) void k_setup(
    const float* __restrict__ eW0, const float* __restrict__ eb0,
    const float* __restrict__ eW1, const float* __restrict__ eb1,
    const float* __restrict__ eW2, const float* __restrict__ eb2,
    const float* __restrict__ fW0, const float* __restrict__ fW1,
    const float* __restrict__ coord,
    h16* __restrict__ tbl, h16* __restrict__ W0t, h16* __restrict__ W1t,
    f4* __restrict__ coordP)
{
  const int bid = blockIdx.x, tid = threadIdx.x;
  if (bid < 512) {
    __shared__ float sW1[512];
    __shared__ float sW2[2048];
    __shared__ float sW0s[16], sb0s[16], sb1s[32], sb2s[64];
    const int net = bid >> 7;
    for (int i = tid; i < 512; i += 256) sW1[i] = eW1[net * 512 + i];
    for (int i = tid; i < 2048; i += 256) sW2[i] = eW2[net * 2048 + i];
    if (tid < 16) { sW0s[tid] = eW0[net * 16 + tid]; sb0s[tid] = eb0[net * 16 + tid]; }
    else if (tid >= 32 && tid < 64) sb1s[tid - 32] = eb1[net * 32 + tid - 32];
    else if (tid >= 64 && tid < 128) sb2s[tid - 64] = eb2[net * 64 + tid - 64];
    __syncthreads();

    const int u = (bid & 127) * 256 + tid;     // 0..32767
    const int e = u >> 4, cq = u & 15;
    const float w = W0MIN_ + (float)e * DW_;
    const float s = 8.0f * w * rcp_fast(1.0f - fabsf(w));
    float h0[16];
#pragma unroll
    for (int i = 0; i < 16; ++i)
      h0[i] = tanh_e2(K2 * fmaf(s, sW0s[i], sb0s[i]));
    float h1[32];
#pragma unroll
    for (int j = 0; j < 32; ++j) {
      float a = sb1s[j];
#pragma unroll
      for (int i = 0; i < 16; ++i) a = fmaf(h0[i], sW1[i * 32 + j], a);
      h1[j] = tanh_e2(K2 * a);
    }
    f4 a4 = *(const f4*)&sb2s[cq * 4];
    for (int j = 0; j < 32; ++j) {
      f4 wv4 = *(const f4*)&sW2[j * 64 + cq * 4];
      a4 += h1[j] * wv4;
    }
    union { h16 e4[4]; unsigned long long q; } o;
#pragma unroll
    for (int q = 0; q < 4; ++q) o.e4[q] = (h16)tanh_e2(K2 * a4[q]);
    *(unsigned long long*)&tbl[((size_t)(net * TBL_N + e)) * 64 + cq * 4] = o.q;
  } else if (bid < 640) {
    int idx = (bid - 512) * 256 + tid;          // 0..32767
    int t = idx >> 14, n = idx & 127, k8 = (idx >> 7) & 127;
    union { v8h v; h16 e[8]; } o;
#pragma unroll
    for (int i = 0; i < 8; ++i)
      o.e[i] = (h16)(W0SCL * fW0[(size_t)t * 131072 + (size_t)(k8 * 8 + i) * 128 + n]);
    *(v8h*)&W0t[((size_t)t * 128 + n) * 1024 + k8 * 8] = o.v;
  } else if (bid < 656) {
    int idx = (bid - 640) * 256 + tid;          // 0..4095
    f4 c;
    c.x = coord[idx]; c.y = coord[NATOM + idx]; c.z = coord[2 * NATOM + idx];
    c.w = 0.0f;
    coordP[idx] = c;
  } else {
    int idx = (bid - 656) * 256 + tid;          // 0..4095
    int t = idx >> 11, rem = idx & 2047;
    int n = rem >> 4, k8 = rem & 15;
    union { v8h v; h16 e[8]; } o;
#pragma unroll
    for (int i = 0; i < 8; ++i)
      o.e[i] = (h16)(K2 * fW1[(size_t)t * 16384 + (size_t)(k8 * 8 + i) * 128 + n]);
    *(v8h*)&W1t[((size_t)t * 128 + n) * 128 + k8 * 8] = o.v;
  }
}

// ---------------------------------------------------------------------------
// Kernel 1: 256 thr = 4 waves = 4 atoms. Table-lookup embedding, 2-deep
// pipelined gathers, T = Rp@E on the matrix pipe. launch_bounds(256,2):
// the 2x8-v8h pipeline buffers need ~64 VGPR -> the (256,3) cap spilled.
// ---------------------------------------------------------------------------
__global__ __launch_bounds__(256, 2) void k_embed(
    const f4* __restrict__ coordP, const float* __restrict__ box,
    const int* __restrict__ nbrs, const float* __restrict__ Tbias,
    const h16* __restrict__ tbl, h16* __restrict__ Gout)
{
  __shared__ h16   E32t[4][64][40] __attribute__((aligned(16)));  // [wv][ch][m]
  __shared__ h16   Rls[4][10][136] __attribute__((aligned(16)));
  __shared__ float Tls[4][10][64];

  const int tid = threadIdx.x;
  const int wv = tid >> 6;
  const int lane = tid & 63;
  const int n = blockIdx.x * 4 + wv;
  const int ti = (n >= HALF_N) ? 1 : 0;
  const int c15 = lane & 15, g4 = lane >> 4;
  const int mloc = lane >> 1, hh = lane & 1;

  const int jnb0 = nbrs[(size_t)n * 128 + lane];
  const int jnb1 = nbrs[(size_t)n * 128 + 64 + lane];

  int uf0 = 0, uf1 = 0;
  {
    const float bx = box[0], by = box[1], bz = box[2];
    const float rbx = rcp_fast(bx), rby = rcp_fast(by), rbz = rcp_fast(bz);
    const f4 cme = coordP[n];
#pragma unroll
    for (int nb = 0; nb < 2; ++nb) {
      const int m = nb * 64 + lane;
      const f4 cj = coordP[nb ? jnb1 : jnb0];
      float dx = cj.x - cme.x;
      float dy = cj.y - cme.y;
      float dz = cj.z - cme.z;
      dx -= bx * rintf(dx * rbx);
      dy -= by * rintf(dy * rby);
      dz -= bz * rintf(dz * rbz);
      float r2 = dx * dx + dy * dy + dz * dz;
      bool mk = r2 > 1e-12f;
      float rs = sqrtf(mk ? r2 : 1.0f);
      float r  = mk ? rs : 0.0f;
      float sw = 0.5f * __cosf(0.52359878f * fminf(r, 6.0f)) + 0.5f;
      float invr = mk ? rcp_fast(rs) : 1.0f;
      float sr = (mk && r < 6.0f) ? sw * invr : 0.0f;
      float x0 = dx * invr, x1 = dy * invr, x2 = dz * invr;
      float srn = sr * 20.0f;
      float s   = (sr - 0.1f) * 20.0f;
      Rls[wv][0][m] = (h16)srn;
      Rls[wv][1][m] = (h16)(1.7320508f * srn * x0);
      Rls[wv][2][m] = (h16)(1.7320508f * srn * x1);
      Rls[wv][3][m] = (h16)(1.7320508f * srn * x2);
      Rls[wv][4][m] = (h16)(3.0f * srn * (x0 * x0 - 0.33333334f));
      Rls[wv][5][m] = (h16)(3.0f * srn * (x1 * x1 - 0.33333334f));
      Rls[wv][6][m] = (h16)(3.0f * srn * (x2 * x2 - 0.33333334f));
      Rls[wv][7][m] = (h16)(4.2426407f * srn * (x0 * x1));
      Rls[wv][8][m] = (h16)(4.2426407f * srn * (x1 * x2));
      Rls[wv][9][m] = (h16)(4.2426407f * srn * (x2 * x0));
      float wr = s * rcp_fast(8.0f + fabsf(s));
      float fidx = (wr - W0MIN_) * RSCALE_;
      fidx = fminf(fmaxf(fidx, 0.0f), 2045.99f);
      float i0f = floorf(fidx);
      h16 frh = (h16)(fidx - i0f);
      int uf = ((int)i0f << 16) |
               (int)__builtin_bit_cast(unsigned short, frh);
      if (nb == 0) uf0 = uf; else uf1 = uf;
    }
  }

  union U8 { v8h v; v2h p[4]; h16 e[8]; };
  const int rrow = (c15 < 10) ? c15 : 9;
  const v8h vzero = {};
  f4 tac[4];
#pragma unroll
  for (int nt = 0; nt < 4; ++nt) tac[nt] = (f4){0.f, 0.f, 0.f, 0.f};

  auto issue = [&](int ks, U8* buf) -> float {
    unsigned uu = (unsigned)__builtin_amdgcn_ds_bpermute(
        (((ks & 1) * 32) + mloc) * 4, (ks < 2) ? uf0 : uf1);
    int i0 = (int)(uu >> 16);
    float fr = (float)__builtin_bit_cast(h16, (unsigned short)(uu & 0xffffu));
    const int net = ti * 2 + (ks >> 1);
    const h16* rp = tbl + ((size_t)net * TBL_N + i0) * 64 + hh * 8;
#pragma unroll
    for (int q = 0; q < 4; ++q) {
      buf[q].v     = *(const v8h*)(rp + q * 16);       // row i0
      buf[4 + q].v = *(const v8h*)(rp + 64 + q * 16);  // row i0+1
    }
    return fr;
  };

  auto proc = [&](int ks, U8* buf, float fr) {
    v2h fr2; fr2.x = (h16)fr; fr2.y = (h16)fr;
#pragma unroll
    for (int q = 0; q < 4; ++q) {
#pragma unroll
      for (int p = 0; p < 4; ++p) {
        v2h d = buf[4 + q].p[p] - buf[q].p[p];
        v2h e2 = buf[q].p[p] + fr2 * d;
        const int ch = q * 16 + hh * 8 + p * 2;
        E32t[wv][ch][mloc]     = e2.x;
        E32t[wv][ch + 1][mloc] = e2.y;
      }
    }
    v8h ra = *(const v8h*)&Rls[wv][rrow][ks * 32 + g4 * 8];
    if (c15 >= 10) ra = vzero;
#pragma unroll
    for (int nt = 0; nt < 4; ++nt) {
      v8h bf = *(const v8h*)&E32t[wv][nt * 16 + c15][g4 * 8];
      tac[nt] = __builtin_amdgcn_mfma_f32_16x16x32_f16(ra, bf, tac[nt], 0, 0, 0);
    }
  };

  U8 bA[8], bB[8];
  float frA = issue(0, bA);
  float frB = issue(1, bB);
  proc(0, bA, frA);
  frA = issue(2, bA);
  proc(1, bB, frB);
  frB = issue(3, bB);
  proc(2, bA, frA);
  proc(3, bB, frB);

#pragma unroll
  for (int nt = 0; nt < 4; ++nt)
#pragma unroll
    for (int r = 0; r < 4; ++r) {
      int x = g4 * 4 + r;
      if (x < 10) Tls[wv][x][nt * 16 + c15] = tac[nt][r] * 0.05f;
    }

  {
    const int c = lane;
    const float tnc  = Tls[wv][0][c] + Tbias[c];
    const float t3c0 = Tls[wv][1][c], t3c1 = Tls[wv][2][c], t3c2 = Tls[wv][3][c];
    const float t6c0 = Tls[wv][4][c], t6c1 = Tls[wv][5][c], t6c2 = Tls[wv][6][c];
    const float t6c3 = Tls[wv][7][c], t6c4 = Tls[wv][8][c], t6c5 = Tls[wv][9][c];
    h16* gp = Gout + (size_t)n * 1024;
#pragma unroll
    for (int a = 0; a < 16; ++a) {
      float g = tnc * (Tls[wv][0][a] + Tbias[a]);
      g += t3c0 * Tls[wv][1][a] + t3c1 * Tls[wv][2][a] + t3c2 * Tls[wv][3][a];
      const float g1x = Tls[wv][1][16 + a], g1y = Tls[wv][2][16 + a], g1z = Tls[wv][3][16 + a];
      g += (g1x * g1x + Tls[wv][4][16 + a]) * t6c0;
      g += (g1y * g1y + Tls[wv][5][16 + a]) * t6c1;
      g += (g1z * g1z + Tls[wv][6][16 + a]) * t6c2;
      g += (1.4142135f * g1x * g1y + Tls[wv][7][16 + a]) * t6c3;
      g += (1.4142135f * g1y * g1z + Tls[wv][8][16 + a]) * t6c4;
      g += (1.4142135f * g1z * g1x + Tls[wv][9][16 + a]) * t6c5;
      gp[a * 64 + c] = (h16)(g * GSCL);
    }
  }
}

// ---------------------------------------------------------------------------
// Fused fit: 128 blocks x 32 atoms, full K=1024 (no ksplit, no P roundtrip).
// Layer 0: double-buffered K-stream MFMA GEMM (W0t from L2, 256KB/block).
// Layer 1: MFMA vs W1t staged once in LDS. Layer 2 + energy partial: VALU.
// ---------------------------------------------------------------------------
__global__ __launch_bounds__(256) void k_fit(
    const h16* __restrict__ G16, const h16* __restrict__ W0t,
    const h16* __restrict__ W1t,
    const float* __restrict__ fb0, const float* __restrict__ fb1,
    const float* __restrict__ fW2, const float* __restrict__ fb2,
    const float* __restrict__ Ebias, float* __restrict__ BP)
{
  __shared__ h16 As[2][32][64]  __attribute__((aligned(16)));   // 8 KB
  __shared__ h16 Bs[2][128][64] __attribute__((aligned(16)));   // 32 KB
  __shared__ h16 ht[32][128]    __attribute__((aligned(16)));   // 8 KB
  __shared__ h16 W1s[128][128]  __attribute__((aligned(16)));   // 32 KB
  __shared__ float red[32][33];

  const int tid = threadIdx.x;
  const int abase = blockIdx.x * 32;
  const int t = (abase >= HALF_N) ? 1 : 0;
  const int lane = tid & 63, w = tid >> 6;
  const int c15 = lane & 15, g4 = lane >> 4;
  const int rt = w & 1, ng = w >> 1;   // wave: atoms rt*16..+15, cols ng*64..+63

  // hoisted per-lane constants (n = ng*64 + nt*16 + c15)
  float fb0v[4], b1v[4], w2v[4];
#pragma unroll
  for (int nt = 0; nt < 4; ++nt) {
    const int nn = ng * 64 + nt * 16 + c15;
    fb0v[nt] = K2 * fb0[t * 128 + nn];
    b1v[nt]  = K2 * fb1[t * 128 + nn];
    w2v[nt]  = fW2[t * 128 + nn];
  }

  // stage W1s early (completes under the layer-0 loop's barriers)
#pragma unroll
  for (int u = 0; u < 8; ++u) {
    int idx = u * 256 + tid;           // 0..2047 v8h
    int nrow = idx >> 4, c8 = idx & 15;
    v8h v = *(const v8h*)&W1t[((size_t)t * 128 + nrow) * 128 + c8 * 8];
    int byte = nrow * 256 + ((c8 * 16) ^ ((nrow & 7) << 4));
    *(v8h*)((char*)&W1s[0][0] + byte) = v;
  }

  f4 acc[4];
#pragma unroll
  for (int nt = 0; nt < 4; ++nt) acc[nt] = (f4){0.f, 0.f, 0.f, 0.f};

  auto stageK = [&](int kc, int p) {
    {
      int r = tid >> 3, c8 = tid & 7;
      v8h v = *(const v8h*)&G16[(size_t)(abase + r) * 1024 + kc * 64 + c8 * 8];
      int byte = r * 128 + ((c8 * 16) ^ ((r & 7) << 4));
      *(v8h*)((char*)&As[p][0][0] + byte) = v;
    }
#pragma unroll
    for (int u = 0; u < 4; ++u) {
      int idx = u * 256 + tid;
      int nrow = idx >> 3, c8 = idx & 7;
      v8h v = *(const v8h*)&W0t[((size_t)t * 128 + nrow) * 1024 + kc * 64 + c8 * 8];
      int byte = nrow * 128 + ((c8 * 16) ^ ((nrow & 7) << 4));
      *(v8h*)((char*)&Bs[p][0][0] + byte) = v;
    }
  };

  stageK(0, 0);
  __syncthreads();
  for (int kc = 0; kc < 16; ++kc) {
    const int p = kc & 1;
    if (kc < 15) stageK(kc + 1, p ^ 1);
#pragma unroll
    for (int ksub = 0; ksub < 2; ++ksub) {
      const int ar = rt * 16 + c15;
      const int koff = (ksub * 32 + g4 * 8) * 2;
      v8h a = lds_v8h(&As[p][0][0], ar * 128 + (koff ^ ((ar & 7) << 4)));
#pragma unroll
      for (int nt = 0; nt < 4; ++nt) {
        const int br = ng * 64 + nt * 16 + c15;
        v8h b = lds_v8h(&Bs[p][0][0], br * 128 + (koff ^ ((br & 7) << 4)));
        acc[nt] = __builtin_amdgcn_mfma_f32_16x16x32_f16(a, b, acc[nt], 0, 0, 0);
      }
    }
    __syncthreads();
  }

  // layer-0 epilogue: h0 = tanh -> ht (fp16, swizzled rows)
#pragma unroll
  for (int nt = 0; nt < 4; ++nt)
#pragma unroll
    for (int r = 0; r < 4; ++r) {
      int a = rt * 16 + g4 * 4 + r;
      int k = ng * 64 + nt * 16 + c15;
      h16 hv = (h16)tanh_e2(acc[nt][r] + fb0v[nt]);
      int byte = a * 256 + ((k * 2) ^ ((a & 7) << 4));
      *((h16*)((char*)&ht[0][0] + byte)) = hv;
    }
  __syncthreads();

  // layer 1: h1 = tanh(h0 @ W1) via MFMA
  f4 acc2[4];
#pragma unroll
  for (int nt = 0; nt < 4; ++nt) acc2[nt] = (f4){0.f, 0.f, 0.f, 0.f};
#pragma unroll
  for (int ks2 = 0; ks2 < 4; ++ks2) {
    const int ar = rt * 16 + c15;
    const int koff = (ks2 * 32 + g4 * 8) * 2;
    v8h a = lds_v8h(&ht[0][0], ar * 256 + (koff ^ ((ar & 7) << 4)));
#pragma unroll
    for (int nt = 0; nt < 4; ++nt) {
      const int br = ng * 64 + nt * 16 + c15;
      v8h b = lds_v8h(&W1s[0][0], br * 256 + (koff ^ ((br & 7) << 4)));
      acc2[nt] = __builtin_amdgcn_mfma_f32_16x16x32_f16(a, b, acc2[nt], 0, 0, 0);
    }
  }

  // layer 2 + per-block energy partial
#pragma unroll
  for (int r = 0; r < 4; ++r) {
    float v = 0.0f;
#pragma unroll
    for (int nt = 0; nt < 4; ++nt)
      v += tanh_e2(acc2[nt][r] + b1v[nt]) * w2v[nt];
    red[rt * 16 + g4 * 4 + r][ng * 16 + c15] = v;
  }
  __syncthreads();
  if (tid < 64) {
    const int a = tid & 31, half = tid >> 5;
    float s = 0.0f;
#pragma unroll
    for (int c = 0; c < 16; ++c) s += red[a][half * 16 + c];
    s += __shfl_xor(s, 32);
    s += __shfl_xor(s, 16);
    s += __shfl_xor(s, 8);
    s += __shfl_xor(s, 4);
    s += __shfl_xor(s, 2);
    s += __shfl_xor(s, 1);
    if (tid == 0) BP[blockIdx.x] = s + 32.0f * (fb2[t] + Ebias[t]);
  }
}

__global__ __launch_bounds__(64) void k_reduce(const float* __restrict__ BP,
                                               float* __restrict__ out)
{
  int tid = threadIdx.x;
  float s = BP[tid] + BP[tid + 64];
  s += __shfl_xor(s, 32);
  s += __shfl_xor(s, 16);
  s += __shfl_xor(s, 8);
  s += __shfl_xor(s, 4);
  s += __shfl_xor(s, 2);
  s += __shfl_xor(s, 1);
  if (tid == 0) out[0] = s;
}

extern "C" void kernel_launch(void* const* d_in, const int* in_sizes, int n_in,
                              void* d_out, int out_size, void* d_ws, size_t ws_size,
                              hipStream_t stream) {
  const float* coord = (const float*)d_in[0];
  const float* box   = (const float*)d_in[1];
  const int*   nbrs  = (const int*)d_in[2];
  const float* eW0   = (const float*)d_in[3];
  const float* eb0   = (const float*)d_in[4];
  const float* eW1   = (const float*)d_in[5];
  const float* eb1   = (const float*)d_in[6];
  const float* eW2   = (const float*)d_in[7];
  const float* eb2   = (const float*)d_in[8];
  const float* Tbias = (const float*)d_in[9];
  const float* fW0   = (const float*)d_in[10];
  const float* fb0   = (const float*)d_in[11];
  const float* fW1   = (const float*)d_in[12];
  const float* fb1   = (const float*)d_in[13];
  const float* fW2   = (const float*)d_in[14];
  const float* fb2   = (const float*)d_in[15];
  const float* Ebias = (const float*)d_in[16];

  char* ws = (char*)d_ws;
  h16*   G16 = (h16*)ws;                                   // 8 MB
  h16*   W0t = (h16*)(ws + (size_t)8  * 1024 * 1024);      // 512 KB
  h16*   W1t = (h16*)(ws + (size_t)9  * 1024 * 1024);      // 64 KB
  h16*   tbl = (h16*)(ws + (size_t)10 * 1024 * 1024);      // 1 MB
  f4*    cP  = (f4*)(ws + (size_t)11 * 1024 * 1024);       // 64 KB
  float* BP  = (float*)(ws + (size_t)12 * 1024 * 1024);    // 512 B

  k_setup<<<672, 256, 0, stream>>>(eW0, eb0, eW1, eb1, eW2, eb2, fW0, fW1,
                                   coord, tbl, W0t, W1t, cP);
  k_embed<<<1024, 256, 0, stream>>>(cP, box, nbrs, Tbias, tbl, G16);
  k_fit<<<128, 256, 0, stream>>>(G16, W0t, W1t, fb0, fb1, fW2, fb2, Ebias, BP);
  k_reduce<<<1, 64, 0, stream>>>(BP, (float*)d_out);
}

// Round 12
// 42.696 us; speedup vs baseline: 3.7659x; 1.0503x over previous
//
#include <hip/hip_runtime.h>
#include <hip/hip_fp16.h>

typedef _Float16 h16;
typedef h16 v2h __attribute__((ext_vector_type(2)));
typedef h16 v4h __attribute__((ext_vector_type(4)));
typedef h16 v8h __attribute__((ext_vector_type(8)));
typedef float f4 __attribute__((ext_vector_type(4)));

#define NATOM 4096
#define HALF_N 2048
#define K2 2.885390081777927f      // 2/ln2: tanh(x) = 1 - 2/(1+exp2(K2*x))
#define GSCL 0.015625f             // G stored as fp16 * 1/64
#define W0SCL (64.0f * K2)         // W0t staged as fp16 * 64 * K2
#define USCL 0.0625f               // U rows stored /16 (fp16 headroom)
#define GOUTS (GSCL / USCL)        // 0.25: G16 = (U/16 · V) * 0.25 = G/64

// ---- embedding table: E(srcn) tabulated on w = s/(8+|s|), uniform in w ----
#define TBL_N 2048
#define W0MIN_ (-0.201f)
#define DW_ (1.2005f / 2047.0f)
#define RSCALE_ (2047.0f / 1.2005f)

__device__ __forceinline__ float rcp_fast(float x) {
#if __has_builtin(__builtin_amdgcn_rcpf)
  return __builtin_amdgcn_rcpf(x);
#else
  return 1.0f / x;
#endif
}

__device__ __forceinline__ float exp2_fast(float x) {
#if __has_builtin(__builtin_amdgcn_exp2f)
  return __builtin_amdgcn_exp2f(x);
#else
  return exp2f(x);
#endif
}

// input d is already pre-scaled by K2=2/ln2: returns tanh(d/K2)
__device__ __forceinline__ float tanh_e2(float d) {
  float r = rcp_fast(1.0f + exp2_fast(d));
  return fmaf(-2.0f, r, 1.0f);
}

__device__ __forceinline__ v8h lds_v8h(const h16* base, int byte) {
  return *(const v8h*)((const char*)base + byte);
}

// ---------------------------------------------------------------------------
// Setup. Blocks 0..511: embedding table. 512..639: fW0 -> W0t transpose.
// 640..655: coord float4 pack. 656..671: fW1 -> W1t transpose.
// ---------------------------------------------------------------------------
__global__ __launch_bounds__(256) void k_setup(
    const float* __restrict__ eW0, const float* __restrict__ eb0,
    const float* __restrict__ eW1, const float* __restrict__ eb1,
    const float* __restrict__ eW2, const float* __restrict__ eb2,
    const float* __restrict__ fW0, const float* __restrict__ fW1,
    const float* __restrict__ coord,
    h16* __restrict__ tbl, h16* __restrict__ W0t, h16* __restrict__ W1t,
    f4* __restrict__ coordP)
{
  const int bid = blockIdx.x, tid = threadIdx.x;
  if (bid < 512) {
    __shared__ float sW1[512];
    __shared__ float sW2[2048];
    __shared__ float sW0s[16], sb0s[16], sb1s[32], sb2s[64];
    const int net = bid >> 7;
    for (int i = tid; i < 512; i += 256) sW1[i] = eW1[net * 512 + i];
    for (int i = tid; i < 2048; i += 256) sW2[i] = eW2[net * 2048 + i];
    if (tid < 16) { sW0s[tid] = eW0[net * 16 + tid]; sb0s[tid] = eb0[net * 16 + tid]; }
    else if (tid >= 32 && tid < 64) sb1s[tid - 32] = eb1[net * 32 + tid - 32];
    else if (tid >= 64 && tid < 128) sb2s[tid - 64] = eb2[net * 64 + tid - 64];
    __syncthreads();

    const int u = (bid & 127) * 256 + tid;     // 0..32767
    const int e = u >> 4, cq = u & 15;
    const float w = W0MIN_ + (float)e * DW_;
    const float s = 8.0f * w * rcp_fast(1.0f - fabsf(w));
    float h0[16];
#pragma unroll
    for (int i = 0; i < 16; ++i)
      h0[i] = tanh_e2(K2 * fmaf(s, sW0s[i], sb0s[i]));
    float h1[32];
#pragma unroll
    for (int j = 0; j < 32; ++j) {
      float a = sb1s[j];
#pragma unroll
      for (int i = 0; i < 16; ++i) a = fmaf(h0[i], sW1[i * 32 + j], a);
      h1[j] = tanh_e2(K2 * a);
    }
    f4 a4 = *(const f4*)&sb2s[cq * 4];
    for (int j = 0; j < 32; ++j) {
      f4 wv4 = *(const f4*)&sW2[j * 64 + cq * 4];
      a4 += h1[j] * wv4;
    }
    union { h16 e4[4]; unsigned long long q; } o;
#pragma unroll
    for (int q = 0; q < 4; ++q) o.e4[q] = (h16)tanh_e2(K2 * a4[q]);
    *(unsigned long long*)&tbl[((size_t)(net * TBL_N + e)) * 64 + cq * 4] = o.q;
  } else if (bid < 640) {
    int idx = (bid - 512) * 256 + tid;          // 0..32767
    int t = idx >> 14, n = idx & 127, k8 = (idx >> 7) & 127;
    union { v8h v; h16 e[8]; } o;
#pragma unroll
    for (int i = 0; i < 8; ++i)
      o.e[i] = (h16)(W0SCL * fW0[(size_t)t * 131072 + (size_t)(k8 * 8 + i) * 128 + n]);
    *(v8h*)&W0t[((size_t)t * 128 + n) * 1024 + k8 * 8] = o.v;
  } else if (bid < 656) {
    int idx = (bid - 640) * 256 + tid;          // 0..4095
    f4 c;
    c.x = coord[idx]; c.y = coord[NATOM + idx]; c.z = coord[2 * NATOM + idx];
    c.w = 0.0f;
    coordP[idx] = c;
  } else {
    int idx = (bid - 656) * 256 + tid;          // 0..4095
    int t = idx >> 11, rem = idx & 2047;
    int n = rem >> 4, k8 = rem & 15;
    union { v8h v; h16 e[8]; } o;
#pragma unroll
    for (int i = 0; i < 8; ++i)
      o.e[i] = (h16)(K2 * fW1[(size_t)t * 16384 + (size_t)(k8 * 8 + i) * 128 + n]);
    *(v8h*)&W1t[((size_t)t * 128 + n) * 128 + k8 * 8] = o.v;
  }
}

// ---------------------------------------------------------------------------
// Kernel 1: 256 thr = 4 waves = 4 atoms. Table-lookup embedding, m-pair
// gathers (b32 transpose writes, CHUNK-LOCAL m index), T = Rp@E on MFMA,
// stage G as MFMA pair-contraction G = U^T V. LDS pooled -> 30.6 KB ->
// 4 blocks/CU at launch_bounds(256,4).
// ---------------------------------------------------------------------------
__global__ __launch_bounds__(256, 4) void k_embed(
    const f4* __restrict__ coordP, const float* __restrict__ box,
    const int* __restrict__ nbrs, const float* __restrict__ Tbias,
    const h16* __restrict__ tbl, h16* __restrict__ Gout)
{
  __shared__ h16 pool1[4][2560] __attribute__((aligned(16))); // E32t[64][40] / Vt[64][40]
  __shared__ h16 pool2[4][1360] __attribute__((aligned(16))); // Rls[10][136] / Uls[16][40]

  const int tid = threadIdx.x;
  const int wv = tid >> 6;
  const int lane = tid & 63;
  const int n = blockIdx.x * 4 + wv;
  const int ti = (n >= HALF_N) ? 1 : 0;
  const int c15 = lane & 15, g4 = lane >> 4;
  const int mp = lane >> 2, cg = lane & 3;   // gather mapping: m-pair x 16ch

  h16* E32 = &pool1[wv][0];   // [ch][40] during T phase; Vt [col][40] after
  h16* Rl  = &pool2[wv][0];   // [x][136] during T phase; Uls [a][40] after

  const int jnb0 = nbrs[(size_t)n * 128 + lane];
  const int jnb1 = nbrs[(size_t)n * 128 + 64 + lane];

  // ---- stage A: geometry + R rows + per-lane table index/frac regs ----
  int uf0 = 0, uf1 = 0;
  {
    const float bx = box[0], by = box[1], bz = box[2];
    const float rbx = rcp_fast(bx), rby = rcp_fast(by), rbz = rcp_fast(bz);
    const f4 cme = coordP[n];
#pragma unroll
    for (int nb = 0; nb < 2; ++nb) {
      const int m = nb * 64 + lane;
      const f4 cj = coordP[nb ? jnb1 : jnb0];
      float dx = cj.x - cme.x;
      float dy = cj.y - cme.y;
      float dz = cj.z - cme.z;
      dx -= bx * rintf(dx * rbx);
      dy -= by * rintf(dy * rby);
      dz -= bz * rintf(dz * rbz);
      float r2 = dx * dx + dy * dy + dz * dz;
      bool mk = r2 > 1e-12f;
      float rs = sqrtf(mk ? r2 : 1.0f);
      float r  = mk ? rs : 0.0f;
      float sw = 0.5f * __cosf(0.52359878f * fminf(r, 6.0f)) + 0.5f;
      float invr = mk ? rcp_fast(rs) : 1.0f;
      float sr = (mk && r < 6.0f) ? sw * invr : 0.0f;
      float x0 = dx * invr, x1 = dy * invr, x2 = dz * invr;
      float srn = sr * 20.0f;
      float s   = (sr - 0.1f) * 20.0f;
      Rl[0 * 136 + m] = (h16)srn;
      Rl[1 * 136 + m] = (h16)(1.7320508f * srn * x0);
      Rl[2 * 136 + m] = (h16)(1.7320508f * srn * x1);
      Rl[3 * 136 + m] = (h16)(1.7320508f * srn * x2);
      Rl[4 * 136 + m] = (h16)(3.0f * srn * (x0 * x0 - 0.33333334f));
      Rl[5 * 136 + m] = (h16)(3.0f * srn * (x1 * x1 - 0.33333334f));
      Rl[6 * 136 + m] = (h16)(3.0f * srn * (x2 * x2 - 0.33333334f));
      Rl[7 * 136 + m] = (h16)(4.2426407f * srn * (x0 * x1));
      Rl[8 * 136 + m] = (h16)(4.2426407f * srn * (x1 * x2));
      Rl[9 * 136 + m] = (h16)(4.2426407f * srn * (x2 * x0));
      float wr = s * rcp_fast(8.0f + fabsf(s));
      float fidx = (wr - W0MIN_) * RSCALE_;
      fidx = fminf(fmaxf(fidx, 0.0f), 2045.99f);
      float i0f = floorf(fidx);
      h16 frh = (h16)(fidx - i0f);
      int uf = ((int)i0f << 16) |
               (int)__builtin_bit_cast(unsigned short, frh);
      if (nb == 0) uf0 = uf; else uf1 = uf;
    }
  }

  union U8 { v8h v; v2h p[4]; h16 e[8]; };
  const int rrow = (c15 < 10) ? c15 : 9;
  const v8h vzero = {};
  f4 tac[4];
#pragma unroll
  for (int nt = 0; nt < 4; ++nt) tac[nt] = (f4){0.f, 0.f, 0.f, 0.f};

  // issue: gather chunk ks (2 m x 16 ch per lane) -> 8 v8h; returns 2 fracs
  auto issue = [&](int ks, U8* buf, float* fr) {
#pragma unroll
    for (int e = 0; e < 2; ++e) {
      int src = ((ks & 1) * 32 + mp * 2 + e) * 4;
      unsigned uu = (unsigned)__builtin_amdgcn_ds_bpermute(src, (ks < 2) ? uf0 : uf1);
      int i0 = (int)(uu >> 16);
      fr[e] = (float)__builtin_bit_cast(h16, (unsigned short)(uu & 0xffffu));
      const int net = ti * 2 + (ks >> 1);
      const h16* rp = tbl + ((size_t)net * TBL_N + i0) * 64 + cg * 16;
      buf[e * 4 + 0].v = *(const v8h*)(rp);            // row i0, ch 0..7
      buf[e * 4 + 1].v = *(const v8h*)(rp + 8);        // row i0, ch 8..15
      buf[e * 4 + 2].v = *(const v8h*)(rp + 64);       // row i0+1
      buf[e * 4 + 3].v = *(const v8h*)(rp + 72);
    }
  };

  // proc: lerp 2 m x 16 ch -> b32 transpose writes (LOCAL m!), 4 T-MFMAs
  auto proc = [&](int ks, U8* buf, const float* fr) {
    v2h f0; f0.x = (h16)fr[0]; f0.y = (h16)fr[0];
    v2h f1; f1.x = (h16)fr[1]; f1.y = (h16)fr[1];
    const int m0 = mp * 2;   // FIX: chunk-local m (was ks*32+mp*2 -> OOB)
#pragma unroll
    for (int ch8 = 0; ch8 < 2; ++ch8) {
#pragma unroll
      for (int p = 0; p < 4; ++p) {
        v2h e0 = buf[ch8].p[p]     + f0 * (buf[2 + ch8].p[p] - buf[ch8].p[p]);
        v2h e1 = buf[4 + ch8].p[p] + f1 * (buf[6 + ch8].p[p] - buf[4 + ch8].p[p]);
        const int c = cg * 16 + ch8 * 8 + p * 2;
        v2h w0; w0.x = e0.x; w0.y = e1.x;
        v2h w1; w1.x = e0.y; w1.y = e1.y;
        *(v2h*)&E32[c * 40 + m0]       = w0;
        *(v2h*)&E32[(c + 1) * 40 + m0] = w1;
      }
    }
    v8h ra = *(const v8h*)&Rl[rrow * 136 + ks * 32 + g4 * 8];
    if (c15 >= 10) ra = vzero;
#pragma unroll
    for (int nt = 0; nt < 4; ++nt) {
      v8h bf = *(const v8h*)&E32[(nt * 16 + c15) * 40 + g4 * 8];
      tac[nt] = __builtin_amdgcn_mfma_f32_16x16x32_f16(ra, bf, tac[nt], 0, 0, 0);
    }
  };

  // 2-deep pipeline over the 4 chunks
  U8 bA[8], bB[8];
  float frA[2], frB[2];
  issue(0, bA, frA);
  issue(1, bB, frB);
  proc(0, bA, frA);
  issue(2, bA, frA);
  proc(1, bB, frB);
  issue(3, bB, frB);
  proc(2, bA, frA);
  proc(3, bB, frB);

  // ---- Vt: V[x][col] = T rows (x<10; 10..15 are genuine zeros from tac) ----
  h16* Vt = E32;   // reuse (same-wave lifetime: E32 fully consumed above)
  h16* Ul = Rl;
#pragma unroll
  for (int nt = 0; nt < 4; ++nt) {
    const int col = nt * 16 + c15;
    float tb = (g4 == 0) ? Tbias[col] : 0.0f;
    v4h pk;
    pk[0] = (h16)(tac[nt][0] * 0.05f + tb);
    pk[1] = (h16)(tac[nt][1] * 0.05f);
    pk[2] = (h16)(tac[nt][2] * 0.05f);
    pk[3] = (h16)(tac[nt][3] * 0.05f);
    *(v4h*)&Vt[col * 40 + g4 * 4] = pk;
  }
  // zero pad x = 16..31 (col = lane covers all 64 columns)
  *(v8h*)&Vt[lane * 40 + 16] = vzero;
  *(v8h*)&Vt[lane * 40 + 24] = vzero;

  // ---- U rows (16 lanes; a = lane): quadratic G2 terms, scaled by 1/16 ----
  if (lane < 16) {
    const h16* va = &Vt[lane * 40];
    const h16* vb = &Vt[(16 + lane) * 40];
    v8h Ta = *(const v8h*)va;
    v8h Tb = *(const v8h*)vb;
    v2h Tb8 = *(const v2h*)(vb + 8);
    float g1x = (float)Tb[1], g1y = (float)Tb[2], g1z = (float)Tb[3];
    v8h up;
    up[0] = (h16)((float)Ta[0] * USCL);
    up[1] = (h16)((float)Ta[1] * USCL);
    up[2] = (h16)((float)Ta[2] * USCL);
    up[3] = (h16)((float)Ta[3] * USCL);
    up[4] = (h16)((g1x * g1x + (float)Tb[4]) * USCL);
    up[5] = (h16)((g1y * g1y + (float)Tb[5]) * USCL);
    up[6] = (h16)((g1z * g1z + (float)Tb[6]) * USCL);
    up[7] = (h16)((1.4142135f * g1x * g1y + (float)Tb[7]) * USCL);
    *(v8h*)&Ul[lane * 40] = up;
    v2h u89;
    u89.x = (h16)((1.4142135f * g1y * g1z + (float)Tb8[0]) * USCL);
    u89.y = (h16)((1.4142135f * g1z * g1x + (float)Tb8[1]) * USCL);
    *(v2h*)&Ul[lane * 40 + 8] = u89;
    v2h z2 = {};
    v4h z4 = {};
    *(v2h*)&Ul[lane * 40 + 10] = z2;
    *(v4h*)&Ul[lane * 40 + 12] = z4;
    *(v8h*)&Ul[lane * 40 + 16] = vzero;
    *(v8h*)&Ul[lane * 40 + 24] = vzero;
  }

  // ---- G = U^T V via 4 MFMAs; store Gflat fp16/64 ----
  {
    v8h ua = *(const v8h*)&Ul[c15 * 40 + g4 * 8];
    h16* gp = Gout + (size_t)n * 1024;
#pragma unroll
    for (int nt = 0; nt < 4; ++nt) {
      v8h vb = *(const v8h*)&Vt[(nt * 16 + c15) * 40 + g4 * 8];
      f4 z = (f4){0.f, 0.f, 0.f, 0.f};
      f4 g = __builtin_amdgcn_mfma_f32_16x16x32_f16(ua, vb, z, 0, 0, 0);
#pragma unroll
      for (int r = 0; r < 4; ++r) {
        const int a = g4 * 4 + r;
        gp[a * 64 + nt * 16 + c15] = (h16)(g[r] * GOUTS);
      }
    }
  }
}

// ---------------------------------------------------------------------------
// Fused fit: 128 blocks x 32 atoms, full K=1024. Layer 0: double-buffered
// K-stream MFMA GEMM. Layer 1: MFMA vs W1t in LDS. Layer 2 + partial: VALU.
// ---------------------------------------------------------------------------
__global__ __launch_bounds__(256) void k_fit(
    const h16* __restrict__ G16, const h16* __restrict__ W0t,
    const h16* __restrict__ W1t,
    const float* __restrict__ fb0, const float* __restrict__ fb1,
    const float* __restrict__ fW2, const float* __restrict__ fb2,
    const float* __restrict__ Ebias, float* __restrict__ BP)
{
  __shared__ h16 As[2][32][64]  __attribute__((aligned(16)));
  __shared__ h16 Bs[2][128][64] __attribute__((aligned(16)));
  __shared__ h16 ht[32][128]    __attribute__((aligned(16)));
  __shared__ h16 W1s[128][128]  __attribute__((aligned(16)));
  __shared__ float red[32][33];

  const int tid = threadIdx.x;
  const int abase = blockIdx.x * 32;
  const int t = (abase >= HALF_N) ? 1 : 0;
  const int lane = tid & 63, w = tid >> 6;
  const int c15 = lane & 15, g4 = lane >> 4;
  const int rt = w & 1, ng = w >> 1;

  float fb0v[4], b1v[4], w2v[4];
#pragma unroll
  for (int nt = 0; nt < 4; ++nt) {
    const int nn = ng * 64 + nt * 16 + c15;
    fb0v[nt] = K2 * fb0[t * 128 + nn];
    b1v[nt]  = K2 * fb1[t * 128 + nn];
    w2v[nt]  = fW2[t * 128 + nn];
  }

#pragma unroll
  for (int u = 0; u < 8; ++u) {
    int idx = u * 256 + tid;
    int nrow = idx >> 4, c8 = idx & 15;
    v8h v = *(const v8h*)&W1t[((size_t)t * 128 + nrow) * 128 + c8 * 8];
    int byte = nrow * 256 + ((c8 * 16) ^ ((nrow & 7) << 4));
    *(v8h*)((char*)&W1s[0][0] + byte) = v;
  }

  f4 acc[4];
#pragma unroll
  for (int nt = 0; nt < 4; ++nt) acc[nt] = (f4){0.f, 0.f, 0.f, 0.f};

  auto stageK = [&](int kc, int p) {
    {
      int r = tid >> 3, c8 = tid & 7;
      v8h v = *(const v8h*)&G16[(size_t)(abase + r) * 1024 + kc * 64 + c8 * 8];
      int byte = r * 128 + ((c8 * 16) ^ ((r & 7) << 4));
      *(v8h*)((char*)&As[p][0][0] + byte) = v;
    }
#pragma unroll
    for (int u = 0; u < 4; ++u) {
      int idx = u * 256 + tid;
      int nrow = idx >> 3, c8 = idx & 7;
      v8h v = *(const v8h*)&W0t[((size_t)t * 128 + nrow) * 1024 + kc * 64 + c8 * 8];
      int byte = nrow * 128 + ((c8 * 16) ^ ((nrow & 7) << 4));
      *(v8h*)((char*)&Bs[p][0][0] + byte) = v;
    }
  };

  stageK(0, 0);
  __syncthreads();
  for (int kc = 0; kc < 16; ++kc) {
    const int p = kc & 1;
    if (kc < 15) stageK(kc + 1, p ^ 1);
#pragma unroll
    for (int ksub = 0; ksub < 2; ++ksub) {
      const int ar = rt * 16 + c15;
      const int koff = (ksub * 32 + g4 * 8) * 2;
      v8h a = lds_v8h(&As[p][0][0], ar * 128 + (koff ^ ((ar & 7) << 4)));
#pragma unroll
      for (int nt = 0; nt < 4; ++nt) {
        const int br = ng * 64 + nt * 16 + c15;
        v8h b = lds_v8h(&Bs[p][0][0], br * 128 + (koff ^ ((br & 7) << 4)));
        acc[nt] = __builtin_amdgcn_mfma_f32_16x16x32_f16(a, b, acc[nt], 0, 0, 0);
      }
    }
    __syncthreads();
  }

#pragma unroll
  for (int nt = 0; nt < 4; ++nt)
#pragma unroll
    for (int r = 0; r < 4; ++r) {
      int a = rt * 16 + g4 * 4 + r;
      int k = ng * 64 + nt * 16 + c15;
      h16 hv = (h16)tanh_e2(acc[nt][r] + fb0v[nt]);
      int byte = a * 256 + ((k * 2) ^ ((a & 7) << 4));
      *((h16*)((char*)&ht[0][0] + byte)) = hv;
    }
  __syncthreads();

  f4 acc2[4];
#pragma unroll
  for (int nt = 0; nt < 4; ++nt) acc2[nt] = (f4){0.f, 0.f, 0.f, 0.f};
#pragma unroll
  for (int ks2 = 0; ks2 < 4; ++ks2) {
    const int ar = rt * 16 + c15;
    const int koff = (ks2 * 32 + g4 * 8) * 2;
    v8h a = lds_v8h(&ht[0][0], ar * 256 + (koff ^ ((ar & 7) << 4)));
#pragma unroll
    for (int nt = 0; nt < 4; ++nt) {
      const int br = ng * 64 + nt * 16 + c15;
      v8h b = lds_v8h(&W1s[0][0], br * 256 + (koff ^ ((br & 7) << 4)));
      acc2[nt] = __builtin_amdgcn_mfma_f32_16x16x32_f16(a, b, acc2[nt], 0, 0, 0);
    }
  }

#pragma unroll
  for (int r = 0; r < 4; ++r) {
    float v = 0.0f;
#pragma unroll
    for (int nt = 0; nt < 4; ++nt)
      v += tanh_e2(acc2[nt][r] + b1v[nt]) * w2v[nt];
    red[rt * 16 + g4 * 4 + r][ng * 16 + c15] = v;
  }
  __syncthreads();
  if (tid < 64) {
    const int a = tid & 31, half = tid >> 5;
    float s = 0.0f;
#pragma unroll
    for (int c = 0; c < 16; ++c) s += red[a][half * 16 + c];
    s += __shfl_xor(s, 32);
    s += __shfl_xor(s, 16);
    s += __shfl_xor(s, 8);
    s += __shfl_xor(s, 4);
    s += __shfl_xor(s, 2);
    s += __shfl_xor(s, 1);
    if (tid == 0) BP[blockIdx.x] = s + 32.0f * (fb2[t] + Ebias[t]);
  }
}

__global__ __launch_bounds__(64) void k_reduce(const float* __restrict__ BP,
                                               float* __restrict__ out)
{
  int tid = threadIdx.x;
  float s = BP[tid] + BP[tid + 64];
  s += __shfl_xor(s, 32);
  s += __shfl_xor(s, 16);
  s += __shfl_xor(s, 8);
  s += __shfl_xor(s, 4);
  s += __shfl_xor(s, 2);
  s += __shfl_xor(s, 1);
  if (tid == 0) out[0] = s;
}

extern "C" void kernel_launch(void* const* d_in, const int* in_sizes, int n_in,
                              void* d_out, int out_size, void* d_ws, size_t ws_size,
                              hipStream_t stream) {
  const float* coord = (const float*)d_in[0];
  const float* box   = (const float*)d_in[1];
  const int*   nbrs  = (const int*)d_in[2];
  const float* eW0   = (const float*)d_in[3];
  const float* eb0   = (const float*)d_in[4];
  const float* eW1   = (const float*)d_in[5];
  const float* eb1   = (const float*)d_in[6];
  const float* eW2   = (const float*)d_in[7];
  const float* eb2   = (const float*)d_in[8];
  const float* Tbias = (const float*)d_in[9];
  const float* fW0   = (const float*)d_in[10];
  const float* fb0   = (const float*)d_in[11];
  const float* fW1   = (const float*)d_in[12];
  const float* fb1   = (const float*)d_in[13];
  const float* fW2   = (const float*)d_in[14];
  const float* fb2   = (const float*)d_in[15];
  const float* Ebias = (const float*)d_in[16];

  char* ws = (char*)d_ws;
  h16*   G16 = (h16*)ws;                                   // 8 MB
  h16*   W0t = (h16*)(ws + (size_t)8  * 1024 * 1024);      // 512 KB
  h16*   W1t = (h16*)(ws + (size_t)9  * 1024 * 1024);      // 64 KB
  h16*   tbl = (h16*)(ws + (size_t)10 * 1024 * 1024);      // 1 MB
  f4*    cP  = (f4*)(ws + (size_t)11 * 1024 * 1024);       // 64 KB
  float* BP  = (float*)(ws + (size_t)12 * 1024 * 1024);    // 512 B

  k_setup<<<672, 256, 0, stream>>>(eW0, eb0, eW1, eb1, eW2, eb2, fW0, fW1,
                                   coord, tbl, W0t, W1t, cP);
  k_embed<<<1024, 256, 0, stream>>>(cP, box, nbrs, Tbias, tbl, G16);
  k_fit<<<128, 256, 0, stream>>>(G16, W0t, W1t, fb0, fb1, fW2, fb2, Ebias, BP);
  k_reduce<<<1, 64, 0, stream>>>(BP, (float*)d_out);
}